// Round 9
// baseline (293.468 us; speedup 1.0000x reference)
//
#include <hip/hip_runtime.h>

#define NFULL 8192
#define BATCH 4

typedef unsigned long long u64;
typedef unsigned int u32;
typedef __attribute__((ext_vector_type(8))) short bf8_t;   // 8 bf16 (4 VGPRs)
typedef __attribute__((ext_vector_type(4))) float f4_t;    // MFMA C/D

__device__ __forceinline__ u32 fbias(float f) {
  u32 u = __float_as_uint(f);
  return (u & 0x80000000u) ? ~u : (u | 0x80000000u);
}
__device__ __forceinline__ float funbias(u32 b) {
  u32 u = (b & 0x80000000u) ? (b & 0x7fffffffu) : ~b;
  return __uint_as_float(u);
}
__device__ __forceinline__ short f2bf(float f) {
  u32 u = __float_as_uint(f);
  u32 r = u + 0x7FFFu + ((u >> 16) & 1u);
  return (short)(r >> 16);
}

// ================= K=16 machinery, 32 lanes per query ======================
__device__ __forceinline__ void group_insert_g32(u32 m32, u64 ck, int slot16,
                                                 u64& val, u64& tau) {
  if (m32) {
    while (m32) {
      int src = __ffs(m32) - 1;
      m32 &= m32 - 1;
      u64 c = __shfl((unsigned long long)ck, src, 32);
      u64 prev = __shfl_up((unsigned long long)val, 1, 16);
      if (slot16 == 0) prev = 0ull;
      val = (val <= c) ? val : ((prev <= c) ? c : prev);
    }
    tau = __shfl((unsigned long long)val, 15, 16);
  }
}

// Round-1 bulk build: 15-stage bitonic sort of the first 32 candidates.
__device__ __forceinline__ void first_round_sort32(u64 ck, int gl,
                                                   u64& val, u64& tau) {
  u64 v = ck;
#pragma unroll
  for (int size = 2; size <= 32; size <<= 1) {
#pragma unroll
    for (int stride = size >> 1; stride > 0; stride >>= 1) {
      u64 other = __shfl_xor((unsigned long long)v, stride, 32);
      bool ddd = ((gl & size) == 0);
      bool takeMin = (((gl & stride) == 0) == ddd);
      u64 mn = (v <= other) ? v : other;
      u64 mx = (v <= other) ? other : v;
      v = takeMin ? mn : mx;
    }
  }
  val = __shfl((unsigned long long)v, gl & 15, 32);
  tau = __shfl((unsigned long long)val, 15, 16);
}

__device__ __forceinline__ void scan_range_g32(const float4* __restrict__ sb,
    int s, int e, float qx, float qy, float qz, float qq,
    int g32, int gl, int slot16, u64& val, u64& tau) {
  for (int t0 = s; t0 < e; t0 += 32) {
    int j = t0 + gl;
    u64 ck = ~0ull;
    if (j < e) {
      float4 P = sb[j];
      float rr = P.x * P.x + P.y * P.y + P.z * P.z;
      float d2 = qq + rr - 2.0f * (qx * P.x + qy * P.y + qz * P.z);
      ck = ((u64)fbias(d2) << 32) | (u32)__float_as_uint(P.w);
    }
    u64 full = __ballot(ck < tau);
    u32 m32 = (u32)(full >> (g32 * 32));
    group_insert_g32(m32, ck, slot16, val, tau);
  }
}

// Exactness: after scanning box B, if the Kth smallest d2 is strictly less
// than the squared distance to the nearest NON-clipped face of B, no outside
// point can enter the top-K. Ring expansion scans box(R+1)\box(R) exactly
// once per point; unique u64 keys keep tie-breaking identical to reference.
template<int GR, int R, int NREF>
__device__ __forceinline__ void knn_tail16_g32(
    const float4* __restrict__ sb, const int* __restrict__ cs,
    float qx, float qy, float qz, float qq,
    int ix, int iy, int iz, int x0, int x1, int y0, int y1, int z0, int z1,
    int g32, int gl, int slot16, u64& val, u64& tau) {
  const float h = 1.0f / GR;
  float m = 1e30f;
  if (x0 > 0)      m = fminf(m, qx - x0 * h);
  if (x1 < GR - 1) m = fminf(m, (x1 + 1) * h - qx);
  if (y0 > 0)      m = fminf(m, qy - y0 * h);
  if (y1 < GR - 1) m = fminf(m, (y1 + 1) * h - qy);
  if (z0 > 0)      m = fminf(m, qz - z0 * h);
  if (z1 < GR - 1) m = fminf(m, (z1 + 1) * h - qz);
  float bound = m * m;
  float kth_d2 = funbias((u32)(tau >> 32));
  if (!(kth_d2 < bound)) {  // group-uniform; rare
    int X0 = max(ix - (R + 1), 0), X1 = min(ix + (R + 1), GR - 1);
    int Y0 = max(iy - (R + 1), 0), Y1 = min(iy + (R + 1), GR - 1);
    int Z0 = max(iz - (R + 1), 0), Z1 = min(iz + (R + 1), GR - 1);
    int NY2 = Y1 - Y0 + 1;
    int nrow2 = (Z1 - Z0 + 1) * NY2;
    for (int rr2 = 0; rr2 < nrow2; ++rr2) {
      int zz = Z0 + rr2 / NY2, yy = Y0 + rr2 % NY2;
      int c0 = (zz * GR + yy) * GR;
      bool mid = (zz >= z0 && zz <= z1 && yy >= y0 && yy <= y1);
      int s1 = cs[c0 + X0];
      int e1 = mid ? cs[c0 + x0] : cs[c0 + X1 + 1];
      scan_range_g32(sb, s1, e1, qx, qy, qz, qq, g32, gl, slot16, val, tau);
      if (mid) {
        int s2 = cs[c0 + x1 + 1];
        int e2 = cs[c0 + X1 + 1];
        scan_range_g32(sb, s2, e2, qx, qy, qz, qq, g32, gl, slot16, val, tau);
      }
    }
    x0 = X0; x1 = X1; y0 = Y0; y1 = Y1; z0 = Z0; z1 = Z1;
    m = 1e30f;
    if (x0 > 0)      m = fminf(m, qx - x0 * h);
    if (x1 < GR - 1) m = fminf(m, (x1 + 1) * h - qx);
    if (y0 > 0)      m = fminf(m, qy - y0 * h);
    if (y1 < GR - 1) m = fminf(m, (y1 + 1) * h - qy);
    if (z0 > 0)      m = fminf(m, qz - z0 * h);
    if (z1 < GR - 1) m = fminf(m, (z1 + 1) * h - qz);
    bound = m * m;
    kth_d2 = funbias((u32)(tau >> 32));
    if (!(kth_d2 < bound)) {  // essentially unreachable
      for (int t0 = 0; t0 < NREF; t0 += 32) {
        int j = t0 + gl;
        u64 ck = ~0ull;
        if (j < NREF) {
          float4 P = sb[j];
          int cx = min(max((int)(P.x * GR), 0), GR - 1);
          int cy = min(max((int)(P.y * GR), 0), GR - 1);
          int cz = min(max((int)(P.z * GR), 0), GR - 1);
          bool inbox = (cx >= x0 && cx <= x1 && cy >= y0 && cy <= y1 &&
                        cz >= z0 && cz <= z1);
          if (!inbox) {
            float rr = P.x * P.x + P.y * P.y + P.z * P.z;
            float d2 = qq + rr - 2.0f * (qx * P.x + qy * P.y + qz * P.z);
            ck = ((u64)fbias(d2) << 32) | (u32)__float_as_uint(P.w);
          }
        }
        u64 full = __ballot(ck < tau);
        u32 m32 = (u32)(full >> (g32 * 32));
        group_insert_g32(m32, ck, slot16, val, tau);
      }
    }
  }
}

// ---------------- K=16 grid (nrow <= 32 fits directly in 32 lanes) ---------
template<int GR, int R, int NREF>
__device__ void knn_grid16_g32_dev(int vbx, int b,
    const float* __restrict__ pos, const float4* __restrict__ sorted,
    const int* __restrict__ cellStart, int csStride, int Mq,
    int* __restrict__ oidx) {
  int wv = threadIdx.x >> 6, lane = threadIdx.x & 63;
  int g32 = lane >> 5, gl = lane & 31;
  int q = vbx * 8 + wv * 2 + g32;
  const float* pb = pos + (size_t)b * NFULL * 3;
  const float4* sb = sorted + (size_t)b * NREF;
  const int* cs = cellStart + b * csStride;
  float qx = pb[q * 3 + 0], qy = pb[q * 3 + 1], qz = pb[q * 3 + 2];
  float qq = qx * qx + qy * qy + qz * qz;
  int ix = min(max((int)(qx * GR), 0), GR - 1);
  int iy = min(max((int)(qy * GR), 0), GR - 1);
  int iz = min(max((int)(qz * GR), 0), GR - 1);
  int x0 = max(ix - R, 0), x1 = min(ix + R, GR - 1);
  int y0 = max(iy - R, 0), y1 = min(iy + R, GR - 1);
  int z0 = max(iz - R, 0), z1 = min(iz + R, GR - 1);

  int ny = y1 - y0 + 1;
  int nrow = (z1 - z0 + 1) * ny;  // <= 25 for R=2
  int s_i = 0, len_i = 0;
  if (gl < nrow) {
    int zz = z0 + gl / ny, yy = y0 + gl % ny;
    int c0 = (zz * GR + yy) * GR + x0;
    s_i = cs[c0];
    len_i = cs[c0 + (x1 - x0) + 1] - s_i;
  }
  int p_i = len_i;
#pragma unroll
  for (int st = 1; st < 32; st <<= 1) {
    int o = __shfl_up(p_i, st, 32);
    if (gl >= st) p_i += o;
  }
  int T = __shfl(p_i, 31, 32);
  p_i -= len_i;              // exclusive prefix
  int d_i = s_i - p_i;       // sorted index = v + d_row
  if (gl >= nrow) p_i = 0x7fffffff;

  int slot16 = lane & 15;
  u64 val, tau;

  // ---- round 1: 32-candidate bitonic bulk build
  {
    int v = gl;
    int r = 0;
#pragma unroll
    for (int st = 16; st >= 1; st >>= 1) {
      int pc = __shfl(p_i, r + st, 32);
      if (v >= pc) r += st;
    }
    int addr = v + __shfl(d_i, r, 32);
    u64 ck = ~0ull;
    if (v < T) {
      float4 P = sb[addr];
      float rr = P.x * P.x + P.y * P.y + P.z * P.z;
      float d2 = qq + rr - 2.0f * (qx * P.x + qy * P.y + qz * P.z);
      ck = ((u64)fbias(d2) << 32) | (u32)__float_as_uint(P.w);
    }
    first_round_sort32(ck, gl, val, tau);
  }

  for (int v0 = 32; v0 < T; v0 += 32) {  // T group-uniform
    int v = v0 + gl;
    int r = 0;
#pragma unroll
    for (int st = 16; st >= 1; st >>= 1) {
      int pc = __shfl(p_i, r + st, 32);
      if (v >= pc) r += st;
    }
    int addr = v + __shfl(d_i, r, 32);
    u64 ck = ~0ull;
    if (v < T) {
      float4 P = sb[addr];
      float rr = P.x * P.x + P.y * P.y + P.z * P.z;
      float d2 = qq + rr - 2.0f * (qx * P.x + qy * P.y + qz * P.z);
      ck = ((u64)fbias(d2) << 32) | (u32)__float_as_uint(P.w);
    }
    u64 full = __ballot(ck < tau);
    u32 m32 = (u32)(full >> (g32 * 32));
    group_insert_g32(m32, ck, slot16, val, tau);
  }

  knn_tail16_g32<GR, R, NREF>(sb, cs, qx, qy, qz, qq,
      ix, iy, iz, x0, x1, y0, y1, z0, z1, g32, gl, slot16, val, tau);

  if (gl < 16) {
    size_t base = ((size_t)b * Mq + q) * 16;
    oidx[base + gl] = (int)(u32)val;
  }
}

// ----------------------------------------------- K=16 brute (32-lane) ------
__device__ void knn_brute16_g32_dev(int vbx, int b,
    const float* __restrict__ pos, int Nref, int Mq, int* __restrict__ oidx) {
  int wv = threadIdx.x >> 6, lane = threadIdx.x & 63;
  int g32 = lane >> 5, gl = lane & 31;
  int q = vbx * 8 + wv * 2 + g32;
  const float* pb = pos + (size_t)b * NFULL * 3;
  float qx = pb[q * 3 + 0], qy = pb[q * 3 + 1], qz = pb[q * 3 + 2];
  float qq = qx * qx + qy * qy + qz * qz;

  int slot16 = lane & 15;
  u64 val, tau;

  {
    int j = gl;
    float rx = pb[j * 3 + 0];
    float ry = pb[j * 3 + 1];
    float rz = pb[j * 3 + 2];
    float rr = rx * rx + ry * ry + rz * rz;
    float d2 = qq + rr - 2.0f * (qx * rx + qy * ry + qz * rz);
    u64 ck = ((u64)fbias(d2) << 32) | (u32)j;
    first_round_sort32(ck, gl, val, tau);
  }

  for (int t0 = 32; t0 < Nref; t0 += 32) {
    int j = t0 + gl;
    float rx = pb[j * 3 + 0];
    float ry = pb[j * 3 + 1];
    float rz = pb[j * 3 + 2];
    float rr = rx * rx + ry * ry + rz * rz;
    float d2 = qq + rr - 2.0f * (qx * rx + qy * ry + qz * rz);
    u64 ck = ((u64)fbias(d2) << 32) | (u32)j;
    u64 full = __ballot(ck < tau);
    u32 m32 = (u32)(full >> (g32 * 32));
    group_insert_g32(m32, ck, slot16, val, tau);
  }

  if (gl < 16) {
    size_t base = ((size_t)b * Mq + q) * 16;
    oidx[base + gl] = (int)(u32)val;
  }
}

// ================= K=3 machinery (16 lanes/query, per-lane top-3) ==========
__device__ __forceinline__ void lane_insert3(u64 ck, u64& v0, u64& v1, u64& v2) {
  u64 a = (v0 <= ck) ? v0 : ck;
  u64 bb = (v0 <= ck) ? ck : v0;
  v0 = a;
  u64 c = (v1 <= bb) ? v1 : bb;
  u64 d = (v1 <= bb) ? bb : v1;
  v1 = c;
  v2 = (v2 <= d) ? v2 : d;
}

__device__ __forceinline__ void merge3(u64 v0, u64 v1, u64 v2,
                                       u64& o0, u64& o1, u64& o2) {
  u64 h = v0;
  int hc = 0;
  u64 outs[3];
#pragma unroll
  for (int k = 0; k < 3; ++k) {
    u64 m = h;
#pragma unroll
    for (int st = 1; st < 16; st <<= 1) {
      u64 o = __shfl_xor((unsigned long long)m, st, 16);
      m = (m <= o) ? m : o;
    }
    outs[k] = m;
    if (h == m) { ++hc; h = (hc == 1) ? v1 : ((hc == 2) ? v2 : ~0ull); }
  }
  o0 = outs[0]; o1 = outs[1]; o2 = outs[2];
}

__device__ __forceinline__ void scan_range3(const float4* __restrict__ sb,
    int s, int e, float qx, float qy, float qz, float qq,
    int gl, u64& v0, u64& v1, u64& v2) {
  for (int t0 = s; t0 < e; t0 += 16) {
    int j = t0 + gl;
    if (j < e) {
      float4 P = sb[j];
      float rr = P.x * P.x + P.y * P.y + P.z * P.z;
      float d2 = qq + rr - 2.0f * (qx * P.x + qy * P.y + qz * P.z);
      u64 ck = ((u64)fbias(d2) << 32) | (u32)__float_as_uint(P.w);
      lane_insert3(ck, v0, v1, v2);
    }
  }
}

template<int GR, int R, int NREF>
__device__ __forceinline__ void knn_tail3(
    const float4* __restrict__ sb, const int* __restrict__ cs,
    float qx, float qy, float qz, float qq,
    int ix, int iy, int iz, int x0, int x1, int y0, int y1, int z0, int z1,
    int gl, u64& v0, u64& v1, u64& v2, u64& o0, u64& o1, u64& o2) {
  const float h = 1.0f / GR;
  float m = 1e30f;
  if (x0 > 0)      m = fminf(m, qx - x0 * h);
  if (x1 < GR - 1) m = fminf(m, (x1 + 1) * h - qx);
  if (y0 > 0)      m = fminf(m, qy - y0 * h);
  if (y1 < GR - 1) m = fminf(m, (y1 + 1) * h - qy);
  if (z0 > 0)      m = fminf(m, qz - z0 * h);
  if (z1 < GR - 1) m = fminf(m, (z1 + 1) * h - qz);
  float bound = m * m;
  merge3(v0, v1, v2, o0, o1, o2);
  float kth_d2 = funbias((u32)(o2 >> 32));
  if (!(kth_d2 < bound)) {  // group-uniform; rare
    int X0 = max(ix - (R + 1), 0), X1 = min(ix + (R + 1), GR - 1);
    int Y0 = max(iy - (R + 1), 0), Y1 = min(iy + (R + 1), GR - 1);
    int Z0 = max(iz - (R + 1), 0), Z1 = min(iz + (R + 1), GR - 1);
    int NY2 = Y1 - Y0 + 1;
    int nrow2 = (Z1 - Z0 + 1) * NY2;
    for (int rr2 = 0; rr2 < nrow2; ++rr2) {
      int zz = Z0 + rr2 / NY2, yy = Y0 + rr2 % NY2;
      int c0 = (zz * GR + yy) * GR;
      bool mid = (zz >= z0 && zz <= z1 && yy >= y0 && yy <= y1);
      int s1 = cs[c0 + X0];
      int e1 = mid ? cs[c0 + x0] : cs[c0 + X1 + 1];
      scan_range3(sb, s1, e1, qx, qy, qz, qq, gl, v0, v1, v2);
      if (mid) {
        int s2 = cs[c0 + x1 + 1];
        int e2 = cs[c0 + X1 + 1];
        scan_range3(sb, s2, e2, qx, qy, qz, qq, gl, v0, v1, v2);
      }
    }
    x0 = X0; x1 = X1; y0 = Y0; y1 = Y1; z0 = Z0; z1 = Z1;
    m = 1e30f;
    if (x0 > 0)      m = fminf(m, qx - x0 * h);
    if (x1 < GR - 1) m = fminf(m, (x1 + 1) * h - qx);
    if (y0 > 0)      m = fminf(m, qy - y0 * h);
    if (y1 < GR - 1) m = fminf(m, (y1 + 1) * h - qy);
    if (z0 > 0)      m = fminf(m, qz - z0 * h);
    if (z1 < GR - 1) m = fminf(m, (z1 + 1) * h - qz);
    bound = m * m;
    merge3(v0, v1, v2, o0, o1, o2);
    kth_d2 = funbias((u32)(o2 >> 32));
    if (!(kth_d2 < bound)) {  // essentially unreachable
      for (int t0 = 0; t0 < NREF; t0 += 16) {
        int j = t0 + gl;
        if (j < NREF) {
          float4 P = sb[j];
          int cx = min(max((int)(P.x * GR), 0), GR - 1);
          int cy = min(max((int)(P.y * GR), 0), GR - 1);
          int cz = min(max((int)(P.z * GR), 0), GR - 1);
          bool inbox = (cx >= x0 && cx <= x1 && cy >= y0 && cy <= y1 &&
                        cz >= z0 && cz <= z1);
          if (!inbox) {
            float rr = P.x * P.x + P.y * P.y + P.z * P.z;
            float d2 = qq + rr - 2.0f * (qx * P.x + qy * P.y + qz * P.z);
            u64 ck = ((u64)fbias(d2) << 32) | (u32)__float_as_uint(P.w);
            lane_insert3(ck, v0, v1, v2);
          }
        }
      }
      merge3(v0, v1, v2, o0, o1, o2);
    }
  }
}

template<int GR, int R, int NREF>
__device__ void knn_grid_flat3_dev(int vbx, int b,
    const float* __restrict__ pos, const float4* __restrict__ sorted,
    const int* __restrict__ cellStart, int csStride, int Mq,
    int* __restrict__ oidx, float* __restrict__ od2) {
  int wv = threadIdx.x >> 6, lane = threadIdx.x & 63;
  int g = lane >> 4, gl = lane & 15;
  int q = vbx * 16 + wv * 4 + g;
  const float* pb = pos + (size_t)b * NFULL * 3;
  const float4* sb = sorted + (size_t)b * NREF;
  const int* cs = cellStart + b * csStride;
  float qx = pb[q * 3 + 0], qy = pb[q * 3 + 1], qz = pb[q * 3 + 2];
  float qq = qx * qx + qy * qy + qz * qz;
  int ix = min(max((int)(qx * GR), 0), GR - 1);
  int iy = min(max((int)(qy * GR), 0), GR - 1);
  int iz = min(max((int)(qz * GR), 0), GR - 1);
  int x0 = max(ix - R, 0), x1 = min(ix + R, GR - 1);
  int y0 = max(iy - R, 0), y1 = min(iy + R, GR - 1);
  int z0 = max(iz - R, 0), z1 = min(iz + R, GR - 1);

  int ny = y1 - y0 + 1;
  int nrow = (z1 - z0 + 1) * ny;  // <= 9 for R=1
  int s_i = 0, len_i = 0;
  if (gl < nrow) {
    int zz = z0 + gl / ny, yy = y0 + gl % ny;
    int c0 = (zz * GR + yy) * GR + x0;
    s_i = cs[c0];
    len_i = cs[c0 + (x1 - x0) + 1] - s_i;
  }
  int p_i = len_i;
#pragma unroll
  for (int st = 1; st < 16; st <<= 1) {
    int o = __shfl_up(p_i, st, 16);
    if (gl >= st) p_i += o;
  }
  int T = __shfl(p_i, 15, 16);
  p_i -= len_i;              // exclusive prefix
  int d_i = s_i - p_i;       // sorted index = v + d_row
  if (gl >= nrow) p_i = 0x7fffffff;

  u64 v0 = ~0ull, v1 = ~0ull, v2 = ~0ull;

  for (int vb = 0; vb < T; vb += 16) {  // T group-uniform
    int v = vb + gl;
    int r = 0;
#pragma unroll
    for (int st = 8; st >= 1; st >>= 1) {
      int pc = __shfl(p_i, r + st, 16);
      if (v >= pc) r += st;
    }
    int addr = v + __shfl(d_i, r, 16);
    if (v < T) {
      float4 P = sb[addr];
      float rr = P.x * P.x + P.y * P.y + P.z * P.z;
      float d2 = qq + rr - 2.0f * (qx * P.x + qy * P.y + qz * P.z);
      u64 ck = ((u64)fbias(d2) << 32) | (u32)__float_as_uint(P.w);
      lane_insert3(ck, v0, v1, v2);
    }
  }

  u64 o0, o1, o2;
  knn_tail3<GR, R, NREF>(sb, cs, qx, qy, qz, qq,
      ix, iy, iz, x0, x1, y0, y1, z0, z1, gl, v0, v1, v2, o0, o1, o2);

  if (gl < 3) {
    u64 val = (gl == 0) ? o0 : ((gl == 1) ? o1 : o2);
    size_t base = ((size_t)b * Mq + q) * 3;
    oidx[base + gl] = (int)(u32)val;
    od2[base + gl] = fmaxf(funbias((u32)(val >> 32)), 0.0f);
  }
}

template<int GR, int R, int NREF>
__device__ void knn_grid_flat32_3_dev(int vbx, int b,
    const float* __restrict__ pos, const float4* __restrict__ sorted,
    const int* __restrict__ cellStart, int csStride, int Mq,
    int* __restrict__ oidx, float* __restrict__ od2) {
  int wv = threadIdx.x >> 6, lane = threadIdx.x & 63;
  int g = lane >> 4, gl = lane & 15;
  int q = vbx * 16 + wv * 4 + g;
  const float* pb = pos + (size_t)b * NFULL * 3;
  const float4* sb = sorted + (size_t)b * NREF;
  const int* cs = cellStart + b * csStride;
  float qx = pb[q * 3 + 0], qy = pb[q * 3 + 1], qz = pb[q * 3 + 2];
  float qq = qx * qx + qy * qy + qz * qz;
  int ix = min(max((int)(qx * GR), 0), GR - 1);
  int iy = min(max((int)(qy * GR), 0), GR - 1);
  int iz = min(max((int)(qz * GR), 0), GR - 1);
  int x0 = max(ix - R, 0), x1 = min(ix + R, GR - 1);
  int y0 = max(iy - R, 0), y1 = min(iy + R, GR - 1);
  int z0 = max(iz - R, 0), z1 = min(iz + R, GR - 1);

  int ny = y1 - y0 + 1;
  int nrow = (z1 - z0 + 1) * ny;  // <= 25 for R=2
  int sLo = 0, lenLo = 0, sHi = 0, lenHi = 0;
  if (gl < nrow) {
    int zz = z0 + gl / ny, yy = y0 + gl % ny;
    int c0 = (zz * GR + yy) * GR + x0;
    sLo = cs[c0]; lenLo = cs[c0 + (x1 - x0) + 1] - sLo;
  }
  {
    int i2 = gl + 16;
    if (i2 < nrow) {
      int zz = z0 + i2 / ny, yy = y0 + i2 % ny;
      int c0 = (zz * GR + yy) * GR + x0;
      sHi = cs[c0]; lenHi = cs[c0 + (x1 - x0) + 1] - sHi;
    }
  }
  int pLo = lenLo, pHi = lenHi;
#pragma unroll
  for (int st = 1; st < 16; st <<= 1) {
    int o = __shfl_up(pLo, st, 16);
    if (gl >= st) pLo += o;
    int o2_ = __shfl_up(pHi, st, 16);
    if (gl >= st) pHi += o2_;
  }
  int tot16 = __shfl(pLo, 15, 16);
  pHi += tot16;
  int T = __shfl(pHi, 15, 16);
  pLo -= lenLo; pHi -= lenHi;      // exclusive prefixes
  int dLo = sLo - pLo, dHi = sHi - pHi;
  if (gl >= nrow) pLo = 0x7fffffff;
  if (gl + 16 >= nrow) pHi = 0x7fffffff;

  u64 v0 = ~0ull, v1 = ~0ull, v2 = ~0ull;

  for (int vb = 0; vb < T; vb += 16) {  // T group-uniform
    int v = vb + gl;
    int r = 0;
#pragma unroll
    for (int st = 16; st >= 1; st >>= 1) {
      int j = r + st;                      // j <= 31
      int pcL = __shfl(pLo, j & 15, 16);
      int pcH = __shfl(pHi, j & 15, 16);
      int pc = (j < 16) ? pcL : pcH;
      if (v >= pc) r = j;
    }
    int dL = __shfl(dLo, r & 15, 16);
    int dH = __shfl(dHi, r & 15, 16);
    int addr = v + ((r < 16) ? dL : dH);
    if (v < T) {
      float4 P = sb[addr];
      float rr = P.x * P.x + P.y * P.y + P.z * P.z;
      float d2 = qq + rr - 2.0f * (qx * P.x + qy * P.y + qz * P.z);
      u64 ck = ((u64)fbias(d2) << 32) | (u32)__float_as_uint(P.w);
      lane_insert3(ck, v0, v1, v2);
    }
  }

  u64 o0, o1, o2;
  knn_tail3<GR, R, NREF>(sb, cs, qx, qy, qz, qq,
      ix, iy, iz, x0, x1, y0, y1, z0, z1, gl, v0, v1, v2, o0, o1, o2);

  if (gl < 3) {
    u64 val = (gl == 0) ? o0 : ((gl == 1) ? o1 : o2);
    size_t base = ((size_t)b * Mq + q) * 3;
    oidx[base + gl] = (int)(u32)val;
    od2[base + gl] = fmaxf(funbias((u32)(val >> 32)), 0.0f);
  }
}

__device__ void knn_brute3_dev(int vbx, int b,
    const float* __restrict__ pos, int Nref, int Mq,
    int* __restrict__ oidx, float* __restrict__ od2) {
  int wv = threadIdx.x >> 6, lane = threadIdx.x & 63;
  int g = lane >> 4, gl = lane & 15;
  int q = vbx * 16 + wv * 4 + g;
  const float* pb = pos + (size_t)b * NFULL * 3;
  float qx = pb[q * 3 + 0], qy = pb[q * 3 + 1], qz = pb[q * 3 + 2];
  float qq = qx * qx + qy * qy + qz * qz;

  u64 v0 = ~0ull, v1 = ~0ull, v2 = ~0ull;
  for (int j = gl; j < Nref; j += 16) {
    float rx = pb[j * 3 + 0];
    float ry = pb[j * 3 + 1];
    float rz = pb[j * 3 + 2];
    float rr = rx * rx + ry * ry + rz * rz;
    float d2 = qq + rr - 2.0f * (qx * rx + qy * ry + qz * rz);
    u64 ck = ((u64)fbias(d2) << 32) | (u32)j;
    lane_insert3(ck, v0, v1, v2);
  }
  u64 o0, o1, o2;
  merge3(v0, v1, v2, o0, o1, o2);

  if (gl < 3) {
    u64 val = (gl == 0) ? o0 : ((gl == 1) ? o1 : o2);
    size_t base = ((size_t)b * Mq + q) * 3;
    oidx[base + gl] = (int)(u32)val;
    od2[base + gl] = fmaxf(funbias((u32)(val >> 32)), 0.0f);
  }
}

// ----------------------------------- fused weight packing helpers ---------
__device__ __forceinline__ void pack_tile_rt(const float* __restrict__ W,
                                             short* __restrict__ outp,
                                             int KDIM, int N, int tile, int lane) {
  int NT = N >> 4;
  int kt = tile / NT, nt = tile - kt * NT;
  int n = nt * 16 + (lane & 15);
  int k0 = kt * 32 + (lane >> 4) * 8;
  bf8_t v;
#pragma unroll
  for (int j = 0; j < 8; ++j) {
    int k = k0 + j;
    v[j] = (k < KDIM) ? f2bf(W[(size_t)k * N + n]) : (short)0;
  }
  *(bf8_t*)(outp + ((size_t)tile * 64 + lane) * 8) = v;
}

__device__ void pack_dispatch(int blk, int lane,
    const float* d0W1, short* d0W1p, const float* d0W2, short* d0W2p,
    const float* d1W1, short* d1W1p, const float* d1W2, short* d1W2p,
    const float* d2W1, short* d2W1p, const float* d2W2, short* d2W2p,
    const float* u2W, short* u2Wp, const float* fW1, short* fW1p,
    const float* fW2, short* fW2p,
    const float* u0W, short* u0Wp, const float* u1W, short* u1Wp,
    const float* pos, float* posOut) {
  if      (blk < 8)    pack_tile_rt(d0W1, d0W1p, 6, 128, blk, lane);
  else if (blk < 40)   pack_tile_rt(d0W2, d0W2p, 128, 128, blk - 8, lane);
  else if (blk < 120)  pack_tile_rt(d1W1, d1W1p, 131, 256, blk - 40, lane);
  else if (blk < 248)  pack_tile_rt(d1W2, d1W2p, 256, 256, blk - 120, lane);
  else if (blk < 536)  pack_tile_rt(d2W1, d2W1p, 259, 512, blk - 248, lane);
  else if (blk < 1048) pack_tile_rt(d2W2, d2W2p, 512, 512, blk - 536, lane);
  else if (blk < 1088) pack_tile_rt(u2W, u2Wp, 134, 128, blk - 1048, lane);
  else if (blk < 1120) pack_tile_rt(fW1, fW1p, 128, 128, blk - 1088, lane);
  else if (blk < 1152) pack_tile_rt(fW2, fW2p, 128, 128, blk - 1120, lane);
  else if (blk < 1536) pack_tile_rt(u0W, u0Wp, 768, 256, blk - 1152, lane);
  else if (blk < 1632) pack_tile_rt(u1W, u1Wp, 384, 128, blk - 1536, lane);
  else {
    int base = (blk - 1632) * 256;  // 384 x 256 = 98304 = BATCH*NFULL*3
#pragma unroll
    for (int j = 0; j < 4; ++j) {
      int i = base + lane + j * 64;
      posOut[i] = pos[i];
    }
  }
}

// ---- fused pre-kernel: grid builds + packing + brute kNN (idx2, idxu0) ----
// bx<12: grid build; 12..515: packing; 516..579: idx2; 580..707: idxu0.
__global__ __launch_bounds__(256) void pre_kernel(
    const float* __restrict__ pos, float4* __restrict__ sortedA,
    int* __restrict__ csA, float4* __restrict__ sortedB, int* __restrict__ csB,
    float4* __restrict__ sortedC, int* __restrict__ csC,
    const float* d0W1, short* d0W1p, const float* d0W2, short* d0W2p,
    const float* d1W1, short* d1W1p, const float* d1W2, short* d1W2p,
    const float* d2W1, short* d2W1p, const float* d2W2, short* d2W2p,
    const float* u2W, short* u2Wp, const float* fW1, short* fW1p,
    const float* fW2, short* fW2p,
    const float* u0W, short* u0Wp, const float* u1W, short* u1Wp,
    float* posOut,
    int* __restrict__ idx2, int* __restrict__ idxu0, float* __restrict__ d2u0) {
  __shared__ int cnt[4096];
  __shared__ int partial[256];
  int bx = blockIdx.x, t = threadIdx.x;
  if (bx >= 580) {          // idxu0: 512 q over 128 pts (brute K=3)
    int i = bx - 580;
    knn_brute3_dev(i & 31, i >> 5, pos, 128, 512, idxu0, d2u0);
    return;
  }
  if (bx >= 516) {          // idx2: 128 q over 512 pts (brute K=16)
    int i = bx - 516;
    knn_brute16_g32_dev(i & 15, i >> 4, pos, 512, 128, idx2);
    return;
  }
  if (bx >= 12) {
    int tt = (bx - 12) * 4 + (t >> 6);
    pack_dispatch(tt, t & 63,
        d0W1, d0W1p, d0W2, d0W2p, d1W1, d1W1p, d1W2, d1W2p,
        d2W1, d2W1p, d2W2, d2W2p, u2W, u2Wp, fW1, fW1p, fW2, fW2p,
        u0W, u0Wp, u1W, u1Wp, pos, posOut);
    return;
  }
  int which = bx >> 2, b = bx & 3;
  int NREF = (which == 0) ? 8192 : (which == 1) ? 2048 : 512;
  int GR = (which == 0) ? 16 : 8;
  int NC = GR * GR * GR;
  float4* sorted = ((which == 0) ? sortedA : (which == 1) ? sortedB : sortedC)
                   + (size_t)b * NREF;
  int* cs = ((which == 0) ? csA + b * 4097 : (which == 1) ? csB + b * 513
                                           : csC + b * 513);
  const float* pb = pos + (size_t)b * NFULL * 3;
  for (int c = t; c < NC; c += 256) cnt[c] = 0;
  __syncthreads();
  for (int p = t; p < NREF; p += 256) {
    float x = pb[p * 3 + 0], y = pb[p * 3 + 1], z = pb[p * 3 + 2];
    int cx = min(max((int)(x * GR), 0), GR - 1);
    int cy = min(max((int)(y * GR), 0), GR - 1);
    int cz = min(max((int)(z * GR), 0), GR - 1);
    atomicAdd(&cnt[(cz * GR + cy) * GR + cx], 1);
  }
  __syncthreads();
  int chunk = (NC + 255) / 256;
  int s = 0;
  for (int i = 0; i < chunk; ++i) {
    int c = t * chunk + i;
    if (c < NC) s += cnt[c];
  }
  partial[t] = s;
  __syncthreads();
  if (t == 0) {
    int run = 0;
    for (int i = 0; i < 256; ++i) { int v = partial[i]; partial[i] = run; run += v; }
  }
  __syncthreads();
  int run = partial[t];
  for (int i = 0; i < chunk; ++i) {
    int c = t * chunk + i;
    if (c < NC) { int v = cnt[c]; cnt[c] = run; run += v; }
  }
  __syncthreads();
  for (int c = t; c < NC; c += 256) cs[c] = cnt[c];
  if (t == 0) cs[NC] = NREF;
  __syncthreads();
  for (int p = t; p < NREF; p += 256) {
    float x = pb[p * 3 + 0], y = pb[p * 3 + 1], z = pb[p * 3 + 2];
    int cx = min(max((int)(x * GR), 0), GR - 1);
    int cy = min(max((int)(y * GR), 0), GR - 1);
    int cz = min(max((int)(z * GR), 0), GR - 1);
    int slot = atomicAdd(&cnt[(cz * GR + cy) * GR + cx], 1);
    sorted[slot] = make_float4(x, y, z, __uint_as_float((u32)p));
  }
}

// ---------------- kNN critical path: idx1 (heaviest) + idx0 ----------------
__global__ __launch_bounds__(256) void knn16_kernel(
    const float* __restrict__ pos,
    const float4* __restrict__ sortedA, const int* __restrict__ csA,
    const float4* __restrict__ sortedB, const int* __restrict__ csB,
    int* __restrict__ idx0, int* __restrict__ idx1) {
  int bx = blockIdx.x, b = blockIdx.y;
  if (bx < 64)   // idx1: 512 q over 2048 pts
    knn_grid16_g32_dev<8, 2, 2048>(bx, b, pos, sortedB, csB, 513, 512, idx1);
  else           // idx0: 2048 q over 8192 pts
    knn_grid16_g32_dev<16, 2, 8192>(bx - 64, b, pos, sortedA, csA, 4097, 2048, idx0);
}

// ----------------------------------------------------- down MLP (MFMA) -----
template<int FEAT, int CIN, int CHID, int FPAD, int QB, int WAVES>
__device__ void down_mfma_body(int bxx, int b,
    const float* __restrict__ pos, const float* __restrict__ xin,
    const int* __restrict__ idx,
    const short* __restrict__ W1p, const float* __restrict__ b1,
    const short* __restrict__ W2p, const float* __restrict__ b2,
    float* __restrict__ out, int n, int nprev) {
  const int KT1 = FPAD / 32, NT1 = CHID / 16;
  const int KT2 = CHID / 32, NT2 = CHID / 16;
  __shared__ short sFeat[QB][16][FPAD + 8];
  __shared__ short sH1[QB][16][CHID + 8];
  __shared__ int sIdx[QB][16];
  __shared__ float sCtr[QB][3];
  int q0 = bxx * QB;
  int t = threadIdx.x;
  int lane = t & 63, wv = t >> 6;
  const float* pb = pos + (size_t)b * NFULL * 3;
  const float* xb = xin + (size_t)b * nprev * CIN;
  if (t < QB * 16)
    sIdx[t >> 4][t & 15] = idx[((size_t)b * n + q0 + (t >> 4)) * 16 + (t & 15)];
  if (t < QB * 3) sCtr[t / 3][t % 3] = pb[(q0 + t / 3) * 3 + (t % 3)];
  __syncthreads();
  for (int e = t; e < QB * 16 * FPAD; e += 64 * WAVES) {
    int k = e / FPAD, c = e - k * FPAD;
    int qq = k >> 4, kk = k & 15;
    float v = 0.f;
    if (c < 3) v = pb[sIdx[qq][kk] * 3 + c] - sCtr[qq][c];
    else if (c < FEAT) v = xb[(size_t)sIdx[qq][kk] * CIN + (c - 3)];
    sFeat[qq][kk][c] = f2bf(v);
  }
  __syncthreads();

  int col = lane & 15, quad = lane >> 4;
  const bf8_t* W1t = (const bf8_t*)W1p;
  for (int nt = 2 * wv; nt < NT1; nt += 2 * WAVES) {
    f4_t acc[QB][2];
    float bb0 = b1[nt * 16 + col], bb1 = b1[nt * 16 + 16 + col];
#pragma unroll
    for (int q = 0; q < QB; ++q) {
      acc[q][0] = {bb0, bb0, bb0, bb0};
      acc[q][1] = {bb1, bb1, bb1, bb1};
    }
#pragma unroll
    for (int kt = 0; kt < KT1; ++kt) {
      bf8_t bf0 = W1t[(kt * NT1 + nt) * 64 + lane];
      bf8_t bf1 = W1t[(kt * NT1 + nt + 1) * 64 + lane];
#pragma unroll
      for (int q = 0; q < QB; ++q) {
        bf8_t a = *(const bf8_t*)&sFeat[q][col][kt * 32 + quad * 8];
        acc[q][0] = __builtin_amdgcn_mfma_f32_16x16x32_bf16(a, bf0, acc[q][0], 0, 0, 0);
        acc[q][1] = __builtin_amdgcn_mfma_f32_16x16x32_bf16(a, bf1, acc[q][1], 0, 0, 0);
      }
    }
#pragma unroll
    for (int q = 0; q < QB; ++q)
#pragma unroll
      for (int r = 0; r < 4; ++r) {
        sH1[q][quad * 4 + r][nt * 16 + col] = f2bf(fmaxf(acc[q][0][r], 0.f));
        sH1[q][quad * 4 + r][nt * 16 + 16 + col] = f2bf(fmaxf(acc[q][1][r], 0.f));
      }
  }
  __syncthreads();

  const bf8_t* W2t = (const bf8_t*)W2p;
  for (int nt = 2 * wv; nt < NT2; nt += 2 * WAVES) {
    f4_t acc[QB][2];
    float bb0 = b2[nt * 16 + col], bb1 = b2[nt * 16 + 16 + col];
#pragma unroll
    for (int q = 0; q < QB; ++q) {
      acc[q][0] = {bb0, bb0, bb0, bb0};
      acc[q][1] = {bb1, bb1, bb1, bb1};
    }
#pragma unroll
    for (int kt = 0; kt < KT2; ++kt) {
      bf8_t bf0 = W2t[(kt * NT2 + nt) * 64 + lane];
      bf8_t bf1 = W2t[(kt * NT2 + nt + 1) * 64 + lane];
#pragma unroll
      for (int q = 0; q < QB; ++q) {
        bf8_t a = *(const bf8_t*)&sH1[q][col][kt * 32 + quad * 8];
        acc[q][0] = __builtin_amdgcn_mfma_f32_16x16x32_bf16(a, bf0, acc[q][0], 0, 0, 0);
        acc[q][1] = __builtin_amdgcn_mfma_f32_16x16x32_bf16(a, bf1, acc[q][1], 0, 0, 0);
      }
    }
#pragma unroll
    for (int q = 0; q < QB; ++q) {
      float m0 = fmaxf(fmaxf(acc[q][0][0], acc[q][0][1]), fmaxf(acc[q][0][2], acc[q][0][3]));
      float m1 = fmaxf(fmaxf(acc[q][1][0], acc[q][1][1]), fmaxf(acc[q][1][2], acc[q][1][3]));
      m0 = fmaxf(m0, __shfl_xor(m0, 16, 64));
      m0 = fmaxf(m0, __shfl_xor(m0, 32, 64));
      m1 = fmaxf(m1, __shfl_xor(m1, 16, 64));
      m1 = fmaxf(m1, __shfl_xor(m1, 32, 64));
      if (lane < 16) {
        float* ob = out + ((size_t)b * n + q0 + q) * CHID;
        ob[nt * 16 + lane] = m0;
        ob[nt * 16 + 16 + lane] = m1;
      }
    }
  }
}

template<int FEAT, int CIN, int CHID, int FPAD, int QB, int WAVES>
__global__ __launch_bounds__(64 * WAVES) void down_mfma_kernel(
    const float* __restrict__ pos, const float* __restrict__ xin,
    const int* __restrict__ idx,
    const short* __restrict__ W1p, const float* __restrict__ b1,
    const short* __restrict__ W2p, const float* __restrict__ b2,
    float* __restrict__ out, int n, int nprev) {
  down_mfma_body<FEAT, CIN, CHID, FPAD, QB, WAVES>(blockIdx.x, blockIdx.y,
      pos, xin, idx, W1p, b1, W2p, b2, out, n, nprev);
}

// ------------- fused: down0 MLP + K=3 kNN (idxu1, idxu2) -------------------
// K=3 results consumed 4+ kernels later; hide their latency under down0 MFMA.
__global__ __launch_bounds__(256) void down0_knn3_kernel(
    const float* __restrict__ pos, const float* __restrict__ xin,
    const int* __restrict__ idx,
    const short* __restrict__ W1p, const float* __restrict__ b1,
    const short* __restrict__ W2p, const float* __restrict__ b2,
    float* __restrict__ out,
    const float4* __restrict__ sortedB, const int* __restrict__ csB,
    const float4* __restrict__ sortedC, const int* __restrict__ csC,
    int* __restrict__ idxu1, float* __restrict__ d2u1,
    int* __restrict__ idxu2, float* __restrict__ d2u2) {
  int bx = blockIdx.x, b = blockIdx.y;
  if (bx < 512)        // down0 MLP: 2048 q, QB=4
    down_mfma_body<6, 3, 128, 32, 4, 4>(bx, b, pos, xin, idx,
        W1p, b1, W2p, b2, out, 2048, 8192);
  else if (bx < 1024)  // idxu2: 8192 q over 2048 pts, K=3
    knn_grid_flat3_dev<8, 1, 2048>(bx - 512, b, pos, sortedB, csB, 513, 8192, idxu2, d2u2);
  else                 // idxu1: 2048 q over 512 pts, K=3 (gridC)
    knn_grid_flat32_3_dev<8, 2, 512>(bx - 1024, b, pos, sortedC, csC, 513, 2048, idxu1, d2u1);
}

// -------------------------------------------- up MLP (bf16 MFMA version) ---
template<int CIN, int CPRV, int COUT, int WPB>
__global__ __launch_bounds__(64 * WPB) void up_mfma_kernel(
    const float* __restrict__ xc, int ncoarse,
    const int* __restrict__ idx3, const float* __restrict__ d23,
    const float* __restrict__ prv, const short* __restrict__ Wp,
    const float* __restrict__ bvec, float* __restrict__ out, int m) {
  const int CTOT = CIN + CPRV;
  const int KT = CTOT / 32, NT = COUT / 16;
  __shared__ short sA[16][CTOT + 8];
  __shared__ float sWt[16][3];
  __shared__ int   sIt[16][3];
  int b = blockIdx.y, q0 = blockIdx.x * 16, t = threadIdx.x;
  int lane = t & 63, wv = t >> 6;
  if (t < 16) {
    size_t base = ((size_t)b * m + q0 + t) * 3;
    float d0 = d23[base + 0], d1 = d23[base + 1], d2v = d23[base + 2];
    float w0 = 1.f / (d0 + 1e-8f), w1 = 1.f / (d1 + 1e-8f), w2 = 1.f / (d2v + 1e-8f);
    float s = w0 + w1 + w2;
    sWt[t][0] = w0 / s; sWt[t][1] = w1 / s; sWt[t][2] = w2 / s;
    sIt[t][0] = idx3[base + 0]; sIt[t][1] = idx3[base + 1]; sIt[t][2] = idx3[base + 2];
  }
  __syncthreads();
  const float* xb = xc + (size_t)b * ncoarse * CIN;
  const float* pvb = prv + ((size_t)b * m + q0) * CPRV;
  for (int e = t; e < 16 * CIN; e += 64 * WPB) {
    int p = e / CIN, c = e % CIN;
    float v = sWt[p][0] * xb[(size_t)sIt[p][0] * CIN + c]
            + sWt[p][1] * xb[(size_t)sIt[p][1] * CIN + c]
            + sWt[p][2] * xb[(size_t)sIt[p][2] * CIN + c];
    sA[p][c] = f2bf(v);
  }
  for (int e = t; e < 16 * CPRV; e += 64 * WPB) {
    int p = e / CPRV, c = e % CPRV;
    sA[p][CIN + c] = f2bf(pvb[(size_t)p * CPRV + c]);
  }
  __syncthreads();
  int col = lane & 15, quad = lane >> 4;
  const bf8_t* Wt = (const bf8_t*)Wp;
  float* ob = out + ((size_t)b * m + q0) * COUT;
  for (int nt = 2 * wv; nt < NT; nt += 2 * WPB) {
    float bb0 = bvec[nt * 16 + col], bb1 = bvec[nt * 16 + 16 + col];
    f4_t acc0 = {bb0, bb0, bb0, bb0}, acc1 = {bb1, bb1, bb1, bb1};
#pragma unroll
    for (int kt = 0; kt < KT; ++kt) {
      bf8_t a = *(const bf8_t*)&sA[col][kt * 32 + quad * 8];
      bf8_t bf0 = Wt[(kt * NT + nt) * 64 + lane];
      bf8_t bf1 = Wt[(kt * NT + nt + 1) * 64 + lane];
      acc0 = __builtin_amdgcn_mfma_f32_16x16x32_bf16(a, bf0, acc0, 0, 0, 0);
      acc1 = __builtin_amdgcn_mfma_f32_16x16x32_bf16(a, bf1, acc1, 0, 0, 0);
    }
#pragma unroll
    for (int r = 0; r < 4; ++r) {
      ob[(size_t)(quad * 4 + r) * COUT + nt * 16 + col] = fmaxf(acc0[r], 0.f);
      ob[(size_t)(quad * 4 + r) * COUT + nt * 16 + 16 + col] = fmaxf(acc1[r], 0.f);
    }
  }
}

// ------------------------------------- fused up2 + final MLP (bf16 MFMA) ---
__global__ __launch_bounds__(128) void up2f_mfma_kernel(
    const float* __restrict__ xc,
    const int* __restrict__ idx3, const float* __restrict__ d23,
    const float* __restrict__ x0, const float* __restrict__ pos0,
    const short* __restrict__ u2Wp, const float* __restrict__ u2b,
    const short* __restrict__ fW1p, const float* __restrict__ fb1,
    const short* __restrict__ fW2p, const float* __restrict__ fb2,
    float* __restrict__ out) {
  __shared__ short sA[16][168];
  __shared__ short sB[16][136];
  __shared__ float sWt[16][3];
  __shared__ int   sIt[16][3];
  int b = blockIdx.y, q0 = blockIdx.x * 16, t = threadIdx.x;
  int lane = t & 63, wv = t >> 6;
  if (t < 16) {
    size_t base = ((size_t)b * NFULL + q0 + t) * 3;
    float d0 = d23[base + 0], d1 = d23[base + 1], d2v = d23[base + 2];
    float w0 = 1.f / (d0 + 1e-8f), w1 = 1.f / (d1 + 1e-8f), w2 = 1.f / (d2v + 1e-8f);
    float s = w0 + w1 + w2;
    sWt[t][0] = w0 / s; sWt[t][1] = w1 / s; sWt[t][2] = w2 / s;
    sIt[t][0] = idx3[base + 0]; sIt[t][1] = idx3[base + 1]; sIt[t][2] = idx3[base + 2];
  }
  __syncthreads();
  const float* xb = xc + (size_t)b * 2048 * 128;
#pragma unroll
  for (int p = 0; p < 16; ++p) {
    float v = sWt[p][0] * xb[(size_t)sIt[p][0] * 128 + t]
            + sWt[p][1] * xb[(size_t)sIt[p][1] * 128 + t]
            + sWt[p][2] * xb[(size_t)sIt[p][2] * 128 + t];
    sA[p][t] = f2bf(v);
  }
  for (int e = t; e < 16 * 32; e += 128) {
    int p = e / 32, c = 128 + (e % 32);
    float v = 0.f;
    if (c < 131) v = x0[((size_t)b * NFULL + q0 + p) * 3 + (c - 128)];
    else if (c < 134) v = pos0[((size_t)b * NFULL + q0 + p) * 3 + (c - 131)];
    sA[p][c] = f2bf(v);
  }
  __syncthreads();
  int col = lane & 15, quad = lane >> 4;

  bf8_t a1[5];
#pragma unroll
  for (int kt = 0; kt < 5; ++kt)
    a1[kt] = *(const bf8_t*)&sA[col][kt * 32 + quad * 8];
  const bf8_t* W1t = (const bf8_t*)u2Wp;
  for (int nt = 2 * wv; nt < 8; nt += 4) {
    float bb0 = u2b[nt * 16 + col], bb1 = u2b[nt * 16 + 16 + col];
    f4_t acc0 = {bb0, bb0, bb0, bb0}, acc1 = {bb1, bb1, bb1, bb1};
#pragma unroll
    for (int kt = 0; kt < 5; ++kt) {
      bf8_t bf0 = W1t[(kt * 8 + nt) * 64 + lane];
      bf8_t bf1 = W1t[(kt * 8 + nt + 1) * 64 + lane];
      acc0 = __builtin_amdgcn_mfma_f32_16x16x32_bf16(a1[kt], bf0, acc0, 0, 0, 0);
      acc1 = __builtin_amdgcn_mfma_f32_16x16x32_bf16(a1[kt], bf1, acc1, 0, 0, 0);
    }
#pragma unroll
    for (int r = 0; r < 4; ++r) {
      sB[quad * 4 + r][nt * 16 + col] = f2bf(fmaxf(acc0[r], 0.f));
      sB[quad * 4 + r][nt * 16 + 16 + col] = f2bf(fmaxf(acc1[r], 0.f));
    }
  }
  __syncthreads();

  bf8_t a2[4];
#pragma unroll
  for (int kt = 0; kt < 4; ++kt)
    a2[kt] = *(const bf8_t*)&sB[col][kt * 32 + quad * 8];
  const bf8_t* W2t = (const bf8_t*)fW1p;
  for (int nt = 2 * wv; nt < 8; nt += 4) {
    float bb0 = fb1[nt * 16 + col], bb1 = fb1[nt * 16 + 16 + col];
    f4_t acc0 = {bb0, bb0, bb0, bb0}, acc1 = {bb1, bb1, bb1, bb1};
#pragma unroll
    for (int kt = 0; kt < 4; ++kt) {
      bf8_t bf0 = W2t[(kt * 8 + nt) * 64 + lane];
      bf8_t bf1 = W2t[(kt * 8 + nt + 1) * 64 + lane];
      acc0 = __builtin_amdgcn_mfma_f32_16x16x32_bf16(a2[kt], bf0, acc0, 0, 0, 0);
      acc1 = __builtin_amdgcn_mfma_f32_16x16x32_bf16(a2[kt], bf1, acc1, 0, 0, 0);
    }
#pragma unroll
    for (int r = 0; r < 4; ++r) {
      sA[quad * 4 + r][nt * 16 + col] = f2bf(fmaxf(acc0[r], 0.f));
      sA[quad * 4 + r][nt * 16 + 16 + col] = f2bf(fmaxf(acc1[r], 0.f));
    }
  }
  __syncthreads();

  bf8_t a3[4];
#pragma unroll
  for (int kt = 0; kt < 4; ++kt)
    a3[kt] = *(const bf8_t*)&sA[col][kt * 32 + quad * 8];
  const bf8_t* W3t = (const bf8_t*)fW2p;
  float* ob = out + ((size_t)b * NFULL + q0) * 128;
  for (int nt = 2 * wv; nt < 8; nt += 4) {
    float bb0 = fb2[nt * 16 + col], bb1 = fb2[nt * 16 + 16 + col];
    f4_t acc0 = {bb0, bb0, bb0, bb0}, acc1 = {bb1, bb1, bb1, bb1};
#pragma unroll
    for (int kt = 0; kt < 4; ++kt) {
      bf8_t bf0 = W3t[(kt * 8 + nt) * 64 + lane];
      bf8_t bf1 = W3t[(kt * 8 + nt + 1) * 64 + lane];
      acc0 = __builtin_amdgcn_mfma_f32_16x16x32_bf16(a3[kt], bf0, acc0, 0, 0, 0);
      acc1 = __builtin_amdgcn_mfma_f32_16x16x32_bf16(a3[kt], bf1, acc1, 0, 0, 0);
    }
#pragma unroll
    for (int r = 0; r < 4; ++r) {
      ob[(size_t)(quad * 4 + r) * 128 + nt * 16 + col] = acc0[r];
      ob[(size_t)(quad * 4 + r) * 128 + nt * 16 + 16 + col] = acc1[r];
    }
  }
}

// ------------------------------------------------------------------ launch -
extern "C" void kernel_launch(void* const* d_in, const int* in_sizes, int n_in,
                              void* d_out, int out_size, void* d_ws, size_t ws_size,
                              hipStream_t stream) {
  const float* x    = (const float*)d_in[0];
  const float* pos  = (const float*)d_in[1];
  const float* d0W1 = (const float*)d_in[2];
  const float* d0b1 = (const float*)d_in[3];
  const float* d0W2 = (const float*)d_in[4];
  const float* d0b2 = (const float*)d_in[5];
  const float* d1W1 = (const float*)d_in[6];
  const float* d1b1 = (const float*)d_in[7];
  const float* d1W2 = (const float*)d_in[8];
  const float* d1b2 = (const float*)d_in[9];
  const float* d2W1 = (const float*)d_in[10];
  const float* d2b1 = (const float*)d_in[11];
  const float* d2W2 = (const float*)d_in[12];
  const float* d2b2 = (const float*)d_in[13];
  const float* u0W  = (const float*)d_in[14];
  const float* u0b  = (const float*)d_in[15];
  const float* u1W  = (const float*)d_in[16];
  const float* u1b  = (const float*)d_in[17];
  const float* u2W  = (const float*)d_in[18];
  const float* u2b  = (const float*)d_in[19];
  const float* fW1  = (const float*)d_in[20];
  const float* fb1  = (const float*)d_in[21];
  const float* fW2  = (const float*)d_in[22];
  const float* fb2  = (const float*)d_in[23];

  char* ws = (char*)d_ws;
  float* x1    = (float*)(ws + 0);
  float* x2    = (float*)(ws + 4194304);
  float* x3    = (float*)(ws + 6291456);
  float* up0o  = (float*)(ws + 7340032);
  float* up1o  = (float*)(ws + 9437184);
  int*   idx0  = (int*)  (ws + 13631488);
  int*   idx1  = (int*)  (ws + 14155776);
  int*   idx2  = (int*)  (ws + 14286848);
  float4* sortedC = (float4*)(ws + 14319616); // 4*512*16 = 32768
  int*    csC     = (int*)   (ws + 14352384); // 4*513*4  = 8208
  int*   idxu0 = (int*)  (ws + 14843904);
  float* d2u0  = (float*)(ws + 14868480);
  int*   idxu1 = (int*)  (ws + 14893056);
  float* d2u1  = (float*)(ws + 14991360);
  int*   idxu2 = (int*)  (ws + 15089664);
  float* d2u2  = (float*)(ws + 15482880);
  short* d1W1p = (short*)(ws + 15876096);
  short* d1W2p = (short*)(ws + 15958016);
  short* d2W1p = (short*)(ws + 16089088);
  short* d2W2p = (short*)(ws + 16384000);
  short* d0W1p = (short*)(ws + 16908288);
  short* d0W2p = (short*)(ws + 16916480);
  float4* sortedA = (float4*)(ws + 16949248);  // 4*8192*16 = 524288
  int*    csA     = (int*)   (ws + 17473536);  // 4*4097*4  = 65552
  float4* sortedB = (float4*)(ws + 17539136);  // 4*2048*16 = 131072
  int*    csB     = (int*)   (ws + 17670208);  // 4*513*4   = 8208
  short* u2Wp  = (short*)(ws + 17697920);
  short* fW1p  = (short*)(ws + 17738880);
  short* fW2p  = (short*)(ws + 17771648);

  float* out = (float*)d_out;
  // Packed u0W/u1W live in the d_out main region: it is dead until the final
  // up2f_mfma_kernel writes it, and both are fully consumed before that.
  short* u0Wp = (short*)out;                       // 768*256*2 = 393216 B
  short* u1Wp = (short*)(out + 98304);             // 384*128*2 =  98304 B

  // ---- pre: grids + packing + pos copy + brute kNN (idx2, idxu0) ----
  pre_kernel<<<dim3(708), 256, 0, stream>>>(
      pos, sortedA, csA, sortedB, csB, sortedC, csC,
      d0W1, d0W1p, d0W2, d0W2p, d1W1, d1W1p, d1W2, d1W2p,
      d2W1, d2W1p, d2W2, d2W2p, u2W, u2Wp, fW1, fW1p, fW2, fW2p,
      u0W, u0Wp, u1W, u1Wp,
      out + (size_t)BATCH * NFULL * 128,
      idx2, idxu0, d2u0);

  // ---- kNN critical path: idx1 + idx0 only ----
  knn16_kernel<<<dim3(320, BATCH), 256, 0, stream>>>(
      pos, sortedA, csA, sortedB, csB, idx0, idx1);

  // ---- down0 + hidden K=3 kNN (idxu1, idxu2) ----
  down0_knn3_kernel<<<dim3(1152, BATCH), 256, 0, stream>>>(
      pos, x, idx0, d0W1p, d0b1, d0W2p, d0b2, x1,
      sortedB, csB, sortedC, csC, idxu1, d2u1, idxu2, d2u2);

  // ---- rest of down path ----
  down_mfma_kernel<131, 128, 256, 160, 4, 8><<<dim3(128, BATCH), 512, 0, stream>>>(
      pos, x1, idx1, d1W1p, d1b1, d1W2p, d1b2, x2, 512, 2048);
  down_mfma_kernel<259, 256, 512, 288, 2, 8><<<dim3(64, BATCH), 512, 0, stream>>>(
      pos, x2, idx2, d2W1p, d2b1, d2W2p, d2b2, x3, 128, 512);

  // ---- up path ----
  up_mfma_kernel<512, 256, 256, 4><<<dim3(32, BATCH), 256, 0, stream>>>(
      x3, 128, idxu0, d2u0, x2, u0Wp, u0b, up0o, 512);
  up_mfma_kernel<256, 128, 128, 2><<<dim3(128, BATCH), 128, 0, stream>>>(
      up0o, 512, idxu1, d2u1, x1, u1Wp, u1b, up1o, 2048);
  up2f_mfma_kernel<<<dim3(512, BATCH), 128, 0, stream>>>(
      up1o, idxu2, d2u2, x, pos, u2Wp, u2b, fW1p, fb1, fW2p, fb2, out);
}

// Round 10
// 289.734 us; speedup vs baseline: 1.0129x; 1.0129x over previous
//
#include <hip/hip_runtime.h>

#define NFULL 8192
#define BATCH 4

typedef unsigned long long u64;
typedef unsigned int u32;
typedef __attribute__((ext_vector_type(8))) short bf8_t;   // 8 bf16 (4 VGPRs)
typedef __attribute__((ext_vector_type(4))) float f4_t;    // MFMA C/D

__device__ __forceinline__ u32 fbias(float f) {
  u32 u = __float_as_uint(f);
  return (u & 0x80000000u) ? ~u : (u | 0x80000000u);
}
__device__ __forceinline__ float funbias(u32 b) {
  u32 u = (b & 0x80000000u) ? (b & 0x7fffffffu) : ~b;
  return __uint_as_float(u);
}
__device__ __forceinline__ short f2bf(float f) {
  u32 u = __float_as_uint(f);
  u32 r = u + 0x7FFFu + ((u >> 16) & 1u);
  return (short)(r >> 16);
}

// ================= K=16 window-insert primitives ===========================
// Window of 16 sorted keys replicated in each 16-lane sub-group; candidate
// broadcast across the given width; insertion shift stays in the 16-group.
__device__ __forceinline__ void group_insert_g32(u32 m32, u64 ck, int slot16,
                                                 u64& val, u64& tau) {
  if (m32) {
    while (m32) {
      int src = __ffs(m32) - 1;
      m32 &= m32 - 1;
      u64 c = __shfl((unsigned long long)ck, src, 32);
      u64 prev = __shfl_up((unsigned long long)val, 1, 16);
      if (slot16 == 0) prev = 0ull;
      val = (val <= c) ? val : ((prev <= c) ? c : prev);
    }
    tau = __shfl((unsigned long long)val, 15, 16);
  }
}

__device__ __forceinline__ void group_insert_g64(u64 m64, u64 ck, int slot16,
                                                 u64& val, u64& tau) {
  if (m64) {
    while (m64) {
      int src = __ffsll((unsigned long long)m64) - 1;
      m64 &= m64 - 1;
      u64 c = __shfl((unsigned long long)ck, src, 64);
      u64 prev = __shfl_up((unsigned long long)val, 1, 16);
      if (slot16 == 0) prev = 0ull;
      val = (val <= c) ? val : ((prev <= c) ? c : prev);
    }
    tau = __shfl((unsigned long long)val, 15, 16);
  }
}

// Round-1 bulk build: bitonic sort of the first 32 candidates (g32 paths).
__device__ __forceinline__ void first_round_sort32(u64 ck, int gl,
                                                   u64& val, u64& tau) {
  u64 v = ck;
#pragma unroll
  for (int size = 2; size <= 32; size <<= 1) {
#pragma unroll
    for (int stride = size >> 1; stride > 0; stride >>= 1) {
      u64 other = __shfl_xor((unsigned long long)v, stride, 32);
      bool ddd = ((gl & size) == 0);
      bool takeMin = (((gl & stride) == 0) == ddd);
      u64 mn = (v <= other) ? v : other;
      u64 mx = (v <= other) ? other : v;
      v = takeMin ? mn : mx;
    }
  }
  val = __shfl((unsigned long long)v, gl & 15, 32);
  tau = __shfl((unsigned long long)val, 15, 16);
}

// Round-1 bulk build: 21-stage bitonic sort of first 64 candidates (g64).
__device__ __forceinline__ void first_round_sort64(u64 ck, int gl,
                                                   u64& val, u64& tau) {
  u64 v = ck;
#pragma unroll
  for (int size = 2; size <= 64; size <<= 1) {
#pragma unroll
    for (int stride = size >> 1; stride > 0; stride >>= 1) {
      u64 other = __shfl_xor((unsigned long long)v, stride, 64);
      bool ddd = ((gl & size) == 0);
      bool takeMin = (((gl & stride) == 0) == ddd);
      u64 mn = (v <= other) ? v : other;
      u64 mx = (v <= other) ? other : v;
      v = takeMin ? mn : mx;
    }
  }
  val = __shfl((unsigned long long)v, gl & 15, 64);
  tau = __shfl((unsigned long long)val, 15, 16);
}

__device__ __forceinline__ void scan_range_g64(const float4* __restrict__ sb,
    int s, int e, float qx, float qy, float qz, float qq,
    int lane, int slot16, u64& val, u64& tau) {
  for (int t0 = s; t0 < e; t0 += 64) {
    int j = t0 + lane;
    u64 ck = ~0ull;
    if (j < e) {
      float4 P = sb[j];
      float rr = P.x * P.x + P.y * P.y + P.z * P.z;
      float d2 = qq + rr - 2.0f * (qx * P.x + qy * P.y + qz * P.z);
      ck = ((u64)fbias(d2) << 32) | (u32)__float_as_uint(P.w);
    }
    u64 m64 = __ballot(ck < tau);
    group_insert_g64(m64, ck, slot16, val, tau);
  }
}

// Exactness: after scanning box B, if the Kth smallest d2 is strictly less
// than the squared distance to the nearest NON-clipped face of B, no outside
// point can enter the top-K. Ring expansion scans box(R+1)\box(R) exactly
// once per point; unique u64 keys keep tie-breaking identical to reference.
template<int GR, int R, int NREF>
__device__ __forceinline__ void knn_tail16_g64(
    const float4* __restrict__ sb, const int* __restrict__ cs,
    float qx, float qy, float qz, float qq,
    int ix, int iy, int iz, int x0, int x1, int y0, int y1, int z0, int z1,
    int lane, int slot16, u64& val, u64& tau) {
  const float h = 1.0f / GR;
  float m = 1e30f;
  if (x0 > 0)      m = fminf(m, qx - x0 * h);
  if (x1 < GR - 1) m = fminf(m, (x1 + 1) * h - qx);
  if (y0 > 0)      m = fminf(m, qy - y0 * h);
  if (y1 < GR - 1) m = fminf(m, (y1 + 1) * h - qy);
  if (z0 > 0)      m = fminf(m, qz - z0 * h);
  if (z1 < GR - 1) m = fminf(m, (z1 + 1) * h - qz);
  float bound = m * m;
  float kth_d2 = funbias((u32)(tau >> 32));
  if (!(kth_d2 < bound)) {  // wave-uniform; rare
    int X0 = max(ix - (R + 1), 0), X1 = min(ix + (R + 1), GR - 1);
    int Y0 = max(iy - (R + 1), 0), Y1 = min(iy + (R + 1), GR - 1);
    int Z0 = max(iz - (R + 1), 0), Z1 = min(iz + (R + 1), GR - 1);
    int NY2 = Y1 - Y0 + 1;
    int nrow2 = (Z1 - Z0 + 1) * NY2;
    for (int rr2 = 0; rr2 < nrow2; ++rr2) {
      int zz = Z0 + rr2 / NY2, yy = Y0 + rr2 % NY2;
      int c0 = (zz * GR + yy) * GR;
      bool mid = (zz >= z0 && zz <= z1 && yy >= y0 && yy <= y1);
      int s1 = cs[c0 + X0];
      int e1 = mid ? cs[c0 + x0] : cs[c0 + X1 + 1];
      scan_range_g64(sb, s1, e1, qx, qy, qz, qq, lane, slot16, val, tau);
      if (mid) {
        int s2 = cs[c0 + x1 + 1];
        int e2 = cs[c0 + X1 + 1];
        scan_range_g64(sb, s2, e2, qx, qy, qz, qq, lane, slot16, val, tau);
      }
    }
    x0 = X0; x1 = X1; y0 = Y0; y1 = Y1; z0 = Z0; z1 = Z1;
    m = 1e30f;
    if (x0 > 0)      m = fminf(m, qx - x0 * h);
    if (x1 < GR - 1) m = fminf(m, (x1 + 1) * h - qx);
    if (y0 > 0)      m = fminf(m, qy - y0 * h);
    if (y1 < GR - 1) m = fminf(m, (y1 + 1) * h - qy);
    if (z0 > 0)      m = fminf(m, qz - z0 * h);
    if (z1 < GR - 1) m = fminf(m, (z1 + 1) * h - qz);
    bound = m * m;
    kth_d2 = funbias((u32)(tau >> 32));
    if (!(kth_d2 < bound)) {  // essentially unreachable
      for (int t0 = 0; t0 < NREF; t0 += 64) {
        int j = t0 + lane;
        u64 ck = ~0ull;
        if (j < NREF) {
          float4 P = sb[j];
          int cx = min(max((int)(P.x * GR), 0), GR - 1);
          int cy = min(max((int)(P.y * GR), 0), GR - 1);
          int cz = min(max((int)(P.z * GR), 0), GR - 1);
          bool inbox = (cx >= x0 && cx <= x1 && cy >= y0 && cy <= y1 &&
                        cz >= z0 && cz <= z1);
          if (!inbox) {
            float rr = P.x * P.x + P.y * P.y + P.z * P.z;
            float d2 = qq + rr - 2.0f * (qx * P.x + qy * P.y + qz * P.z);
            ck = ((u64)fbias(d2) << 32) | (u32)__float_as_uint(P.w);
          }
        }
        u64 m64 = __ballot(ck < tau);
        group_insert_g64(m64, ck, slot16, val, tau);
      }
    }
  }
}

// ---------------- K=16 grid, one query per 64-lane wave --------------------
template<int GR, int R, int NREF>
__device__ void knn_grid16_g64_dev(int vbx, int b,
    const float* __restrict__ pos, const float4* __restrict__ sorted,
    const int* __restrict__ cellStart, int csStride, int Mq,
    int* __restrict__ oidx) {
  int wv = threadIdx.x >> 6, lane = threadIdx.x & 63;
  int q = vbx * 4 + wv;
  const float* pb = pos + (size_t)b * NFULL * 3;
  const float4* sb = sorted + (size_t)b * NREF;
  const int* cs = cellStart + b * csStride;
  float qx = pb[q * 3 + 0], qy = pb[q * 3 + 1], qz = pb[q * 3 + 2];
  float qq = qx * qx + qy * qy + qz * qz;
  int ix = min(max((int)(qx * GR), 0), GR - 1);
  int iy = min(max((int)(qy * GR), 0), GR - 1);
  int iz = min(max((int)(qz * GR), 0), GR - 1);
  int x0 = max(ix - R, 0), x1 = min(ix + R, GR - 1);
  int y0 = max(iy - R, 0), y1 = min(iy + R, GR - 1);
  int z0 = max(iz - R, 0), z1 = min(iz + R, GR - 1);

  int ny = y1 - y0 + 1;
  int nrow = (z1 - z0 + 1) * ny;  // <= 25 for R=2
  int s_i = 0, len_i = 0;
  if (lane < nrow) {
    int zz = z0 + lane / ny, yy = y0 + lane % ny;
    int c0 = (zz * GR + yy) * GR + x0;
    s_i = cs[c0];
    len_i = cs[c0 + (x1 - x0) + 1] - s_i;
  }
  int p_i = len_i;
#pragma unroll
  for (int st = 1; st < 64; st <<= 1) {
    int o = __shfl_up(p_i, st, 64);
    if (lane >= st) p_i += o;
  }
  int T = __shfl(p_i, 63, 64);
  p_i -= len_i;              // exclusive prefix
  int d_i = s_i - p_i;       // sorted index = v + d_row
  if (lane >= nrow) p_i = 0x7fffffff;

  int slot16 = lane & 15;
  u64 val, tau;

  // ---- round 1: 64-candidate bitonic bulk build
  {
    int v = lane;
    int r = 0;
#pragma unroll
    for (int st = 32; st >= 1; st >>= 1) {
      int pc = __shfl(p_i, r + st, 64);
      if (v >= pc) r += st;
    }
    int addr = v + __shfl(d_i, r, 64);
    u64 ck = ~0ull;
    if (v < T) {
      float4 P = sb[addr];
      float rr = P.x * P.x + P.y * P.y + P.z * P.z;
      float d2 = qq + rr - 2.0f * (qx * P.x + qy * P.y + qz * P.z);
      ck = ((u64)fbias(d2) << 32) | (u32)__float_as_uint(P.w);
    }
    first_round_sort64(ck, lane, val, tau);
  }

  for (int v0 = 64; v0 < T; v0 += 64) {  // T wave-uniform
    int v = v0 + lane;
    int r = 0;
#pragma unroll
    for (int st = 32; st >= 1; st >>= 1) {
      int pc = __shfl(p_i, r + st, 64);
      if (v >= pc) r += st;
    }
    int addr = v + __shfl(d_i, r, 64);
    u64 ck = ~0ull;
    if (v < T) {
      float4 P = sb[addr];
      float rr = P.x * P.x + P.y * P.y + P.z * P.z;
      float d2 = qq + rr - 2.0f * (qx * P.x + qy * P.y + qz * P.z);
      ck = ((u64)fbias(d2) << 32) | (u32)__float_as_uint(P.w);
    }
    u64 m64 = __ballot(ck < tau);
    group_insert_g64(m64, ck, slot16, val, tau);
  }

  knn_tail16_g64<GR, R, NREF>(sb, cs, qx, qy, qz, qq,
      ix, iy, iz, x0, x1, y0, y1, z0, z1, lane, slot16, val, tau);

  if (lane < 16) {
    size_t base = ((size_t)b * Mq + q) * 16;
    oidx[base + lane] = (int)(u32)val;
  }
}

// ----------------------------------------------- K=16 brute (32-lane) ------
__device__ void knn_brute16_g32_dev(int vbx, int b,
    const float* __restrict__ pos, int Nref, int Mq, int* __restrict__ oidx) {
  int wv = threadIdx.x >> 6, lane = threadIdx.x & 63;
  int g32 = lane >> 5, gl = lane & 31;
  int q = vbx * 8 + wv * 2 + g32;
  const float* pb = pos + (size_t)b * NFULL * 3;
  float qx = pb[q * 3 + 0], qy = pb[q * 3 + 1], qz = pb[q * 3 + 2];
  float qq = qx * qx + qy * qy + qz * qz;

  int slot16 = lane & 15;
  u64 val, tau;

  {
    int j = gl;
    float rx = pb[j * 3 + 0];
    float ry = pb[j * 3 + 1];
    float rz = pb[j * 3 + 2];
    float rr = rx * rx + ry * ry + rz * rz;
    float d2 = qq + rr - 2.0f * (qx * rx + qy * ry + qz * rz);
    u64 ck = ((u64)fbias(d2) << 32) | (u32)j;
    first_round_sort32(ck, gl, val, tau);
  }

  for (int t0 = 32; t0 < Nref; t0 += 32) {
    int j = t0 + gl;
    float rx = pb[j * 3 + 0];
    float ry = pb[j * 3 + 1];
    float rz = pb[j * 3 + 2];
    float rr = rx * rx + ry * ry + rz * rz;
    float d2 = qq + rr - 2.0f * (qx * rx + qy * ry + qz * rz);
    u64 ck = ((u64)fbias(d2) << 32) | (u32)j;
    u64 full = __ballot(ck < tau);
    u32 m32 = (u32)(full >> (g32 * 32));
    group_insert_g32(m32, ck, slot16, val, tau);
  }

  if (gl < 16) {
    size_t base = ((size_t)b * Mq + q) * 16;
    oidx[base + gl] = (int)(u32)val;
  }
}

// ================= K=3 machinery (16 lanes/query, per-lane top-3) ==========
__device__ __forceinline__ void lane_insert3(u64 ck, u64& v0, u64& v1, u64& v2) {
  u64 a = (v0 <= ck) ? v0 : ck;
  u64 bb = (v0 <= ck) ? ck : v0;
  v0 = a;
  u64 c = (v1 <= bb) ? v1 : bb;
  u64 d = (v1 <= bb) ? bb : v1;
  v1 = c;
  v2 = (v2 <= d) ? v2 : d;
}

__device__ __forceinline__ void merge3(u64 v0, u64 v1, u64 v2,
                                       u64& o0, u64& o1, u64& o2) {
  u64 h = v0;
  int hc = 0;
  u64 outs[3];
#pragma unroll
  for (int k = 0; k < 3; ++k) {
    u64 m = h;
#pragma unroll
    for (int st = 1; st < 16; st <<= 1) {
      u64 o = __shfl_xor((unsigned long long)m, st, 16);
      m = (m <= o) ? m : o;
    }
    outs[k] = m;
    if (h == m) { ++hc; h = (hc == 1) ? v1 : ((hc == 2) ? v2 : ~0ull); }
  }
  o0 = outs[0]; o1 = outs[1]; o2 = outs[2];
}

__device__ __forceinline__ void scan_range3(const float4* __restrict__ sb,
    int s, int e, float qx, float qy, float qz, float qq,
    int gl, u64& v0, u64& v1, u64& v2) {
  for (int t0 = s; t0 < e; t0 += 16) {
    int j = t0 + gl;
    if (j < e) {
      float4 P = sb[j];
      float rr = P.x * P.x + P.y * P.y + P.z * P.z;
      float d2 = qq + rr - 2.0f * (qx * P.x + qy * P.y + qz * P.z);
      u64 ck = ((u64)fbias(d2) << 32) | (u32)__float_as_uint(P.w);
      lane_insert3(ck, v0, v1, v2);
    }
  }
}

template<int GR, int R, int NREF>
__device__ __forceinline__ void knn_tail3(
    const float4* __restrict__ sb, const int* __restrict__ cs,
    float qx, float qy, float qz, float qq,
    int ix, int iy, int iz, int x0, int x1, int y0, int y1, int z0, int z1,
    int gl, u64& v0, u64& v1, u64& v2, u64& o0, u64& o1, u64& o2) {
  const float h = 1.0f / GR;
  float m = 1e30f;
  if (x0 > 0)      m = fminf(m, qx - x0 * h);
  if (x1 < GR - 1) m = fminf(m, (x1 + 1) * h - qx);
  if (y0 > 0)      m = fminf(m, qy - y0 * h);
  if (y1 < GR - 1) m = fminf(m, (y1 + 1) * h - qy);
  if (z0 > 0)      m = fminf(m, qz - z0 * h);
  if (z1 < GR - 1) m = fminf(m, (z1 + 1) * h - qz);
  float bound = m * m;
  merge3(v0, v1, v2, o0, o1, o2);
  float kth_d2 = funbias((u32)(o2 >> 32));
  if (!(kth_d2 < bound)) {  // group-uniform; rare
    int X0 = max(ix - (R + 1), 0), X1 = min(ix + (R + 1), GR - 1);
    int Y0 = max(iy - (R + 1), 0), Y1 = min(iy + (R + 1), GR - 1);
    int Z0 = max(iz - (R + 1), 0), Z1 = min(iz + (R + 1), GR - 1);
    int NY2 = Y1 - Y0 + 1;
    int nrow2 = (Z1 - Z0 + 1) * NY2;
    for (int rr2 = 0; rr2 < nrow2; ++rr2) {
      int zz = Z0 + rr2 / NY2, yy = Y0 + rr2 % NY2;
      int c0 = (zz * GR + yy) * GR;
      bool mid = (zz >= z0 && zz <= z1 && yy >= y0 && yy <= y1);
      int s1 = cs[c0 + X0];
      int e1 = mid ? cs[c0 + x0] : cs[c0 + X1 + 1];
      scan_range3(sb, s1, e1, qx, qy, qz, qq, gl, v0, v1, v2);
      if (mid) {
        int s2 = cs[c0 + x1 + 1];
        int e2 = cs[c0 + X1 + 1];
        scan_range3(sb, s2, e2, qx, qy, qz, qq, gl, v0, v1, v2);
      }
    }
    x0 = X0; x1 = X1; y0 = Y0; y1 = Y1; z0 = Z0; z1 = Z1;
    m = 1e30f;
    if (x0 > 0)      m = fminf(m, qx - x0 * h);
    if (x1 < GR - 1) m = fminf(m, (x1 + 1) * h - qx);
    if (y0 > 0)      m = fminf(m, qy - y0 * h);
    if (y1 < GR - 1) m = fminf(m, (y1 + 1) * h - qy);
    if (z0 > 0)      m = fminf(m, qz - z0 * h);
    if (z1 < GR - 1) m = fminf(m, (z1 + 1) * h - qz);
    bound = m * m;
    merge3(v0, v1, v2, o0, o1, o2);
    kth_d2 = funbias((u32)(o2 >> 32));
    if (!(kth_d2 < bound)) {  // essentially unreachable
      for (int t0 = 0; t0 < NREF; t0 += 16) {
        int j = t0 + gl;
        if (j < NREF) {
          float4 P = sb[j];
          int cx = min(max((int)(P.x * GR), 0), GR - 1);
          int cy = min(max((int)(P.y * GR), 0), GR - 1);
          int cz = min(max((int)(P.z * GR), 0), GR - 1);
          bool inbox = (cx >= x0 && cx <= x1 && cy >= y0 && cy <= y1 &&
                        cz >= z0 && cz <= z1);
          if (!inbox) {
            float rr = P.x * P.x + P.y * P.y + P.z * P.z;
            float d2 = qq + rr - 2.0f * (qx * P.x + qy * P.y + qz * P.z);
            u64 ck = ((u64)fbias(d2) << 32) | (u32)__float_as_uint(P.w);
            lane_insert3(ck, v0, v1, v2);
          }
        }
      }
      merge3(v0, v1, v2, o0, o1, o2);
    }
  }
}

template<int GR, int R, int NREF>
__device__ void knn_grid_flat3_dev(int vbx, int b,
    const float* __restrict__ pos, const float4* __restrict__ sorted,
    const int* __restrict__ cellStart, int csStride, int Mq,
    int* __restrict__ oidx, float* __restrict__ od2) {
  int wv = threadIdx.x >> 6, lane = threadIdx.x & 63;
  int g = lane >> 4, gl = lane & 15;
  int q = vbx * 16 + wv * 4 + g;
  const float* pb = pos + (size_t)b * NFULL * 3;
  const float4* sb = sorted + (size_t)b * NREF;
  const int* cs = cellStart + b * csStride;
  float qx = pb[q * 3 + 0], qy = pb[q * 3 + 1], qz = pb[q * 3 + 2];
  float qq = qx * qx + qy * qy + qz * qz;
  int ix = min(max((int)(qx * GR), 0), GR - 1);
  int iy = min(max((int)(qy * GR), 0), GR - 1);
  int iz = min(max((int)(qz * GR), 0), GR - 1);
  int x0 = max(ix - R, 0), x1 = min(ix + R, GR - 1);
  int y0 = max(iy - R, 0), y1 = min(iy + R, GR - 1);
  int z0 = max(iz - R, 0), z1 = min(iz + R, GR - 1);

  int ny = y1 - y0 + 1;
  int nrow = (z1 - z0 + 1) * ny;  // <= 9 for R=1
  int s_i = 0, len_i = 0;
  if (gl < nrow) {
    int zz = z0 + gl / ny, yy = y0 + gl % ny;
    int c0 = (zz * GR + yy) * GR + x0;
    s_i = cs[c0];
    len_i = cs[c0 + (x1 - x0) + 1] - s_i;
  }
  int p_i = len_i;
#pragma unroll
  for (int st = 1; st < 16; st <<= 1) {
    int o = __shfl_up(p_i, st, 16);
    if (gl >= st) p_i += o;
  }
  int T = __shfl(p_i, 15, 16);
  p_i -= len_i;              // exclusive prefix
  int d_i = s_i - p_i;       // sorted index = v + d_row
  if (gl >= nrow) p_i = 0x7fffffff;

  u64 v0 = ~0ull, v1 = ~0ull, v2 = ~0ull;

  for (int vb = 0; vb < T; vb += 16) {  // T group-uniform
    int v = vb + gl;
    int r = 0;
#pragma unroll
    for (int st = 8; st >= 1; st >>= 1) {
      int pc = __shfl(p_i, r + st, 16);
      if (v >= pc) r += st;
    }
    int addr = v + __shfl(d_i, r, 16);
    if (v < T) {
      float4 P = sb[addr];
      float rr = P.x * P.x + P.y * P.y + P.z * P.z;
      float d2 = qq + rr - 2.0f * (qx * P.x + qy * P.y + qz * P.z);
      u64 ck = ((u64)fbias(d2) << 32) | (u32)__float_as_uint(P.w);
      lane_insert3(ck, v0, v1, v2);
    }
  }

  u64 o0, o1, o2;
  knn_tail3<GR, R, NREF>(sb, cs, qx, qy, qz, qq,
      ix, iy, iz, x0, x1, y0, y1, z0, z1, gl, v0, v1, v2, o0, o1, o2);

  if (gl < 3) {
    u64 val = (gl == 0) ? o0 : ((gl == 1) ? o1 : o2);
    size_t base = ((size_t)b * Mq + q) * 3;
    oidx[base + gl] = (int)(u32)val;
    od2[base + gl] = fmaxf(funbias((u32)(val >> 32)), 0.0f);
  }
}

template<int GR, int R, int NREF>
__device__ void knn_grid_flat32_3_dev(int vbx, int b,
    const float* __restrict__ pos, const float4* __restrict__ sorted,
    const int* __restrict__ cellStart, int csStride, int Mq,
    int* __restrict__ oidx, float* __restrict__ od2) {
  int wv = threadIdx.x >> 6, lane = threadIdx.x & 63;
  int g = lane >> 4, gl = lane & 15;
  int q = vbx * 16 + wv * 4 + g;
  const float* pb = pos + (size_t)b * NFULL * 3;
  const float4* sb = sorted + (size_t)b * NREF;
  const int* cs = cellStart + b * csStride;
  float qx = pb[q * 3 + 0], qy = pb[q * 3 + 1], qz = pb[q * 3 + 2];
  float qq = qx * qx + qy * qy + qz * qz;
  int ix = min(max((int)(qx * GR), 0), GR - 1);
  int iy = min(max((int)(qy * GR), 0), GR - 1);
  int iz = min(max((int)(qz * GR), 0), GR - 1);
  int x0 = max(ix - R, 0), x1 = min(ix + R, GR - 1);
  int y0 = max(iy - R, 0), y1 = min(iy + R, GR - 1);
  int z0 = max(iz - R, 0), z1 = min(iz + R, GR - 1);

  int ny = y1 - y0 + 1;
  int nrow = (z1 - z0 + 1) * ny;  // <= 25 for R=2
  int sLo = 0, lenLo = 0, sHi = 0, lenHi = 0;
  if (gl < nrow) {
    int zz = z0 + gl / ny, yy = y0 + gl % ny;
    int c0 = (zz * GR + yy) * GR + x0;
    sLo = cs[c0]; lenLo = cs[c0 + (x1 - x0) + 1] - sLo;
  }
  {
    int i2 = gl + 16;
    if (i2 < nrow) {
      int zz = z0 + i2 / ny, yy = y0 + i2 % ny;
      int c0 = (zz * GR + yy) * GR + x0;
      sHi = cs[c0]; lenHi = cs[c0 + (x1 - x0) + 1] - sHi;
    }
  }
  int pLo = lenLo, pHi = lenHi;
#pragma unroll
  for (int st = 1; st < 16; st <<= 1) {
    int o = __shfl_up(pLo, st, 16);
    if (gl >= st) pLo += o;
    int o2_ = __shfl_up(pHi, st, 16);
    if (gl >= st) pHi += o2_;
  }
  int tot16 = __shfl(pLo, 15, 16);
  pHi += tot16;
  int T = __shfl(pHi, 15, 16);
  pLo -= lenLo; pHi -= lenHi;      // exclusive prefixes
  int dLo = sLo - pLo, dHi = sHi - pHi;
  if (gl >= nrow) pLo = 0x7fffffff;
  if (gl + 16 >= nrow) pHi = 0x7fffffff;

  u64 v0 = ~0ull, v1 = ~0ull, v2 = ~0ull;

  for (int vb = 0; vb < T; vb += 16) {  // T group-uniform
    int v = vb + gl;
    int r = 0;
#pragma unroll
    for (int st = 16; st >= 1; st >>= 1) {
      int j = r + st;                      // j <= 31
      int pcL = __shfl(pLo, j & 15, 16);
      int pcH = __shfl(pHi, j & 15, 16);
      int pc = (j < 16) ? pcL : pcH;
      if (v >= pc) r = j;
    }
    int dL = __shfl(dLo, r & 15, 16);
    int dH = __shfl(dHi, r & 15, 16);
    int addr = v + ((r < 16) ? dL : dH);
    if (v < T) {
      float4 P = sb[addr];
      float rr = P.x * P.x + P.y * P.y + P.z * P.z;
      float d2 = qq + rr - 2.0f * (qx * P.x + qy * P.y + qz * P.z);
      u64 ck = ((u64)fbias(d2) << 32) | (u32)__float_as_uint(P.w);
      lane_insert3(ck, v0, v1, v2);
    }
  }

  u64 o0, o1, o2;
  knn_tail3<GR, R, NREF>(sb, cs, qx, qy, qz, qq,
      ix, iy, iz, x0, x1, y0, y1, z0, z1, gl, v0, v1, v2, o0, o1, o2);

  if (gl < 3) {
    u64 val = (gl == 0) ? o0 : ((gl == 1) ? o1 : o2);
    size_t base = ((size_t)b * Mq + q) * 3;
    oidx[base + gl] = (int)(u32)val;
    od2[base + gl] = fmaxf(funbias((u32)(val >> 32)), 0.0f);
  }
}

__device__ void knn_brute3_dev(int vbx, int b,
    const float* __restrict__ pos, int Nref, int Mq,
    int* __restrict__ oidx, float* __restrict__ od2) {
  int wv = threadIdx.x >> 6, lane = threadIdx.x & 63;
  int g = lane >> 4, gl = lane & 15;
  int q = vbx * 16 + wv * 4 + g;
  const float* pb = pos + (size_t)b * NFULL * 3;
  float qx = pb[q * 3 + 0], qy = pb[q * 3 + 1], qz = pb[q * 3 + 2];
  float qq = qx * qx + qy * qy + qz * qz;

  u64 v0 = ~0ull, v1 = ~0ull, v2 = ~0ull;
  for (int j = gl; j < Nref; j += 16) {
    float rx = pb[j * 3 + 0];
    float ry = pb[j * 3 + 1];
    float rz = pb[j * 3 + 2];
    float rr = rx * rx + ry * ry + rz * rz;
    float d2 = qq + rr - 2.0f * (qx * rx + qy * ry + qz * rz);
    u64 ck = ((u64)fbias(d2) << 32) | (u32)j;
    lane_insert3(ck, v0, v1, v2);
  }
  u64 o0, o1, o2;
  merge3(v0, v1, v2, o0, o1, o2);

  if (gl < 3) {
    u64 val = (gl == 0) ? o0 : ((gl == 1) ? o1 : o2);
    size_t base = ((size_t)b * Mq + q) * 3;
    oidx[base + gl] = (int)(u32)val;
    od2[base + gl] = fmaxf(funbias((u32)(val >> 32)), 0.0f);
  }
}

// ----------------------------------- fused weight packing helpers ---------
__device__ __forceinline__ void pack_tile_rt(const float* __restrict__ W,
                                             short* __restrict__ outp,
                                             int KDIM, int N, int tile, int lane) {
  int NT = N >> 4;
  int kt = tile / NT, nt = tile - kt * NT;
  int n = nt * 16 + (lane & 15);
  int k0 = kt * 32 + (lane >> 4) * 8;
  bf8_t v;
#pragma unroll
  for (int j = 0; j < 8; ++j) {
    int k = k0 + j;
    v[j] = (k < KDIM) ? f2bf(W[(size_t)k * N + n]) : (short)0;
  }
  *(bf8_t*)(outp + ((size_t)tile * 64 + lane) * 8) = v;
}

__device__ void pack_dispatch(int blk, int lane,
    const float* d0W1, short* d0W1p, const float* d0W2, short* d0W2p,
    const float* d1W1, short* d1W1p, const float* d1W2, short* d1W2p,
    const float* d2W1, short* d2W1p, const float* d2W2, short* d2W2p,
    const float* u2W, short* u2Wp, const float* fW1, short* fW1p,
    const float* fW2, short* fW2p,
    const float* u0W, short* u0Wp, const float* u1W, short* u1Wp,
    const float* pos, float* posOut) {
  if      (blk < 8)    pack_tile_rt(d0W1, d0W1p, 6, 128, blk, lane);
  else if (blk < 40)   pack_tile_rt(d0W2, d0W2p, 128, 128, blk - 8, lane);
  else if (blk < 120)  pack_tile_rt(d1W1, d1W1p, 131, 256, blk - 40, lane);
  else if (blk < 248)  pack_tile_rt(d1W2, d1W2p, 256, 256, blk - 120, lane);
  else if (blk < 536)  pack_tile_rt(d2W1, d2W1p, 259, 512, blk - 248, lane);
  else if (blk < 1048) pack_tile_rt(d2W2, d2W2p, 512, 512, blk - 536, lane);
  else if (blk < 1088) pack_tile_rt(u2W, u2Wp, 134, 128, blk - 1048, lane);
  else if (blk < 1120) pack_tile_rt(fW1, fW1p, 128, 128, blk - 1088, lane);
  else if (blk < 1152) pack_tile_rt(fW2, fW2p, 128, 128, blk - 1120, lane);
  else if (blk < 1536) pack_tile_rt(u0W, u0Wp, 768, 256, blk - 1152, lane);
  else if (blk < 1632) pack_tile_rt(u1W, u1Wp, 384, 128, blk - 1536, lane);
  else {
    int base = (blk - 1632) * 256;  // 384 x 256 = 98304 = BATCH*NFULL*3
#pragma unroll
    for (int j = 0; j < 4; ++j) {
      int i = base + lane + j * 64;
      posOut[i] = pos[i];
    }
  }
}

// ---- fused pre-kernel: grid builds + packing + brute kNN (idx2, idxu0) ----
// bx<12: grid build; 12..515: packing; 516..579: idx2; 580..707: idxu0.
__global__ __launch_bounds__(256) void pre_kernel(
    const float* __restrict__ pos, float4* __restrict__ sortedA,
    int* __restrict__ csA, float4* __restrict__ sortedB, int* __restrict__ csB,
    float4* __restrict__ sortedC, int* __restrict__ csC,
    const float* d0W1, short* d0W1p, const float* d0W2, short* d0W2p,
    const float* d1W1, short* d1W1p, const float* d1W2, short* d1W2p,
    const float* d2W1, short* d2W1p, const float* d2W2, short* d2W2p,
    const float* u2W, short* u2Wp, const float* fW1, short* fW1p,
    const float* fW2, short* fW2p,
    const float* u0W, short* u0Wp, const float* u1W, short* u1Wp,
    float* posOut,
    int* __restrict__ idx2, int* __restrict__ idxu0, float* __restrict__ d2u0) {
  __shared__ int cnt[4096];
  __shared__ int partial[256];
  int bx = blockIdx.x, t = threadIdx.x;
  if (bx >= 580) {          // idxu0: 512 q over 128 pts (brute K=3)
    int i = bx - 580;
    knn_brute3_dev(i & 31, i >> 5, pos, 128, 512, idxu0, d2u0);
    return;
  }
  if (bx >= 516) {          // idx2: 128 q over 512 pts (brute K=16)
    int i = bx - 516;
    knn_brute16_g32_dev(i & 15, i >> 4, pos, 512, 128, idx2);
    return;
  }
  if (bx >= 12) {
    int tt = (bx - 12) * 4 + (t >> 6);
    pack_dispatch(tt, t & 63,
        d0W1, d0W1p, d0W2, d0W2p, d1W1, d1W1p, d1W2, d1W2p,
        d2W1, d2W1p, d2W2, d2W2p, u2W, u2Wp, fW1, fW1p, fW2, fW2p,
        u0W, u0Wp, u1W, u1Wp, pos, posOut);
    return;
  }
  int which = bx >> 2, b = bx & 3;
  int NREF = (which == 0) ? 8192 : (which == 1) ? 2048 : 512;
  int GR = (which == 0) ? 16 : 8;
  int NC = GR * GR * GR;
  float4* sorted = ((which == 0) ? sortedA : (which == 1) ? sortedB : sortedC)
                   + (size_t)b * NREF;
  int* cs = ((which == 0) ? csA + b * 4097 : (which == 1) ? csB + b * 513
                                           : csC + b * 513);
  const float* pb = pos + (size_t)b * NFULL * 3;
  for (int c = t; c < NC; c += 256) cnt[c] = 0;
  __syncthreads();
  for (int p = t; p < NREF; p += 256) {
    float x = pb[p * 3 + 0], y = pb[p * 3 + 1], z = pb[p * 3 + 2];
    int cx = min(max((int)(x * GR), 0), GR - 1);
    int cy = min(max((int)(y * GR), 0), GR - 1);
    int cz = min(max((int)(z * GR), 0), GR - 1);
    atomicAdd(&cnt[(cz * GR + cy) * GR + cx], 1);
  }
  __syncthreads();
  int chunk = (NC + 255) / 256;
  int s = 0;
  for (int i = 0; i < chunk; ++i) {
    int c = t * chunk + i;
    if (c < NC) s += cnt[c];
  }
  partial[t] = s;
  __syncthreads();
  if (t == 0) {
    int run = 0;
    for (int i = 0; i < 256; ++i) { int v = partial[i]; partial[i] = run; run += v; }
  }
  __syncthreads();
  int run = partial[t];
  for (int i = 0; i < chunk; ++i) {
    int c = t * chunk + i;
    if (c < NC) { int v = cnt[c]; cnt[c] = run; run += v; }
  }
  __syncthreads();
  for (int c = t; c < NC; c += 256) cs[c] = cnt[c];
  if (t == 0) cs[NC] = NREF;
  __syncthreads();
  for (int p = t; p < NREF; p += 256) {
    float x = pb[p * 3 + 0], y = pb[p * 3 + 1], z = pb[p * 3 + 2];
    int cx = min(max((int)(x * GR), 0), GR - 1);
    int cy = min(max((int)(y * GR), 0), GR - 1);
    int cz = min(max((int)(z * GR), 0), GR - 1);
    int slot = atomicAdd(&cnt[(cz * GR + cy) * GR + cx], 1);
    sorted[slot] = make_float4(x, y, z, __uint_as_float((u32)p));
  }
}

// -------- fused kNN: idx1/idx0 (g64 K=16) + idxu1/idxu2 (K=3 overlap) ------
__global__ __launch_bounds__(256) void knn_kernel(
    const float* __restrict__ pos,
    const float4* __restrict__ sortedA, const int* __restrict__ csA,
    const float4* __restrict__ sortedB, const int* __restrict__ csB,
    const float4* __restrict__ sortedC, const int* __restrict__ csC,
    int* __restrict__ idx0, int* __restrict__ idx1,
    int* __restrict__ idxu1, float* __restrict__ d2u1,
    int* __restrict__ idxu2, float* __restrict__ d2u2) {
  int bx = blockIdx.x, b = blockIdx.y;
  if (bx < 128)        // idx1: 512 q over 2048 pts (heaviest per-query)
    knn_grid16_g64_dev<8, 2, 2048>(bx, b, pos, sortedB, csB, 513, 512, idx1);
  else if (bx < 640)   // idx0: 2048 q over 8192 pts
    knn_grid16_g64_dev<16, 2, 8192>(bx - 128, b, pos, sortedA, csA, 4097, 2048, idx0);
  else if (bx < 768)   // idxu1: 2048 q over 512 pts, K=3
    knn_grid_flat32_3_dev<8, 2, 512>(bx - 640, b, pos, sortedC, csC, 513, 2048, idxu1, d2u1);
  else                 // idxu2: 8192 q over 2048 pts, K=3
    knn_grid_flat3_dev<8, 1, 2048>(bx - 768, b, pos, sortedB, csB, 513, 8192, idxu2, d2u2);
}

// ----------------------------------------------------- down MLP (MFMA) -----
template<int FEAT, int CIN, int CHID, int FPAD, int QB, int WAVES>
__global__ __launch_bounds__(64 * WAVES) void down_mfma_kernel(
    const float* __restrict__ pos, const float* __restrict__ xin,
    const int* __restrict__ idx,
    const short* __restrict__ W1p, const float* __restrict__ b1,
    const short* __restrict__ W2p, const float* __restrict__ b2,
    float* __restrict__ out, int n, int nprev) {
  const int KT1 = FPAD / 32, NT1 = CHID / 16;
  const int KT2 = CHID / 32, NT2 = CHID / 16;
  __shared__ short sFeat[QB][16][FPAD + 8];
  __shared__ short sH1[QB][16][CHID + 8];
  __shared__ int sIdx[QB][16];
  __shared__ float sCtr[QB][3];
  int b = blockIdx.y, q0 = blockIdx.x * QB;
  int t = threadIdx.x;
  int lane = t & 63, wv = t >> 6;
  const float* pb = pos + (size_t)b * NFULL * 3;
  const float* xb = xin + (size_t)b * nprev * CIN;
  if (t < QB * 16)
    sIdx[t >> 4][t & 15] = idx[((size_t)b * n + q0 + (t >> 4)) * 16 + (t & 15)];
  if (t < QB * 3) sCtr[t / 3][t % 3] = pb[(q0 + t / 3) * 3 + (t % 3)];
  __syncthreads();
  for (int e = t; e < QB * 16 * FPAD; e += 64 * WAVES) {
    int k = e / FPAD, c = e - k * FPAD;
    int qq = k >> 4, kk = k & 15;
    float v = 0.f;
    if (c < 3) v = pb[sIdx[qq][kk] * 3 + c] - sCtr[qq][c];
    else if (c < FEAT) v = xb[(size_t)sIdx[qq][kk] * CIN + (c - 3)];
    sFeat[qq][kk][c] = f2bf(v);
  }
  __syncthreads();

  int col = lane & 15, quad = lane >> 4;
  const bf8_t* W1t = (const bf8_t*)W1p;
  for (int nt = 2 * wv; nt < NT1; nt += 2 * WAVES) {
    f4_t acc[QB][2];
    float bb0 = b1[nt * 16 + col], bb1 = b1[nt * 16 + 16 + col];
#pragma unroll
    for (int q = 0; q < QB; ++q) {
      acc[q][0] = {bb0, bb0, bb0, bb0};
      acc[q][1] = {bb1, bb1, bb1, bb1};
    }
#pragma unroll
    for (int kt = 0; kt < KT1; ++kt) {
      bf8_t bf0 = W1t[(kt * NT1 + nt) * 64 + lane];
      bf8_t bf1 = W1t[(kt * NT1 + nt + 1) * 64 + lane];
#pragma unroll
      for (int q = 0; q < QB; ++q) {
        bf8_t a = *(const bf8_t*)&sFeat[q][col][kt * 32 + quad * 8];
        acc[q][0] = __builtin_amdgcn_mfma_f32_16x16x32_bf16(a, bf0, acc[q][0], 0, 0, 0);
        acc[q][1] = __builtin_amdgcn_mfma_f32_16x16x32_bf16(a, bf1, acc[q][1], 0, 0, 0);
      }
    }
#pragma unroll
    for (int q = 0; q < QB; ++q)
#pragma unroll
      for (int r = 0; r < 4; ++r) {
        sH1[q][quad * 4 + r][nt * 16 + col] = f2bf(fmaxf(acc[q][0][r], 0.f));
        sH1[q][quad * 4 + r][nt * 16 + 16 + col] = f2bf(fmaxf(acc[q][1][r], 0.f));
      }
  }
  __syncthreads();

  const bf8_t* W2t = (const bf8_t*)W2p;
  for (int nt = 2 * wv; nt < NT2; nt += 2 * WAVES) {
    f4_t acc[QB][2];
    float bb0 = b2[nt * 16 + col], bb1 = b2[nt * 16 + 16 + col];
#pragma unroll
    for (int q = 0; q < QB; ++q) {
      acc[q][0] = {bb0, bb0, bb0, bb0};
      acc[q][1] = {bb1, bb1, bb1, bb1};
    }
#pragma unroll
    for (int kt = 0; kt < KT2; ++kt) {
      bf8_t bf0 = W2t[(kt * NT2 + nt) * 64 + lane];
      bf8_t bf1 = W2t[(kt * NT2 + nt + 1) * 64 + lane];
#pragma unroll
      for (int q = 0; q < QB; ++q) {
        bf8_t a = *(const bf8_t*)&sH1[q][col][kt * 32 + quad * 8];
        acc[q][0] = __builtin_amdgcn_mfma_f32_16x16x32_bf16(a, bf0, acc[q][0], 0, 0, 0);
        acc[q][1] = __builtin_amdgcn_mfma_f32_16x16x32_bf16(a, bf1, acc[q][1], 0, 0, 0);
      }
    }
#pragma unroll
    for (int q = 0; q < QB; ++q) {
      float m0 = fmaxf(fmaxf(acc[q][0][0], acc[q][0][1]), fmaxf(acc[q][0][2], acc[q][0][3]));
      float m1 = fmaxf(fmaxf(acc[q][1][0], acc[q][1][1]), fmaxf(acc[q][1][2], acc[q][1][3]));
      m0 = fmaxf(m0, __shfl_xor(m0, 16, 64));
      m0 = fmaxf(m0, __shfl_xor(m0, 32, 64));
      m1 = fmaxf(m1, __shfl_xor(m1, 16, 64));
      m1 = fmaxf(m1, __shfl_xor(m1, 32, 64));
      if (lane < 16) {
        float* ob = out + ((size_t)b * n + q0 + q) * CHID;
        ob[nt * 16 + lane] = m0;
        ob[nt * 16 + 16 + lane] = m1;
      }
    }
  }
}

// -------------------------------------------- up MLP (bf16 MFMA version) ---
template<int CIN, int CPRV, int COUT, int WPB>
__global__ __launch_bounds__(64 * WPB) void up_mfma_kernel(
    const float* __restrict__ xc, int ncoarse,
    const int* __restrict__ idx3, const float* __restrict__ d23,
    const float* __restrict__ prv, const short* __restrict__ Wp,
    const float* __restrict__ bvec, float* __restrict__ out, int m) {
  const int CTOT = CIN + CPRV;
  const int KT = CTOT / 32, NT = COUT / 16;
  __shared__ short sA[16][CTOT + 8];
  __shared__ float sWt[16][3];
  __shared__ int   sIt[16][3];
  int b = blockIdx.y, q0 = blockIdx.x * 16, t = threadIdx.x;
  int lane = t & 63, wv = t >> 6;
  if (t < 16) {
    size_t base = ((size_t)b * m + q0 + t) * 3;
    float d0 = d23[base + 0], d1 = d23[base + 1], d2v = d23[base + 2];
    float w0 = 1.f / (d0 + 1e-8f), w1 = 1.f / (d1 + 1e-8f), w2 = 1.f / (d2v + 1e-8f);
    float s = w0 + w1 + w2;
    sWt[t][0] = w0 / s; sWt[t][1] = w1 / s; sWt[t][2] = w2 / s;
    sIt[t][0] = idx3[base + 0]; sIt[t][1] = idx3[base + 1]; sIt[t][2] = idx3[base + 2];
  }
  __syncthreads();
  const float* xb = xc + (size_t)b * ncoarse * CIN;
  const float* pvb = prv + ((size_t)b * m + q0) * CPRV;
  for (int e = t; e < 16 * CIN; e += 64 * WPB) {
    int p = e / CIN, c = e % CIN;
    float v = sWt[p][0] * xb[(size_t)sIt[p][0] * CIN + c]
            + sWt[p][1] * xb[(size_t)sIt[p][1] * CIN + c]
            + sWt[p][2] * xb[(size_t)sIt[p][2] * CIN + c];
    sA[p][c] = f2bf(v);
  }
  for (int e = t; e < 16 * CPRV; e += 64 * WPB) {
    int p = e / CPRV, c = e % CPRV;
    sA[p][CIN + c] = f2bf(pvb[(size_t)p * CPRV + c]);
  }
  __syncthreads();
  int col = lane & 15, quad = lane >> 4;
  const bf8_t* Wt = (const bf8_t*)Wp;
  float* ob = out + ((size_t)b * m + q0) * COUT;
  for (int nt = 2 * wv; nt < NT; nt += 2 * WPB) {
    float bb0 = bvec[nt * 16 + col], bb1 = bvec[nt * 16 + 16 + col];
    f4_t acc0 = {bb0, bb0, bb0, bb0}, acc1 = {bb1, bb1, bb1, bb1};
#pragma unroll
    for (int kt = 0; kt < KT; ++kt) {
      bf8_t a = *(const bf8_t*)&sA[col][kt * 32 + quad * 8];
      bf8_t bf0 = Wt[(kt * NT + nt) * 64 + lane];
      bf8_t bf1 = Wt[(kt * NT + nt + 1) * 64 + lane];
      acc0 = __builtin_amdgcn_mfma_f32_16x16x32_bf16(a, bf0, acc0, 0, 0, 0);
      acc1 = __builtin_amdgcn_mfma_f32_16x16x32_bf16(a, bf1, acc1, 0, 0, 0);
    }
#pragma unroll
    for (int r = 0; r < 4; ++r) {
      ob[(size_t)(quad * 4 + r) * COUT + nt * 16 + col] = fmaxf(acc0[r], 0.f);
      ob[(size_t)(quad * 4 + r) * COUT + nt * 16 + 16 + col] = fmaxf(acc1[r], 0.f);
    }
  }
}

// ------------------------------------- fused up2 + final MLP (bf16 MFMA) ---
__global__ __launch_bounds__(128) void up2f_mfma_kernel(
    const float* __restrict__ xc,
    const int* __restrict__ idx3, const float* __restrict__ d23,
    const float* __restrict__ x0, const float* __restrict__ pos0,
    const short* __restrict__ u2Wp, const float* __restrict__ u2b,
    const short* __restrict__ fW1p, const float* __restrict__ fb1,
    const short* __restrict__ fW2p, const float* __restrict__ fb2,
    float* __restrict__ out) {
  __shared__ short sA[16][168];
  __shared__ short sB[16][136];
  __shared__ float sWt[16][3];
  __shared__ int   sIt[16][3];
  int b = blockIdx.y, q0 = blockIdx.x * 16, t = threadIdx.x;
  int lane = t & 63, wv = t >> 6;
  if (t < 16) {
    size_t base = ((size_t)b * NFULL + q0 + t) * 3;
    float d0 = d23[base + 0], d1 = d23[base + 1], d2v = d23[base + 2];
    float w0 = 1.f / (d0 + 1e-8f), w1 = 1.f / (d1 + 1e-8f), w2 = 1.f / (d2v + 1e-8f);
    float s = w0 + w1 + w2;
    sWt[t][0] = w0 / s; sWt[t][1] = w1 / s; sWt[t][2] = w2 / s;
    sIt[t][0] = idx3[base + 0]; sIt[t][1] = idx3[base + 1]; sIt[t][2] = idx3[base + 2];
  }
  __syncthreads();
  const float* xb = xc + (size_t)b * 2048 * 128;
#pragma unroll
  for (int p = 0; p < 16; ++p) {
    float v = sWt[p][0] * xb[(size_t)sIt[p][0] * 128 + t]
            + sWt[p][1] * xb[(size_t)sIt[p][1] * 128 + t]
            + sWt[p][2] * xb[(size_t)sIt[p][2] * 128 + t];
    sA[p][t] = f2bf(v);
  }
  for (int e = t; e < 16 * 32; e += 128) {
    int p = e / 32, c = 128 + (e % 32);
    float v = 0.f;
    if (c < 131) v = x0[((size_t)b * NFULL + q0 + p) * 3 + (c - 128)];
    else if (c < 134) v = pos0[((size_t)b * NFULL + q0 + p) * 3 + (c - 131)];
    sA[p][c] = f2bf(v);
  }
  __syncthreads();
  int col = lane & 15, quad = lane >> 4;

  bf8_t a1[5];
#pragma unroll
  for (int kt = 0; kt < 5; ++kt)
    a1[kt] = *(const bf8_t*)&sA[col][kt * 32 + quad * 8];
  const bf8_t* W1t = (const bf8_t*)u2Wp;
  for (int nt = 2 * wv; nt < 8; nt += 4) {
    float bb0 = u2b[nt * 16 + col], bb1 = u2b[nt * 16 + 16 + col];
    f4_t acc0 = {bb0, bb0, bb0, bb0}, acc1 = {bb1, bb1, bb1, bb1};
#pragma unroll
    for (int kt = 0; kt < 5; ++kt) {
      bf8_t bf0 = W1t[(kt * 8 + nt) * 64 + lane];
      bf8_t bf1 = W1t[(kt * 8 + nt + 1) * 64 + lane];
      acc0 = __builtin_amdgcn_mfma_f32_16x16x32_bf16(a1[kt], bf0, acc0, 0, 0, 0);
      acc1 = __builtin_amdgcn_mfma_f32_16x16x32_bf16(a1[kt], bf1, acc1, 0, 0, 0);
    }
#pragma unroll
    for (int r = 0; r < 4; ++r) {
      sB[quad * 4 + r][nt * 16 + col] = f2bf(fmaxf(acc0[r], 0.f));
      sB[quad * 4 + r][nt * 16 + 16 + col] = f2bf(fmaxf(acc1[r], 0.f));
    }
  }
  __syncthreads();

  bf8_t a2[4];
#pragma unroll
  for (int kt = 0; kt < 4; ++kt)
    a2[kt] = *(const bf8_t*)&sB[col][kt * 32 + quad * 8];
  const bf8_t* W2t = (const bf8_t*)fW1p;
  for (int nt = 2 * wv; nt < 8; nt += 4) {
    float bb0 = fb1[nt * 16 + col], bb1 = fb1[nt * 16 + 16 + col];
    f4_t acc0 = {bb0, bb0, bb0, bb0}, acc1 = {bb1, bb1, bb1, bb1};
#pragma unroll
    for (int kt = 0; kt < 4; ++kt) {
      bf8_t bf0 = W2t[(kt * 8 + nt) * 64 + lane];
      bf8_t bf1 = W2t[(kt * 8 + nt + 1) * 64 + lane];
      acc0 = __builtin_amdgcn_mfma_f32_16x16x32_bf16(a2[kt], bf0, acc0, 0, 0, 0);
      acc1 = __builtin_amdgcn_mfma_f32_16x16x32_bf16(a2[kt], bf1, acc1, 0, 0, 0);
    }
#pragma unroll
    for (int r = 0; r < 4; ++r) {
      sA[quad * 4 + r][nt * 16 + col] = f2bf(fmaxf(acc0[r], 0.f));
      sA[quad * 4 + r][nt * 16 + 16 + col] = f2bf(fmaxf(acc1[r], 0.f));
    }
  }
  __syncthreads();

  bf8_t a3[4];
#pragma unroll
  for (int kt = 0; kt < 4; ++kt)
    a3[kt] = *(const bf8_t*)&sA[col][kt * 32 + quad * 8];
  const bf8_t* W3t = (const bf8_t*)fW2p;
  float* ob = out + ((size_t)b * NFULL + q0) * 128;
  for (int nt = 2 * wv; nt < 8; nt += 4) {
    float bb0 = fb2[nt * 16 + col], bb1 = fb2[nt * 16 + 16 + col];
    f4_t acc0 = {bb0, bb0, bb0, bb0}, acc1 = {bb1, bb1, bb1, bb1};
#pragma unroll
    for (int kt = 0; kt < 4; ++kt) {
      bf8_t bf0 = W3t[(kt * 8 + nt) * 64 + lane];
      bf8_t bf1 = W3t[(kt * 8 + nt + 1) * 64 + lane];
      acc0 = __builtin_amdgcn_mfma_f32_16x16x32_bf16(a3[kt], bf0, acc0, 0, 0, 0);
      acc1 = __builtin_amdgcn_mfma_f32_16x16x32_bf16(a3[kt], bf1, acc1, 0, 0, 0);
    }
#pragma unroll
    for (int r = 0; r < 4; ++r) {
      ob[(size_t)(quad * 4 + r) * 128 + nt * 16 + col] = acc0[r];
      ob[(size_t)(quad * 4 + r) * 128 + nt * 16 + 16 + col] = acc1[r];
    }
  }
}

// ------------------------------------------------------------------ launch -
extern "C" void kernel_launch(void* const* d_in, const int* in_sizes, int n_in,
                              void* d_out, int out_size, void* d_ws, size_t ws_size,
                              hipStream_t stream) {
  const float* x    = (const float*)d_in[0];
  const float* pos  = (const float*)d_in[1];
  const float* d0W1 = (const float*)d_in[2];
  const float* d0b1 = (const float*)d_in[3];
  const float* d0W2 = (const float*)d_in[4];
  const float* d0b2 = (const float*)d_in[5];
  const float* d1W1 = (const float*)d_in[6];
  const float* d1b1 = (const float*)d_in[7];
  const float* d1W2 = (const float*)d_in[8];
  const float* d1b2 = (const float*)d_in[9];
  const float* d2W1 = (const float*)d_in[10];
  const float* d2b1 = (const float*)d_in[11];
  const float* d2W2 = (const float*)d_in[12];
  const float* d2b2 = (const float*)d_in[13];
  const float* u0W  = (const float*)d_in[14];
  const float* u0b  = (const float*)d_in[15];
  const float* u1W  = (const float*)d_in[16];
  const float* u1b  = (const float*)d_in[17];
  const float* u2W  = (const float*)d_in[18];
  const float* u2b  = (const float*)d_in[19];
  const float* fW1  = (const float*)d_in[20];
  const float* fb1  = (const float*)d_in[21];
  const float* fW2  = (const float*)d_in[22];
  const float* fb2  = (const float*)d_in[23];

  char* ws = (char*)d_ws;
  float* x1    = (float*)(ws + 0);
  float* x2    = (float*)(ws + 4194304);
  float* x3    = (float*)(ws + 6291456);
  float* up0o  = (float*)(ws + 7340032);
  float* up1o  = (float*)(ws + 9437184);
  int*   idx0  = (int*)  (ws + 13631488);
  int*   idx1  = (int*)  (ws + 14155776);
  int*   idx2  = (int*)  (ws + 14286848);
  float4* sortedC = (float4*)(ws + 14319616); // 4*512*16 = 32768
  int*    csC     = (int*)   (ws + 14352384); // 4*513*4  = 8208
  int*   idxu0 = (int*)  (ws + 14843904);
  float* d2u0  = (float*)(ws + 14868480);
  int*   idxu1 = (int*)  (ws + 14893056);
  float* d2u1  = (float*)(ws + 14991360);
  int*   idxu2 = (int*)  (ws + 15089664);
  float* d2u2  = (float*)(ws + 15482880);
  short* d1W1p = (short*)(ws + 15876096);
  short* d1W2p = (short*)(ws + 15958016);
  short* d2W1p = (short*)(ws + 16089088);
  short* d2W2p = (short*)(ws + 16384000);
  short* d0W1p = (short*)(ws + 16908288);
  short* d0W2p = (short*)(ws + 16916480);
  float4* sortedA = (float4*)(ws + 16949248);  // 4*8192*16 = 524288
  int*    csA     = (int*)   (ws + 17473536);  // 4*4097*4  = 65552
  float4* sortedB = (float4*)(ws + 17539136);  // 4*2048*16 = 131072
  int*    csB     = (int*)   (ws + 17670208);  // 4*513*4   = 8208
  short* u2Wp  = (short*)(ws + 17697920);
  short* fW1p  = (short*)(ws + 17738880);
  short* fW2p  = (short*)(ws + 17771648);

  float* out = (float*)d_out;
  // Packed u0W/u1W live in the d_out main region: it is dead until the final
  // up2f_mfma_kernel writes it, and both are fully consumed before that.
  short* u0Wp = (short*)out;                       // 768*256*2 = 393216 B
  short* u1Wp = (short*)(out + 98304);             // 384*128*2 =  98304 B

  // ---- pre: grids + packing + pos copy + brute kNN (idx2, idxu0) ----
  pre_kernel<<<dim3(708), 256, 0, stream>>>(
      pos, sortedA, csA, sortedB, csB, sortedC, csC,
      d0W1, d0W1p, d0W2, d0W2p, d1W1, d1W1p, d1W2, d1W2p,
      d2W1, d2W1p, d2W2, d2W2p, u2W, u2Wp, fW1, fW1p, fW2, fW2p,
      u0W, u0Wp, u1W, u1Wp,
      out + (size_t)BATCH * NFULL * 128,
      idx2, idxu0, d2u0);

  // ---- fused kNN: g64 K=16 (idx1, idx0) + K=3 overlap (idxu1, idxu2) ----
  knn_kernel<<<dim3(1280, BATCH), 256, 0, stream>>>(
      pos, sortedA, csA, sortedB, csB, sortedC, csC,
      idx0, idx1, idxu1, d2u1, idxu2, d2u2);

  // ---- down path ----
  down_mfma_kernel<6, 3, 128, 32, 4, 4><<<dim3(512, BATCH), 256, 0, stream>>>(
      pos, x, idx0, d0W1p, d0b1, d0W2p, d0b2, x1, 2048, 8192);
  down_mfma_kernel<131, 128, 256, 160, 4, 8><<<dim3(128, BATCH), 512, 0, stream>>>(
      pos, x1, idx1, d1W1p, d1b1, d1W2p, d1b2, x2, 512, 2048);
  down_mfma_kernel<259, 256, 512, 288, 2, 8><<<dim3(64, BATCH), 512, 0, stream>>>(
      pos, x2, idx2, d2W1p, d2b1, d2W2p, d2b2, x3, 128, 512);

  // ---- up path ----
  up_mfma_kernel<512, 256, 256, 4><<<dim3(32, BATCH), 256, 0, stream>>>(
      x3, 128, idxu0, d2u0, x2, u0Wp, u0b, up0o, 512);
  up_mfma_kernel<256, 128, 128, 2><<<dim3(128, BATCH), 128, 0, stream>>>(
      up0o, 512, idxu1, d2u1, x1, u1Wp, u1b, up1o, 2048);
  up2f_mfma_kernel<<<dim3(512, BATCH), 128, 0, stream>>>(
      up1o, idxu2, d2u2, x, pos, u2Wp, u2b, fW1p, fb1, fW2p, fb2, out);
}

// Round 12
// 270.212 us; speedup vs baseline: 1.0861x; 1.0723x over previous
//
#include <hip/hip_runtime.h>

#define NFULL 8192
#define BATCH 4

typedef unsigned long long u64;
typedef unsigned int u32;
typedef __attribute__((ext_vector_type(8))) short bf8_t;   // 8 bf16 (4 VGPRs)
typedef __attribute__((ext_vector_type(4))) float f4_t;    // MFMA C/D

__device__ __forceinline__ u32 fbias(float f) {
  u32 u = __float_as_uint(f);
  return (u & 0x80000000u) ? ~u : (u | 0x80000000u);
}
__device__ __forceinline__ float funbias(u32 b) {
  u32 u = (b & 0x80000000u) ? (b & 0x7fffffffu) : ~b;
  return __uint_as_float(u);
}
__device__ __forceinline__ short f2bf(float f) {
  u32 u = __float_as_uint(f);
  u32 r = u + 0x7FFFu + ((u >> 16) & 1u);
  return (short)(r >> 16);
}

// ================= K=16 window-insert primitives ===========================
__device__ __forceinline__ void group_insert_g32(u32 m32, u64 ck, int slot16,
                                                 u64& val, u64& tau) {
  if (m32) {
    while (m32) {
      int src = __ffs(m32) - 1;
      m32 &= m32 - 1;
      u64 c = __shfl((unsigned long long)ck, src, 32);
      u64 prev = __shfl_up((unsigned long long)val, 1, 16);
      if (slot16 == 0) prev = 0ull;
      val = (val <= c) ? val : ((prev <= c) ? c : prev);
    }
    tau = __shfl((unsigned long long)val, 15, 16);
  }
}

__device__ __forceinline__ void group_insert_g64(u64 m64, u64 ck, int slot16,
                                                 u64& val, u64& tau) {
  if (m64) {
    while (m64) {
      int src = __ffsll((unsigned long long)m64) - 1;
      m64 &= m64 - 1;
      u64 c = __shfl((unsigned long long)ck, src, 64);
      u64 prev = __shfl_up((unsigned long long)val, 1, 16);
      if (slot16 == 0) prev = 0ull;
      val = (val <= c) ? val : ((prev <= c) ? c : prev);
    }
    tau = __shfl((unsigned long long)val, 15, 16);
  }
}

// Round-1 bulk build: bitonic sort of the first 32 candidates (g32 paths).
__device__ __forceinline__ void first_round_sort32(u64 ck, int gl,
                                                   u64& val, u64& tau) {
  u64 v = ck;
#pragma unroll
  for (int size = 2; size <= 32; size <<= 1) {
#pragma unroll
    for (int stride = size >> 1; stride > 0; stride >>= 1) {
      u64 other = __shfl_xor((unsigned long long)v, stride, 32);
      bool ddd = ((gl & size) == 0);
      bool takeMin = (((gl & stride) == 0) == ddd);
      u64 mn = (v <= other) ? v : other;
      u64 mx = (v <= other) ? other : v;
      v = takeMin ? mn : mx;
    }
  }
  val = __shfl((unsigned long long)v, gl & 15, 32);
  tau = __shfl((unsigned long long)val, 15, 16);
}

// Round-1 bulk build: 21-stage bitonic sort of first 64 candidates (g64).
__device__ __forceinline__ void first_round_sort64(u64 ck, int gl,
                                                   u64& val, u64& tau) {
  u64 v = ck;
#pragma unroll
  for (int size = 2; size <= 64; size <<= 1) {
#pragma unroll
    for (int stride = size >> 1; stride > 0; stride >>= 1) {
      u64 other = __shfl_xor((unsigned long long)v, stride, 64);
      bool ddd = ((gl & size) == 0);
      bool takeMin = (((gl & stride) == 0) == ddd);
      u64 mn = (v <= other) ? v : other;
      u64 mx = (v <= other) ? other : v;
      v = takeMin ? mn : mx;
    }
  }
  val = __shfl((unsigned long long)v, gl & 15, 64);
  tau = __shfl((unsigned long long)val, 15, 16);
}

__device__ __forceinline__ void scan_range_g64(const float4* __restrict__ sb,
    int s, int e, float qx, float qy, float qz, float qq,
    int lane, int slot16, u64& val, u64& tau) {
  for (int t0 = s; t0 < e; t0 += 64) {
    int j = t0 + lane;
    u64 ck = ~0ull;
    if (j < e) {
      float4 P = sb[j];
      float rr = P.x * P.x + P.y * P.y + P.z * P.z;
      float d2 = qq + rr - 2.0f * (qx * P.x + qy * P.y + qz * P.z);
      ck = ((u64)fbias(d2) << 32) | (u32)__float_as_uint(P.w);
    }
    u64 m64 = __ballot(ck < tau);
    group_insert_g64(m64, ck, slot16, val, tau);
  }
}

// Exactness: after scanning box B, if the Kth smallest d2 is strictly less
// than the squared distance to the nearest NON-clipped face of B, no outside
// point can enter the top-K. Ring expansion scans box(R+1)\box(R) exactly
// once per point (flattened over <=34 segments); insertion ORDER does not
// affect the selected set (unique u64 keys) so tie-breaking matches the
// reference top_k. Full fallback remains the final guard.
template<int GR, int R, int NREF>
__device__ __forceinline__ void knn_tail16_g64(
    const float4* __restrict__ sb, const int* __restrict__ cs,
    float qx, float qy, float qz, float qq,
    int ix, int iy, int iz, int x0, int x1, int y0, int y1, int z0, int z1,
    int lane, int slot16, u64& val, u64& tau) {
  const float h = 1.0f / GR;
  float m = 1e30f;
  if (x0 > 0)      m = fminf(m, qx - x0 * h);
  if (x1 < GR - 1) m = fminf(m, (x1 + 1) * h - qx);
  if (y0 > 0)      m = fminf(m, qy - y0 * h);
  if (y1 < GR - 1) m = fminf(m, (y1 + 1) * h - qy);
  if (z0 > 0)      m = fminf(m, qz - z0 * h);
  if (z1 < GR - 1) m = fminf(m, (z1 + 1) * h - qz);
  float bound = m * m;
  float kth_d2 = funbias((u32)(tau >> 32));
  if (!(kth_d2 < bound)) {  // wave-uniform (1 query/wave)
    // ---- flattened ring scan: box(R+1)\box(R) over <=34 segments ----
    int X0 = max(ix - (R + 1), 0), X1 = min(ix + (R + 1), GR - 1);
    int Y0 = max(iy - (R + 1), 0), Y1 = min(iy + (R + 1), GR - 1);
    int Z0 = max(iz - (R + 1), 0), Z1 = min(iz + (R + 1), GR - 1);
    int NY2 = Y1 - Y0 + 1;
    int nrow2 = (Z1 - Z0 + 1) * NY2;
    int nyO = y1 - y0 + 1;
    int nmid = (z1 - z0 + 1) * nyO;
    int nseg = nrow2 + nmid;  // <= 25 + 9 = 34
    int s_i = 0, len_i = 0;
    if (lane < nrow2) {
      int zz = Z0 + lane / NY2, yy = Y0 + lane % NY2;
      int c0 = (zz * GR + yy) * GR;
      bool mid = (zz >= z0 && zz <= z1 && yy >= y0 && yy <= y1);
      s_i = cs[c0 + X0];
      len_i = (mid ? cs[c0 + x0] : cs[c0 + X1 + 1]) - s_i;
    } else if (lane < nseg) {
      int i = lane - nrow2;
      int zz = z0 + i / nyO, yy = y0 + i % nyO;
      int c0 = (zz * GR + yy) * GR;
      s_i = cs[c0 + x1 + 1];
      len_i = cs[c0 + X1 + 1] - s_i;
    }
    int p_i = len_i;
#pragma unroll
    for (int st = 1; st < 64; st <<= 1) {
      int o = __shfl_up(p_i, st, 64);
      if (lane >= st) p_i += o;
    }
    int T2 = __shfl(p_i, 63, 64);
    p_i -= len_i;
    int d_i = s_i - p_i;
    if (lane >= nseg) p_i = 0x7fffffff;

    for (int v0 = 0; v0 < T2; v0 += 64) {
      int v = v0 + lane;
      int r = 0;
#pragma unroll
      for (int st = 32; st >= 1; st >>= 1) {
        int pc = __shfl(p_i, r + st, 64);
        if (v >= pc) r += st;
      }
      int addr = v + __shfl(d_i, r, 64);
      u64 ck = ~0ull;
      if (v < T2) {
        float4 P = sb[addr];
        float rr = P.x * P.x + P.y * P.y + P.z * P.z;
        float d2 = qq + rr - 2.0f * (qx * P.x + qy * P.y + qz * P.z);
        ck = ((u64)fbias(d2) << 32) | (u32)__float_as_uint(P.w);
      }
      u64 m64 = __ballot(ck < tau);
      group_insert_g64(m64, ck, slot16, val, tau);
    }

    x0 = X0; x1 = X1; y0 = Y0; y1 = Y1; z0 = Z0; z1 = Z1;
    m = 1e30f;
    if (x0 > 0)      m = fminf(m, qx - x0 * h);
    if (x1 < GR - 1) m = fminf(m, (x1 + 1) * h - qx);
    if (y0 > 0)      m = fminf(m, qy - y0 * h);
    if (y1 < GR - 1) m = fminf(m, (y1 + 1) * h - qy);
    if (z0 > 0)      m = fminf(m, qz - z0 * h);
    if (z1 < GR - 1) m = fminf(m, (z1 + 1) * h - qz);
    bound = m * m;
    kth_d2 = funbias((u32)(tau >> 32));
    if (!(kth_d2 < bound)) {  // essentially unreachable
      for (int t0 = 0; t0 < NREF; t0 += 64) {
        int j = t0 + lane;
        u64 ck = ~0ull;
        if (j < NREF) {
          float4 P = sb[j];
          int cx = min(max((int)(P.x * GR), 0), GR - 1);
          int cy = min(max((int)(P.y * GR), 0), GR - 1);
          int cz = min(max((int)(P.z * GR), 0), GR - 1);
          bool inbox = (cx >= x0 && cx <= x1 && cy >= y0 && cy <= y1 &&
                        cz >= z0 && cz <= z1);
          if (!inbox) {
            float rr = P.x * P.x + P.y * P.y + P.z * P.z;
            float d2 = qq + rr - 2.0f * (qx * P.x + qy * P.y + qz * P.z);
            ck = ((u64)fbias(d2) << 32) | (u32)__float_as_uint(P.w);
          }
        }
        u64 m64 = __ballot(ck < tau);
        group_insert_g64(m64, ck, slot16, val, tau);
      }
    }
  }
}

// ---------------- K=16 grid, one query per 64-lane wave --------------------
// R=1: the near box is scanned FIRST (round-1 bitonic covers ~all of it ->
// near-final tau), the R=2 ring then runs as cheap ballot-skip rounds.
template<int GR, int R, int NREF>
__device__ void knn_grid16_g64_dev(int vbx, int b,
    const float* __restrict__ pos, const float4* __restrict__ sorted,
    const int* __restrict__ cellStart, int csStride, int Mq,
    int* __restrict__ oidx) {
  int wv = threadIdx.x >> 6, lane = threadIdx.x & 63;
  int q = vbx * 4 + wv;
  const float* pb = pos + (size_t)b * NFULL * 3;
  const float4* sb = sorted + (size_t)b * NREF;
  const int* cs = cellStart + b * csStride;
  float qx = pb[q * 3 + 0], qy = pb[q * 3 + 1], qz = pb[q * 3 + 2];
  float qq = qx * qx + qy * qy + qz * qz;
  int ix = min(max((int)(qx * GR), 0), GR - 1);
  int iy = min(max((int)(qy * GR), 0), GR - 1);
  int iz = min(max((int)(qz * GR), 0), GR - 1);
  int x0 = max(ix - R, 0), x1 = min(ix + R, GR - 1);
  int y0 = max(iy - R, 0), y1 = min(iy + R, GR - 1);
  int z0 = max(iz - R, 0), z1 = min(iz + R, GR - 1);

  int ny = y1 - y0 + 1;
  int nrow = (z1 - z0 + 1) * ny;  // <= 9 for R=1
  int s_i = 0, len_i = 0;
  if (lane < nrow) {
    int zz = z0 + lane / ny, yy = y0 + lane % ny;
    int c0 = (zz * GR + yy) * GR + x0;
    s_i = cs[c0];
    len_i = cs[c0 + (x1 - x0) + 1] - s_i;
  }
  int p_i = len_i;
#pragma unroll
  for (int st = 1; st < 64; st <<= 1) {
    int o = __shfl_up(p_i, st, 64);
    if (lane >= st) p_i += o;
  }
  int T = __shfl(p_i, 63, 64);
  p_i -= len_i;              // exclusive prefix
  int d_i = s_i - p_i;       // sorted index = v + d_row
  if (lane >= nrow) p_i = 0x7fffffff;

  int slot16 = lane & 15;
  u64 val, tau;

  // ---- round 1: 64-candidate bitonic bulk build
  {
    int v = lane;
    int r = 0;
#pragma unroll
    for (int st = 32; st >= 1; st >>= 1) {
      int pc = __shfl(p_i, r + st, 64);
      if (v >= pc) r += st;
    }
    int addr = v + __shfl(d_i, r, 64);
    u64 ck = ~0ull;
    if (v < T) {
      float4 P = sb[addr];
      float rr = P.x * P.x + P.y * P.y + P.z * P.z;
      float d2 = qq + rr - 2.0f * (qx * P.x + qy * P.y + qz * P.z);
      ck = ((u64)fbias(d2) << 32) | (u32)__float_as_uint(P.w);
    }
    first_round_sort64(ck, lane, val, tau);
  }

  for (int v0 = 64; v0 < T; v0 += 64) {  // T wave-uniform
    int v = v0 + lane;
    int r = 0;
#pragma unroll
    for (int st = 32; st >= 1; st >>= 1) {
      int pc = __shfl(p_i, r + st, 64);
      if (v >= pc) r += st;
    }
    int addr = v + __shfl(d_i, r, 64);
    u64 ck = ~0ull;
    if (v < T) {
      float4 P = sb[addr];
      float rr = P.x * P.x + P.y * P.y + P.z * P.z;
      float d2 = qq + rr - 2.0f * (qx * P.x + qy * P.y + qz * P.z);
      ck = ((u64)fbias(d2) << 32) | (u32)__float_as_uint(P.w);
    }
    u64 m64 = __ballot(ck < tau);
    group_insert_g64(m64, ck, slot16, val, tau);
  }

  knn_tail16_g64<GR, R, NREF>(sb, cs, qx, qy, qz, qq,
      ix, iy, iz, x0, x1, y0, y1, z0, z1, lane, slot16, val, tau);

  if (lane < 16) {
    size_t base = ((size_t)b * Mq + q) * 16;
    oidx[base + lane] = (int)(u32)val;
  }
}

// ----------------------------------------------- K=16 brute (32-lane) ------
__device__ void knn_brute16_g32_dev(int vbx, int b,
    const float* __restrict__ pos, int Nref, int Mq, int* __restrict__ oidx) {
  int wv = threadIdx.x >> 6, lane = threadIdx.x & 63;
  int g32 = lane >> 5, gl = lane & 31;
  int q = vbx * 8 + wv * 2 + g32;
  const float* pb = pos + (size_t)b * NFULL * 3;
  float qx = pb[q * 3 + 0], qy = pb[q * 3 + 1], qz = pb[q * 3 + 2];
  float qq = qx * qx + qy * qy + qz * qz;

  int slot16 = lane & 15;
  u64 val, tau;

  {
    int j = gl;
    float rx = pb[j * 3 + 0];
    float ry = pb[j * 3 + 1];
    float rz = pb[j * 3 + 2];
    float rr = rx * rx + ry * ry + rz * rz;
    float d2 = qq + rr - 2.0f * (qx * rx + qy * ry + qz * rz);
    u64 ck = ((u64)fbias(d2) << 32) | (u32)j;
    first_round_sort32(ck, gl, val, tau);
  }

  for (int t0 = 32; t0 < Nref; t0 += 32) {
    int j = t0 + gl;
    float rx = pb[j * 3 + 0];
    float ry = pb[j * 3 + 1];
    float rz = pb[j * 3 + 2];
    float rr = rx * rx + ry * ry + rz * rz;
    float d2 = qq + rr - 2.0f * (qx * rx + qy * ry + qz * rz);
    u64 ck = ((u64)fbias(d2) << 32) | (u32)j;
    u64 full = __ballot(ck < tau);
    u32 m32 = (u32)(full >> (g32 * 32));
    group_insert_g32(m32, ck, slot16, val, tau);
  }

  if (gl < 16) {
    size_t base = ((size_t)b * Mq + q) * 16;
    oidx[base + gl] = (int)(u32)val;
  }
}

// ================= K=3 machinery (16 lanes/query, per-lane top-3) ==========
__device__ __forceinline__ void lane_insert3(u64 ck, u64& v0, u64& v1, u64& v2) {
  u64 a = (v0 <= ck) ? v0 : ck;
  u64 bb = (v0 <= ck) ? ck : v0;
  v0 = a;
  u64 c = (v1 <= bb) ? v1 : bb;
  u64 d = (v1 <= bb) ? bb : v1;
  v1 = c;
  v2 = (v2 <= d) ? v2 : d;
}

__device__ __forceinline__ void merge3(u64 v0, u64 v1, u64 v2,
                                       u64& o0, u64& o1, u64& o2) {
  u64 h = v0;
  int hc = 0;
  u64 outs[3];
#pragma unroll
  for (int k = 0; k < 3; ++k) {
    u64 m = h;
#pragma unroll
    for (int st = 1; st < 16; st <<= 1) {
      u64 o = __shfl_xor((unsigned long long)m, st, 16);
      m = (m <= o) ? m : o;
    }
    outs[k] = m;
    if (h == m) { ++hc; h = (hc == 1) ? v1 : ((hc == 2) ? v2 : ~0ull); }
  }
  o0 = outs[0]; o1 = outs[1]; o2 = outs[2];
}

__device__ __forceinline__ void scan_range3(const float4* __restrict__ sb,
    int s, int e, float qx, float qy, float qz, float qq,
    int gl, u64& v0, u64& v1, u64& v2) {
  for (int t0 = s; t0 < e; t0 += 16) {
    int j = t0 + gl;
    if (j < e) {
      float4 P = sb[j];
      float rr = P.x * P.x + P.y * P.y + P.z * P.z;
      float d2 = qq + rr - 2.0f * (qx * P.x + qy * P.y + qz * P.z);
      u64 ck = ((u64)fbias(d2) << 32) | (u32)__float_as_uint(P.w);
      lane_insert3(ck, v0, v1, v2);
    }
  }
}

template<int GR, int R, int NREF>
__device__ __forceinline__ void knn_tail3(
    const float4* __restrict__ sb, const int* __restrict__ cs,
    float qx, float qy, float qz, float qq,
    int ix, int iy, int iz, int x0, int x1, int y0, int y1, int z0, int z1,
    int gl, u64& v0, u64& v1, u64& v2, u64& o0, u64& o1, u64& o2) {
  const float h = 1.0f / GR;
  float m = 1e30f;
  if (x0 > 0)      m = fminf(m, qx - x0 * h);
  if (x1 < GR - 1) m = fminf(m, (x1 + 1) * h - qx);
  if (y0 > 0)      m = fminf(m, qy - y0 * h);
  if (y1 < GR - 1) m = fminf(m, (y1 + 1) * h - qy);
  if (z0 > 0)      m = fminf(m, qz - z0 * h);
  if (z1 < GR - 1) m = fminf(m, (z1 + 1) * h - qz);
  float bound = m * m;
  merge3(v0, v1, v2, o0, o1, o2);
  float kth_d2 = funbias((u32)(o2 >> 32));
  if (!(kth_d2 < bound)) {  // group-uniform; rare
    int X0 = max(ix - (R + 1), 0), X1 = min(ix + (R + 1), GR - 1);
    int Y0 = max(iy - (R + 1), 0), Y1 = min(iy + (R + 1), GR - 1);
    int Z0 = max(iz - (R + 1), 0), Z1 = min(iz + (R + 1), GR - 1);
    int NY2 = Y1 - Y0 + 1;
    int nrow2 = (Z1 - Z0 + 1) * NY2;
    for (int rr2 = 0; rr2 < nrow2; ++rr2) {
      int zz = Z0 + rr2 / NY2, yy = Y0 + rr2 % NY2;
      int c0 = (zz * GR + yy) * GR;
      bool mid = (zz >= z0 && zz <= z1 && yy >= y0 && yy <= y1);
      int s1 = cs[c0 + X0];
      int e1 = mid ? cs[c0 + x0] : cs[c0 + X1 + 1];
      scan_range3(sb, s1, e1, qx, qy, qz, qq, gl, v0, v1, v2);
      if (mid) {
        int s2 = cs[c0 + x1 + 1];
        int e2 = cs[c0 + X1 + 1];
        scan_range3(sb, s2, e2, qx, qy, qz, qq, gl, v0, v1, v2);
      }
    }
    x0 = X0; x1 = X1; y0 = Y0; y1 = Y1; z0 = Z0; z1 = Z1;
    m = 1e30f;
    if (x0 > 0)      m = fminf(m, qx - x0 * h);
    if (x1 < GR - 1) m = fminf(m, (x1 + 1) * h - qx);
    if (y0 > 0)      m = fminf(m, qy - y0 * h);
    if (y1 < GR - 1) m = fminf(m, (y1 + 1) * h - qy);
    if (z0 > 0)      m = fminf(m, qz - z0 * h);
    if (z1 < GR - 1) m = fminf(m, (z1 + 1) * h - qz);
    bound = m * m;
    merge3(v0, v1, v2, o0, o1, o2);
    kth_d2 = funbias((u32)(o2 >> 32));
    if (!(kth_d2 < bound)) {  // essentially unreachable
      for (int t0 = 0; t0 < NREF; t0 += 16) {
        int j = t0 + gl;
        if (j < NREF) {
          float4 P = sb[j];
          int cx = min(max((int)(P.x * GR), 0), GR - 1);
          int cy = min(max((int)(P.y * GR), 0), GR - 1);
          int cz = min(max((int)(P.z * GR), 0), GR - 1);
          bool inbox = (cx >= x0 && cx <= x1 && cy >= y0 && cy <= y1 &&
                        cz >= z0 && cz <= z1);
          if (!inbox) {
            float rr = P.x * P.x + P.y * P.y + P.z * P.z;
            float d2 = qq + rr - 2.0f * (qx * P.x + qy * P.y + qz * P.z);
            u64 ck = ((u64)fbias(d2) << 32) | (u32)__float_as_uint(P.w);
            lane_insert3(ck, v0, v1, v2);
          }
        }
      }
      merge3(v0, v1, v2, o0, o1, o2);
    }
  }
}

template<int GR, int R, int NREF>
__device__ void knn_grid_flat3_dev(int vbx, int b,
    const float* __restrict__ pos, const float4* __restrict__ sorted,
    const int* __restrict__ cellStart, int csStride, int Mq,
    int* __restrict__ oidx, float* __restrict__ od2) {
  int wv = threadIdx.x >> 6, lane = threadIdx.x & 63;
  int g = lane >> 4, gl = lane & 15;
  int q = vbx * 16 + wv * 4 + g;
  const float* pb = pos + (size_t)b * NFULL * 3;
  const float4* sb = sorted + (size_t)b * NREF;
  const int* cs = cellStart + b * csStride;
  float qx = pb[q * 3 + 0], qy = pb[q * 3 + 1], qz = pb[q * 3 + 2];
  float qq = qx * qx + qy * qy + qz * qz;
  int ix = min(max((int)(qx * GR), 0), GR - 1);
  int iy = min(max((int)(qy * GR), 0), GR - 1);
  int iz = min(max((int)(qz * GR), 0), GR - 1);
  int x0 = max(ix - R, 0), x1 = min(ix + R, GR - 1);
  int y0 = max(iy - R, 0), y1 = min(iy + R, GR - 1);
  int z0 = max(iz - R, 0), z1 = min(iz + R, GR - 1);

  int ny = y1 - y0 + 1;
  int nrow = (z1 - z0 + 1) * ny;  // <= 9 for R=1
  int s_i = 0, len_i = 0;
  if (gl < nrow) {
    int zz = z0 + gl / ny, yy = y0 + gl % ny;
    int c0 = (zz * GR + yy) * GR + x0;
    s_i = cs[c0];
    len_i = cs[c0 + (x1 - x0) + 1] - s_i;
  }
  int p_i = len_i;
#pragma unroll
  for (int st = 1; st < 16; st <<= 1) {
    int o = __shfl_up(p_i, st, 16);
    if (gl >= st) p_i += o;
  }
  int T = __shfl(p_i, 15, 16);
  p_i -= len_i;              // exclusive prefix
  int d_i = s_i - p_i;       // sorted index = v + d_row
  if (gl >= nrow) p_i = 0x7fffffff;

  u64 v0 = ~0ull, v1 = ~0ull, v2 = ~0ull;

  for (int vb = 0; vb < T; vb += 16) {  // T group-uniform
    int v = vb + gl;
    int r = 0;
#pragma unroll
    for (int st = 8; st >= 1; st >>= 1) {
      int pc = __shfl(p_i, r + st, 16);
      if (v >= pc) r += st;
    }
    int addr = v + __shfl(d_i, r, 16);
    if (v < T) {
      float4 P = sb[addr];
      float rr = P.x * P.x + P.y * P.y + P.z * P.z;
      float d2 = qq + rr - 2.0f * (qx * P.x + qy * P.y + qz * P.z);
      u64 ck = ((u64)fbias(d2) << 32) | (u32)__float_as_uint(P.w);
      lane_insert3(ck, v0, v1, v2);
    }
  }

  u64 o0, o1, o2;
  knn_tail3<GR, R, NREF>(sb, cs, qx, qy, qz, qq,
      ix, iy, iz, x0, x1, y0, y1, z0, z1, gl, v0, v1, v2, o0, o1, o2);

  if (gl < 3) {
    u64 val = (gl == 0) ? o0 : ((gl == 1) ? o1 : o2);
    size_t base = ((size_t)b * Mq + q) * 3;
    oidx[base + gl] = (int)(u32)val;
    od2[base + gl] = fmaxf(funbias((u32)(val >> 32)), 0.0f);
  }
}

template<int GR, int R, int NREF>
__device__ void knn_grid_flat32_3_dev(int vbx, int b,
    const float* __restrict__ pos, const float4* __restrict__ sorted,
    const int* __restrict__ cellStart, int csStride, int Mq,
    int* __restrict__ oidx, float* __restrict__ od2) {
  int wv = threadIdx.x >> 6, lane = threadIdx.x & 63;
  int g = lane >> 4, gl = lane & 15;
  int q = vbx * 16 + wv * 4 + g;
  const float* pb = pos + (size_t)b * NFULL * 3;
  const float4* sb = sorted + (size_t)b * NREF;
  const int* cs = cellStart + b * csStride;
  float qx = pb[q * 3 + 0], qy = pb[q * 3 + 1], qz = pb[q * 3 + 2];
  float qq = qx * qx + qy * qy + qz * qz;
  int ix = min(max((int)(qx * GR), 0), GR - 1);
  int iy = min(max((int)(qy * GR), 0), GR - 1);
  int iz = min(max((int)(qz * GR), 0), GR - 1);
  int x0 = max(ix - R, 0), x1 = min(ix + R, GR - 1);
  int y0 = max(iy - R, 0), y1 = min(iy + R, GR - 1);
  int z0 = max(iz - R, 0), z1 = min(iz + R, GR - 1);

  int ny = y1 - y0 + 1;
  int nrow = (z1 - z0 + 1) * ny;  // <= 25 for R=2
  int sLo = 0, lenLo = 0, sHi = 0, lenHi = 0;
  if (gl < nrow) {
    int zz = z0 + gl / ny, yy = y0 + gl % ny;
    int c0 = (zz * GR + yy) * GR + x0;
    sLo = cs[c0]; lenLo = cs[c0 + (x1 - x0) + 1] - sLo;
  }
  {
    int i2 = gl + 16;
    if (i2 < nrow) {
      int zz = z0 + i2 / ny, yy = y0 + i2 % ny;
      int c0 = (zz * GR + yy) * GR + x0;
      sHi = cs[c0]; lenHi = cs[c0 + (x1 - x0) + 1] - sHi;
    }
  }
  int pLo = lenLo, pHi = lenHi;
#pragma unroll
  for (int st = 1; st < 16; st <<= 1) {
    int o = __shfl_up(pLo, st, 16);
    if (gl >= st) pLo += o;
    int o2_ = __shfl_up(pHi, st, 16);
    if (gl >= st) pHi += o2_;
  }
  int tot16 = __shfl(pLo, 15, 16);
  pHi += tot16;
  int T = __shfl(pHi, 15, 16);
  pLo -= lenLo; pHi -= lenHi;      // exclusive prefixes
  int dLo = sLo - pLo, dHi = sHi - pHi;
  if (gl >= nrow) pLo = 0x7fffffff;
  if (gl + 16 >= nrow) pHi = 0x7fffffff;

  u64 v0 = ~0ull, v1 = ~0ull, v2 = ~0ull;

  for (int vb = 0; vb < T; vb += 16) {  // T group-uniform
    int v = vb + gl;
    int r = 0;
#pragma unroll
    for (int st = 16; st >= 1; st >>= 1) {
      int j = r + st;                      // j <= 31
      int pcL = __shfl(pLo, j & 15, 16);
      int pcH = __shfl(pHi, j & 15, 16);
      int pc = (j < 16) ? pcL : pcH;
      if (v >= pc) r = j;
    }
    int dL = __shfl(dLo, r & 15, 16);
    int dH = __shfl(dHi, r & 15, 16);
    int addr = v + ((r < 16) ? dL : dH);
    if (v < T) {
      float4 P = sb[addr];
      float rr = P.x * P.x + P.y * P.y + P.z * P.z;
      float d2 = qq + rr - 2.0f * (qx * P.x + qy * P.y + qz * P.z);
      u64 ck = ((u64)fbias(d2) << 32) | (u32)__float_as_uint(P.w);
      lane_insert3(ck, v0, v1, v2);
    }
  }

  u64 o0, o1, o2;
  knn_tail3<GR, R, NREF>(sb, cs, qx, qy, qz, qq,
      ix, iy, iz, x0, x1, y0, y1, z0, z1, gl, v0, v1, v2, o0, o1, o2);

  if (gl < 3) {
    u64 val = (gl == 0) ? o0 : ((gl == 1) ? o1 : o2);
    size_t base = ((size_t)b * Mq + q) * 3;
    oidx[base + gl] = (int)(u32)val;
    od2[base + gl] = fmaxf(funbias((u32)(val >> 32)), 0.0f);
  }
}

__device__ void knn_brute3_dev(int vbx, int b,
    const float* __restrict__ pos, int Nref, int Mq,
    int* __restrict__ oidx, float* __restrict__ od2) {
  int wv = threadIdx.x >> 6, lane = threadIdx.x & 63;
  int g = lane >> 4, gl = lane & 15;
  int q = vbx * 16 + wv * 4 + g;
  const float* pb = pos + (size_t)b * NFULL * 3;
  float qx = pb[q * 3 + 0], qy = pb[q * 3 + 1], qz = pb[q * 3 + 2];
  float qq = qx * qx + qy * qy + qz * qz;

  u64 v0 = ~0ull, v1 = ~0ull, v2 = ~0ull;
  for (int j = gl; j < Nref; j += 16) {
    float rx = pb[j * 3 + 0];
    float ry = pb[j * 3 + 1];
    float rz = pb[j * 3 + 2];
    float rr = rx * rx + ry * ry + rz * rz;
    float d2 = qq + rr - 2.0f * (qx * rx + qy * ry + qz * rz);
    u64 ck = ((u64)fbias(d2) << 32) | (u32)j;
    lane_insert3(ck, v0, v1, v2);
  }
  u64 o0, o1, o2;
  merge3(v0, v1, v2, o0, o1, o2);

  if (gl < 3) {
    u64 val = (gl == 0) ? o0 : ((gl == 1) ? o1 : o2);
    size_t base = ((size_t)b * Mq + q) * 3;
    oidx[base + gl] = (int)(u32)val;
    od2[base + gl] = fmaxf(funbias((u32)(val >> 32)), 0.0f);
  }
}

// ----------------------------------- fused weight packing helpers ---------
__device__ __forceinline__ void pack_tile_rt(const float* __restrict__ W,
                                             short* __restrict__ outp,
                                             int KDIM, int N, int tile, int lane) {
  int NT = N >> 4;
  int kt = tile / NT, nt = tile - kt * NT;
  int n = nt * 16 + (lane & 15);
  int k0 = kt * 32 + (lane >> 4) * 8;
  bf8_t v;
#pragma unroll
  for (int j = 0; j < 8; ++j) {
    int k = k0 + j;
    v[j] = (k < KDIM) ? f2bf(W[(size_t)k * N + n]) : (short)0;
  }
  *(bf8_t*)(outp + ((size_t)tile * 64 + lane) * 8) = v;
}

__device__ void pack_dispatch(int blk, int lane,
    const float* d0W1, short* d0W1p, const float* d0W2, short* d0W2p,
    const float* d1W1, short* d1W1p, const float* d1W2, short* d1W2p,
    const float* d2W1, short* d2W1p, const float* d2W2, short* d2W2p,
    const float* u2W, short* u2Wp, const float* fW1, short* fW1p,
    const float* fW2, short* fW2p,
    const float* u0W, short* u0Wp, const float* u1W, short* u1Wp,
    const float* pos, float* posOut) {
  if      (blk < 8)    pack_tile_rt(d0W1, d0W1p, 6, 128, blk, lane);
  else if (blk < 40)   pack_tile_rt(d0W2, d0W2p, 128, 128, blk - 8, lane);
  else if (blk < 120)  pack_tile_rt(d1W1, d1W1p, 131, 256, blk - 40, lane);
  else if (blk < 248)  pack_tile_rt(d1W2, d1W2p, 256, 256, blk - 120, lane);
  else if (blk < 536)  pack_tile_rt(d2W1, d2W1p, 259, 512, blk - 248, lane);
  else if (blk < 1048) pack_tile_rt(d2W2, d2W2p, 512, 512, blk - 536, lane);
  else if (blk < 1088) pack_tile_rt(u2W, u2Wp, 134, 128, blk - 1048, lane);
  else if (blk < 1120) pack_tile_rt(fW1, fW1p, 128, 128, blk - 1088, lane);
  else if (blk < 1152) pack_tile_rt(fW2, fW2p, 128, 128, blk - 1120, lane);
  else if (blk < 1536) pack_tile_rt(u0W, u0Wp, 768, 256, blk - 1152, lane);
  else if (blk < 1632) pack_tile_rt(u1W, u1Wp, 384, 128, blk - 1536, lane);
  else {
    int base = (blk - 1632) * 256;  // 384 x 256 = 98304 = BATCH*NFULL*3
#pragma unroll
    for (int j = 0; j < 4; ++j) {
      int i = base + lane + j * 64;
      posOut[i] = pos[i];
    }
  }
}

// ---- fused pre-kernel: grid builds + packing + brute kNN (idx2, idxu0) ----
// bx<12: grid build; 12..515: packing; 516..579: idx2; 580..707: idxu0.
__global__ __launch_bounds__(256) void pre_kernel(
    const float* __restrict__ pos, float4* __restrict__ sortedA,
    int* __restrict__ csA, float4* __restrict__ sortedB, int* __restrict__ csB,
    float4* __restrict__ sortedC, int* __restrict__ csC,
    const float* d0W1, short* d0W1p, const float* d0W2, short* d0W2p,
    const float* d1W1, short* d1W1p, const float* d1W2, short* d1W2p,
    const float* d2W1, short* d2W1p, const float* d2W2, short* d2W2p,
    const float* u2W, short* u2Wp, const float* fW1, short* fW1p,
    const float* fW2, short* fW2p,
    const float* u0W, short* u0Wp, const float* u1W, short* u1Wp,
    float* posOut,
    int* __restrict__ idx2, int* __restrict__ idxu0, float* __restrict__ d2u0) {
  __shared__ int cnt[4096];
  __shared__ int partial[256];
  int bx = blockIdx.x, t = threadIdx.x;
  if (bx >= 580) {          // idxu0: 512 q over 128 pts (brute K=3)
    int i = bx - 580;
    knn_brute3_dev(i & 31, i >> 5, pos, 128, 512, idxu0, d2u0);
    return;
  }
  if (bx >= 516) {          // idx2: 128 q over 512 pts (brute K=16)
    int i = bx - 516;
    knn_brute16_g32_dev(i & 15, i >> 4, pos, 512, 128, idx2);
    return;
  }
  if (bx >= 12) {
    int tt = (bx - 12) * 4 + (t >> 6);
    pack_dispatch(tt, t & 63,
        d0W1, d0W1p, d0W2, d0W2p, d1W1, d1W1p, d1W2, d1W2p,
        d2W1, d2W1p, d2W2, d2W2p, u2W, u2Wp, fW1, fW1p, fW2, fW2p,
        u0W, u0Wp, u1W, u1Wp, pos, posOut);
    return;
  }
  int which = bx >> 2, b = bx & 3;
  int NREF = (which == 0) ? 8192 : (which == 1) ? 2048 : 512;
  int GR = (which == 0) ? 16 : 8;
  int NC = GR * GR * GR;
  float4* sorted = ((which == 0) ? sortedA : (which == 1) ? sortedB : sortedC)
                   + (size_t)b * NREF;
  int* cs = ((which == 0) ? csA + b * 4097 : (which == 1) ? csB + b * 513
                                           : csC + b * 513);
  const float* pb = pos + (size_t)b * NFULL * 3;
  for (int c = t; c < NC; c += 256) cnt[c] = 0;
  __syncthreads();
  for (int p = t; p < NREF; p += 256) {
    float x = pb[p * 3 + 0], y = pb[p * 3 + 1], z = pb[p * 3 + 2];
    int cx = min(max((int)(x * GR), 0), GR - 1);
    int cy = min(max((int)(y * GR), 0), GR - 1);
    int cz = min(max((int)(z * GR), 0), GR - 1);
    atomicAdd(&cnt[(cz * GR + cy) * GR + cx], 1);
  }
  __syncthreads();
  int chunk = (NC + 255) / 256;
  int s = 0;
  for (int i = 0; i < chunk; ++i) {
    int c = t * chunk + i;
    if (c < NC) s += cnt[c];
  }
  partial[t] = s;
  __syncthreads();
  if (t == 0) {
    int run = 0;
    for (int i = 0; i < 256; ++i) { int v = partial[i]; partial[i] = run; run += v; }
  }
  __syncthreads();
  int run = partial[t];
  for (int i = 0; i < chunk; ++i) {
    int c = t * chunk + i;
    if (c < NC) { int v = cnt[c]; cnt[c] = run; run += v; }
  }
  __syncthreads();
  for (int c = t; c < NC; c += 256) cs[c] = cnt[c];
  if (t == 0) cs[NC] = NREF;
  __syncthreads();
  for (int p = t; p < NREF; p += 256) {
    float x = pb[p * 3 + 0], y = pb[p * 3 + 1], z = pb[p * 3 + 2];
    int cx = min(max((int)(x * GR), 0), GR - 1);
    int cy = min(max((int)(y * GR), 0), GR - 1);
    int cz = min(max((int)(z * GR), 0), GR - 1);
    int slot = atomicAdd(&cnt[(cz * GR + cy) * GR + cx], 1);
    sorted[slot] = make_float4(x, y, z, __uint_as_float((u32)p));
  }
}

// -------- fused kNN: idx1/idx0 (g64 K=16, R=1 near-first) + K=3 overlap ----
__global__ __launch_bounds__(256) void knn_kernel(
    const float* __restrict__ pos,
    const float4* __restrict__ sortedA, const int* __restrict__ csA,
    const float4* __restrict__ sortedB, const int* __restrict__ csB,
    const float4* __restrict__ sortedC, const int* __restrict__ csC,
    int* __restrict__ idx0, int* __restrict__ idx1,
    int* __restrict__ idxu1, float* __restrict__ d2u1,
    int* __restrict__ idxu2, float* __restrict__ d2u2) {
  int bx = blockIdx.x, b = blockIdx.y;
  if (bx < 128)        // idx1: 512 q over 2048 pts (heaviest per-query)
    knn_grid16_g64_dev<8, 1, 2048>(bx, b, pos, sortedB, csB, 513, 512, idx1);
  else if (bx < 640)   // idx0: 2048 q over 8192 pts
    knn_grid16_g64_dev<16, 1, 8192>(bx - 128, b, pos, sortedA, csA, 4097, 2048, idx0);
  else if (bx < 768)   // idxu1: 2048 q over 512 pts, K=3
    knn_grid_flat32_3_dev<8, 2, 512>(bx - 640, b, pos, sortedC, csC, 513, 2048, idxu1, d2u1);
  else                 // idxu2: 8192 q over 2048 pts, K=3
    knn_grid_flat3_dev<8, 1, 2048>(bx - 768, b, pos, sortedB, csB, 513, 8192, idxu2, d2u2);
}

// ----------------------------------------------------- down MLP (MFMA) -----
template<int FEAT, int CIN, int CHID, int FPAD, int QB, int WAVES>
__global__ __launch_bounds__(64 * WAVES) void down_mfma_kernel(
    const float* __restrict__ pos, const float* __restrict__ xin,
    const int* __restrict__ idx,
    const short* __restrict__ W1p, const float* __restrict__ b1,
    const short* __restrict__ W2p, const float* __restrict__ b2,
    float* __restrict__ out, int n, int nprev) {
  const int KT1 = FPAD / 32, NT1 = CHID / 16;
  const int KT2 = CHID / 32, NT2 = CHID / 16;
  __shared__ short sFeat[QB][16][FPAD + 8];
  __shared__ short sH1[QB][16][CHID + 8];
  __shared__ int sIdx[QB][16];
  __shared__ float sCtr[QB][3];
  int b = blockIdx.y, q0 = blockIdx.x * QB;
  int t = threadIdx.x;
  int lane = t & 63, wv = t >> 6;
  const float* pb = pos + (size_t)b * NFULL * 3;
  const float* xb = xin + (size_t)b * nprev * CIN;
  if (t < QB * 16)
    sIdx[t >> 4][t & 15] = idx[((size_t)b * n + q0 + (t >> 4)) * 16 + (t & 15)];
  if (t < QB * 3) sCtr[t / 3][t % 3] = pb[(q0 + t / 3) * 3 + (t % 3)];
  __syncthreads();
  for (int e = t; e < QB * 16 * FPAD; e += 64 * WAVES) {
    int k = e / FPAD, c = e - k * FPAD;
    int qq = k >> 4, kk = k & 15;
    float v = 0.f;
    if (c < 3) v = pb[sIdx[qq][kk] * 3 + c] - sCtr[qq][c];
    else if (c < FEAT) v = xb[(size_t)sIdx[qq][kk] * CIN + (c - 3)];
    sFeat[qq][kk][c] = f2bf(v);
  }
  __syncthreads();

  int col = lane & 15, quad = lane >> 4;
  const bf8_t* W1t = (const bf8_t*)W1p;
  for (int nt = 2 * wv; nt < NT1; nt += 2 * WAVES) {
    f4_t acc[QB][2];
    float bb0 = b1[nt * 16 + col], bb1 = b1[nt * 16 + 16 + col];
#pragma unroll
    for (int q = 0; q < QB; ++q) {
      acc[q][0] = {bb0, bb0, bb0, bb0};
      acc[q][1] = {bb1, bb1, bb1, bb1};
    }
#pragma unroll
    for (int kt = 0; kt < KT1; ++kt) {
      bf8_t bf0 = W1t[(kt * NT1 + nt) * 64 + lane];
      bf8_t bf1 = W1t[(kt * NT1 + nt + 1) * 64 + lane];
#pragma unroll
      for (int q = 0; q < QB; ++q) {
        bf8_t a = *(const bf8_t*)&sFeat[q][col][kt * 32 + quad * 8];
        acc[q][0] = __builtin_amdgcn_mfma_f32_16x16x32_bf16(a, bf0, acc[q][0], 0, 0, 0);
        acc[q][1] = __builtin_amdgcn_mfma_f32_16x16x32_bf16(a, bf1, acc[q][1], 0, 0, 0);
      }
    }
#pragma unroll
    for (int q = 0; q < QB; ++q)
#pragma unroll
      for (int r = 0; r < 4; ++r) {
        sH1[q][quad * 4 + r][nt * 16 + col] = f2bf(fmaxf(acc[q][0][r], 0.f));
        sH1[q][quad * 4 + r][nt * 16 + 16 + col] = f2bf(fmaxf(acc[q][1][r], 0.f));
      }
  }
  __syncthreads();

  const bf8_t* W2t = (const bf8_t*)W2p;
  for (int nt = 2 * wv; nt < NT2; nt += 2 * WAVES) {
    f4_t acc[QB][2];
    float bb0 = b2[nt * 16 + col], bb1 = b2[nt * 16 + 16 + col];
#pragma unroll
    for (int q = 0; q < QB; ++q) {
      acc[q][0] = {bb0, bb0, bb0, bb0};
      acc[q][1] = {bb1, bb1, bb1, bb1};
    }
#pragma unroll
    for (int kt = 0; kt < KT2; ++kt) {
      bf8_t bf0 = W2t[(kt * NT2 + nt) * 64 + lane];
      bf8_t bf1 = W2t[(kt * NT2 + nt + 1) * 64 + lane];
#pragma unroll
      for (int q = 0; q < QB; ++q) {
        bf8_t a = *(const bf8_t*)&sH1[q][col][kt * 32 + quad * 8];
        acc[q][0] = __builtin_amdgcn_mfma_f32_16x16x32_bf16(a, bf0, acc[q][0], 0, 0, 0);
        acc[q][1] = __builtin_amdgcn_mfma_f32_16x16x32_bf16(a, bf1, acc[q][1], 0, 0, 0);
      }
    }
#pragma unroll
    for (int q = 0; q < QB; ++q) {
      float m0 = fmaxf(fmaxf(acc[q][0][0], acc[q][0][1]), fmaxf(acc[q][0][2], acc[q][0][3]));
      float m1 = fmaxf(fmaxf(acc[q][1][0], acc[q][1][1]), fmaxf(acc[q][1][2], acc[q][1][3]));
      m0 = fmaxf(m0, __shfl_xor(m0, 16, 64));
      m0 = fmaxf(m0, __shfl_xor(m0, 32, 64));
      m1 = fmaxf(m1, __shfl_xor(m1, 16, 64));
      m1 = fmaxf(m1, __shfl_xor(m1, 32, 64));
      if (lane < 16) {
        float* ob = out + ((size_t)b * n + q0 + q) * CHID;
        ob[nt * 16 + lane] = m0;
        ob[nt * 16 + 16 + lane] = m1;
      }
    }
  }
}

// -------------------------------------------- up MLP (bf16 MFMA version) ---
template<int CIN, int CPRV, int COUT, int WPB>
__global__ __launch_bounds__(64 * WPB) void up_mfma_kernel(
    const float* __restrict__ xc, int ncoarse,
    const int* __restrict__ idx3, const float* __restrict__ d23,
    const float* __restrict__ prv, const short* __restrict__ Wp,
    const float* __restrict__ bvec, float* __restrict__ out, int m) {
  const int CTOT = CIN + CPRV;
  const int KT = CTOT / 32, NT = COUT / 16;
  __shared__ short sA[16][CTOT + 8];
  __shared__ float sWt[16][3];
  __shared__ int   sIt[16][3];
  int b = blockIdx.y, q0 = blockIdx.x * 16, t = threadIdx.x;
  int lane = t & 63, wv = t >> 6;
  if (t < 16) {
    size_t base = ((size_t)b * m + q0 + t) * 3;
    float d0 = d23[base + 0], d1 = d23[base + 1], d2v = d23[base + 2];
    float w0 = 1.f / (d0 + 1e-8f), w1 = 1.f / (d1 + 1e-8f), w2 = 1.f / (d2v + 1e-8f);
    float s = w0 + w1 + w2;
    sWt[t][0] = w0 / s; sWt[t][1] = w1 / s; sWt[t][2] = w2 / s;
    sIt[t][0] = idx3[base + 0]; sIt[t][1] = idx3[base + 1]; sIt[t][2] = idx3[base + 2];
  }
  __syncthreads();
  const float* xb = xc + (size_t)b * ncoarse * CIN;
  const float* pvb = prv + ((size_t)b * m + q0) * CPRV;
  for (int e = t; e < 16 * CIN; e += 64 * WPB) {
    int p = e / CIN, c = e % CIN;
    float v = sWt[p][0] * xb[(size_t)sIt[p][0] * CIN + c]
            + sWt[p][1] * xb[(size_t)sIt[p][1] * CIN + c]
            + sWt[p][2] * xb[(size_t)sIt[p][2] * CIN + c];
    sA[p][c] = f2bf(v);
  }
  for (int e = t; e < 16 * CPRV; e += 64 * WPB) {
    int p = e / CPRV, c = e % CPRV;
    sA[p][CIN + c] = f2bf(pvb[(size_t)p * CPRV + c]);
  }
  __syncthreads();
  int col = lane & 15, quad = lane >> 4;
  const bf8_t* Wt = (const bf8_t*)Wp;
  float* ob = out + ((size_t)b * m + q0) * COUT;
  for (int nt = 2 * wv; nt < NT; nt += 2 * WPB) {
    float bb0 = bvec[nt * 16 + col], bb1 = bvec[nt * 16 + 16 + col];
    f4_t acc0 = {bb0, bb0, bb0, bb0}, acc1 = {bb1, bb1, bb1, bb1};
#pragma unroll
    for (int kt = 0; kt < KT; ++kt) {
      bf8_t a = *(const bf8_t*)&sA[col][kt * 32 + quad * 8];
      bf8_t bf0 = Wt[(kt * NT + nt) * 64 + lane];
      bf8_t bf1 = Wt[(kt * NT + nt + 1) * 64 + lane];
      acc0 = __builtin_amdgcn_mfma_f32_16x16x32_bf16(a, bf0, acc0, 0, 0, 0);
      acc1 = __builtin_amdgcn_mfma_f32_16x16x32_bf16(a, bf1, acc1, 0, 0, 0);
    }
#pragma unroll
    for (int r = 0; r < 4; ++r) {
      ob[(size_t)(quad * 4 + r) * COUT + nt * 16 + col] = fmaxf(acc0[r], 0.f);
      ob[(size_t)(quad * 4 + r) * COUT + nt * 16 + 16 + col] = fmaxf(acc1[r], 0.f);
    }
  }
}

// ------------------------------------- fused up2 + final MLP (bf16 MFMA) ---
__global__ __launch_bounds__(128) void up2f_mfma_kernel(
    const float* __restrict__ xc,
    const int* __restrict__ idx3, const float* __restrict__ d23,
    const float* __restrict__ x0, const float* __restrict__ pos0,
    const short* __restrict__ u2Wp, const float* __restrict__ u2b,
    const short* __restrict__ fW1p, const float* __restrict__ fb1,
    const short* __restrict__ fW2p, const float* __restrict__ fb2,
    float* __restrict__ out) {
  __shared__ short sA[16][168];
  __shared__ short sB[16][136];
  __shared__ float sWt[16][3];
  __shared__ int   sIt[16][3];
  int b = blockIdx.y, q0 = blockIdx.x * 16, t = threadIdx.x;
  int lane = t & 63, wv = t >> 6;
  if (t < 16) {
    size_t base = ((size_t)b * NFULL + q0 + t) * 3;
    float d0 = d23[base + 0], d1 = d23[base + 1], d2v = d23[base + 2];
    float w0 = 1.f / (d0 + 1e-8f), w1 = 1.f / (d1 + 1e-8f), w2 = 1.f / (d2v + 1e-8f);
    float s = w0 + w1 + w2;
    sWt[t][0] = w0 / s; sWt[t][1] = w1 / s; sWt[t][2] = w2 / s;
    sIt[t][0] = idx3[base + 0]; sIt[t][1] = idx3[base + 1]; sIt[t][2] = idx3[base + 2];
  }
  __syncthreads();
  const float* xb = xc + (size_t)b * 2048 * 128;
#pragma unroll
  for (int p = 0; p < 16; ++p) {
    float v = sWt[p][0] * xb[(size_t)sIt[p][0] * 128 + t]
            + sWt[p][1] * xb[(size_t)sIt[p][1] * 128 + t]
            + sWt[p][2] * xb[(size_t)sIt[p][2] * 128 + t];
    sA[p][t] = f2bf(v);
  }
  for (int e = t; e < 16 * 32; e += 128) {
    int p = e / 32, c = 128 + (e % 32);
    float v = 0.f;
    if (c < 131) v = x0[((size_t)b * NFULL + q0 + p) * 3 + (c - 128)];
    else if (c < 134) v = pos0[((size_t)b * NFULL + q0 + p) * 3 + (c - 131)];
    sA[p][c] = f2bf(v);
  }
  __syncthreads();
  int col = lane & 15, quad = lane >> 4;

  bf8_t a1[5];
#pragma unroll
  for (int kt = 0; kt < 5; ++kt)
    a1[kt] = *(const bf8_t*)&sA[col][kt * 32 + quad * 8];
  const bf8_t* W1t = (const bf8_t*)u2Wp;
  for (int nt = 2 * wv; nt < 8; nt += 4) {
    float bb0 = u2b[nt * 16 + col], bb1 = u2b[nt * 16 + 16 + col];
    f4_t acc0 = {bb0, bb0, bb0, bb0}, acc1 = {bb1, bb1, bb1, bb1};
#pragma unroll
    for (int kt = 0; kt < 5; ++kt) {
      bf8_t bf0 = W1t[(kt * 8 + nt) * 64 + lane];
      bf8_t bf1 = W1t[(kt * 8 + nt + 1) * 64 + lane];
      acc0 = __builtin_amdgcn_mfma_f32_16x16x32_bf16(a1[kt], bf0, acc0, 0, 0, 0);
      acc1 = __builtin_amdgcn_mfma_f32_16x16x32_bf16(a1[kt], bf1, acc1, 0, 0, 0);
    }
#pragma unroll
    for (int r = 0; r < 4; ++r) {
      sB[quad * 4 + r][nt * 16 + col] = f2bf(fmaxf(acc0[r], 0.f));
      sB[quad * 4 + r][nt * 16 + 16 + col] = f2bf(fmaxf(acc1[r], 0.f));
    }
  }
  __syncthreads();

  bf8_t a2[4];
#pragma unroll
  for (int kt = 0; kt < 4; ++kt)
    a2[kt] = *(const bf8_t*)&sB[col][kt * 32 + quad * 8];
  const bf8_t* W2t = (const bf8_t*)fW1p;
  for (int nt = 2 * wv; nt < 8; nt += 4) {
    float bb0 = fb1[nt * 16 + col], bb1 = fb1[nt * 16 + 16 + col];
    f4_t acc0 = {bb0, bb0, bb0, bb0}, acc1 = {bb1, bb1, bb1, bb1};
#pragma unroll
    for (int kt = 0; kt < 4; ++kt) {
      bf8_t bf0 = W2t[(kt * 8 + nt) * 64 + lane];
      bf8_t bf1 = W2t[(kt * 8 + nt + 1) * 64 + lane];
      acc0 = __builtin_amdgcn_mfma_f32_16x16x32_bf16(a2[kt], bf0, acc0, 0, 0, 0);
      acc1 = __builtin_amdgcn_mfma_f32_16x16x32_bf16(a2[kt], bf1, acc1, 0, 0, 0);
    }
#pragma unroll
    for (int r = 0; r < 4; ++r) {
      sA[quad * 4 + r][nt * 16 + col] = f2bf(fmaxf(acc0[r], 0.f));
      sA[quad * 4 + r][nt * 16 + 16 + col] = f2bf(fmaxf(acc1[r], 0.f));
    }
  }
  __syncthreads();

  bf8_t a3[4];
#pragma unroll
  for (int kt = 0; kt < 4; ++kt)
    a3[kt] = *(const bf8_t*)&sA[col][kt * 32 + quad * 8];
  const bf8_t* W3t = (const bf8_t*)fW2p;
  float* ob = out + ((size_t)b * NFULL + q0) * 128;
  for (int nt = 2 * wv; nt < 8; nt += 4) {
    float bb0 = fb2[nt * 16 + col], bb1 = fb2[nt * 16 + 16 + col];
    f4_t acc0 = {bb0, bb0, bb0, bb0}, acc1 = {bb1, bb1, bb1, bb1};
#pragma unroll
    for (int kt = 0; kt < 4; ++kt) {
      bf8_t bf0 = W3t[(kt * 8 + nt) * 64 + lane];
      bf8_t bf1 = W3t[(kt * 8 + nt + 1) * 64 + lane];
      acc0 = __builtin_amdgcn_mfma_f32_16x16x32_bf16(a3[kt], bf0, acc0, 0, 0, 0);
      acc1 = __builtin_amdgcn_mfma_f32_16x16x32_bf16(a3[kt], bf1, acc1, 0, 0, 0);
    }
#pragma unroll
    for (int r = 0; r < 4; ++r) {
      ob[(size_t)(quad * 4 + r) * 128 + nt * 16 + col] = acc0[r];
      ob[(size_t)(quad * 4 + r) * 128 + nt * 16 + 16 + col] = acc1[r];
    }
  }
}

// ------------------------------------------------------------------ launch -
extern "C" void kernel_launch(void* const* d_in, const int* in_sizes, int n_in,
                              void* d_out, int out_size, void* d_ws, size_t ws_size,
                              hipStream_t stream) {
  const float* x    = (const float*)d_in[0];
  const float* pos  = (const float*)d_in[1];
  const float* d0W1 = (const float*)d_in[2];
  const float* d0b1 = (const float*)d_in[3];
  const float* d0W2 = (const float*)d_in[4];
  const float* d0b2 = (const float*)d_in[5];
  const float* d1W1 = (const float*)d_in[6];
  const float* d1b1 = (const float*)d_in[7];
  const float* d1W2 = (const float*)d_in[8];
  const float* d1b2 = (const float*)d_in[9];
  const float* d2W1 = (const float*)d_in[10];
  const float* d2b1 = (const float*)d_in[11];
  const float* d2W2 = (const float*)d_in[12];
  const float* d2b2 = (const float*)d_in[13];
  const float* u0W  = (const float*)d_in[14];
  const float* u0b  = (const float*)d_in[15];
  const float* u1W  = (const float*)d_in[16];
  const float* u1b  = (const float*)d_in[17];
  const float* u2W  = (const float*)d_in[18];
  const float* u2b  = (const float*)d_in[19];
  const float* fW1  = (const float*)d_in[20];
  const float* fb1  = (const float*)d_in[21];
  const float* fW2  = (const float*)d_in[22];
  const float* fb2  = (const float*)d_in[23];

  char* ws = (char*)d_ws;
  float* x1    = (float*)(ws + 0);
  float* x2    = (float*)(ws + 4194304);
  float* x3    = (float*)(ws + 6291456);
  float* up0o  = (float*)(ws + 7340032);
  float* up1o  = (float*)(ws + 9437184);
  int*   idx0  = (int*)  (ws + 13631488);
  int*   idx1  = (int*)  (ws + 14155776);
  int*   idx2  = (int*)  (ws + 14286848);
  float4* sortedC = (float4*)(ws + 14319616); // 4*512*16 = 32768
  int*    csC     = (int*)   (ws + 14352384); // 4*513*4  = 8208
  int*   idxu0 = (int*)  (ws + 14843904);
  float* d2u0  = (float*)(ws + 14868480);
  int*   idxu1 = (int*)  (ws + 14893056);
  float* d2u1  = (float*)(ws + 14991360);
  int*   idxu2 = (int*)  (ws + 15089664);
  float* d2u2  = (float*)(ws + 15482880);
  short* d1W1p = (short*)(ws + 15876096);
  short* d1W2p = (short*)(ws + 15958016);
  short* d2W1p = (short*)(ws + 16089088);
  short* d2W2p = (short*)(ws + 16384000);
  short* d0W1p = (short*)(ws + 16908288);
  short* d0W2p = (short*)(ws + 16916480);
  float4* sortedA = (float4*)(ws + 16949248);  // 4*8192*16 = 524288
  int*    csA     = (int*)   (ws + 17473536);  // 4*4097*4  = 65552
  float4* sortedB = (float4*)(ws + 17539136);  // 4*2048*16 = 131072
  int*    csB     = (int*)   (ws + 17670208);  // 4*513*4   = 8208
  short* u2Wp  = (short*)(ws + 17697920);
  short* fW1p  = (short*)(ws + 17738880);
  short* fW2p  = (short*)(ws + 17771648);

  float* out = (float*)d_out;
  // Packed u0W/u1W live in the d_out main region: it is dead until the final
  // up2f_mfma_kernel writes it, and both are fully consumed before that.
  short* u0Wp = (short*)out;                       // 768*256*2 = 393216 B
  short* u1Wp = (short*)(out + 98304);             // 384*128*2 =  98304 B

  // ---- pre: grids + packing + pos copy + brute kNN (idx2, idxu0) ----
  pre_kernel<<<dim3(708), 256, 0, stream>>>(
      pos, sortedA, csA, sortedB, csB, sortedC, csC,
      d0W1, d0W1p, d0W2, d0W2p, d1W1, d1W1p, d1W2, d1W2p,
      d2W1, d2W1p, d2W2, d2W2p, u2W, u2Wp, fW1, fW1p, fW2, fW2p,
      u0W, u0Wp, u1W, u1Wp,
      out + (size_t)BATCH * NFULL * 128,
      idx2, idxu0, d2u0);

  // ---- fused kNN: g64 K=16 near-first (idx1, idx0) + K=3 overlap ----
  knn_kernel<<<dim3(1280, BATCH), 256, 0, stream>>>(
      pos, sortedA, csA, sortedB, csB, sortedC, csC,
      idx0, idx1, idxu1, d2u1, idxu2, d2u2);

  // ---- down path ----
  down_mfma_kernel<6, 3, 128, 32, 4, 4><<<dim3(512, BATCH), 256, 0, stream>>>(
      pos, x, idx0, d0W1p, d0b1, d0W2p, d0b2, x1, 2048, 8192);
  down_mfma_kernel<131, 128, 256, 160, 4, 8><<<dim3(128, BATCH), 512, 0, stream>>>(
      pos, x1, idx1, d1W1p, d1b1, d1W2p, d1b2, x2, 512, 2048);
  down_mfma_kernel<259, 256, 512, 288, 2, 8><<<dim3(64, BATCH), 512, 0, stream>>>(
      pos, x2, idx2, d2W1p, d2b1, d2W2p, d2b2, x3, 128, 512);

  // ---- up path ----
  up_mfma_kernel<512, 256, 256, 4><<<dim3(32, BATCH), 256, 0, stream>>>(
      x3, 128, idxu0, d2u0, x2, u0Wp, u0b, up0o, 512);
  up_mfma_kernel<256, 128, 128, 2><<<dim3(128, BATCH), 128, 0, stream>>>(
      up0o, 512, idxu1, d2u1, x1, u1Wp, u1b, up1o, 2048);
  up2f_mfma_kernel<<<dim3(512, BATCH), 128, 0, stream>>>(
      up1o, idxu2, d2u2, x, pos, u2Wp, u2b, fW1p, fb1, fW2p, fb2, out);
}

// Round 13
// 269.483 us; speedup vs baseline: 1.0890x; 1.0027x over previous
//
#include <hip/hip_runtime.h>

#define NFULL 8192
#define BATCH 4

typedef unsigned long long u64;
typedef unsigned int u32;
typedef __attribute__((ext_vector_type(8))) short bf8_t;   // 8 bf16 (4 VGPRs)
typedef __attribute__((ext_vector_type(4))) float f4_t;    // MFMA C/D

__device__ __forceinline__ u32 fbias(float f) {
  u32 u = __float_as_uint(f);
  return (u & 0x80000000u) ? ~u : (u | 0x80000000u);
}
__device__ __forceinline__ float funbias(u32 b) {
  u32 u = (b & 0x80000000u) ? (b & 0x7fffffffu) : ~b;
  return __uint_as_float(u);
}
__device__ __forceinline__ short f2bf(float f) {
  u32 u = __float_as_uint(f);
  u32 r = u + 0x7FFFu + ((u >> 16) & 1u);
  return (short)(r >> 16);
}

// ================= K=16 window-insert primitives ===========================
__device__ __forceinline__ void group_insert_g64(u64 m64, u64 ck, int slot16,
                                                 u64& val, u64& tau) {
  if (m64) {
    while (m64) {
      int src = __ffsll((unsigned long long)m64) - 1;
      m64 &= m64 - 1;
      u64 c = __shfl((unsigned long long)ck, src, 64);
      u64 prev = __shfl_up((unsigned long long)val, 1, 16);
      if (slot16 == 0) prev = 0ull;
      val = (val <= c) ? val : ((prev <= c) ? c : prev);
    }
    tau = __shfl((unsigned long long)val, 15, 16);
  }
}

// Round-1 bulk build: 21-stage bitonic sort of first 64 candidates (g64).
__device__ __forceinline__ void first_round_sort64(u64 ck, int gl,
                                                   u64& val, u64& tau) {
  u64 v = ck;
#pragma unroll
  for (int size = 2; size <= 64; size <<= 1) {
#pragma unroll
    for (int stride = size >> 1; stride > 0; stride >>= 1) {
      u64 other = __shfl_xor((unsigned long long)v, stride, 64);
      bool ddd = ((gl & size) == 0);
      bool takeMin = (((gl & stride) == 0) == ddd);
      u64 mn = (v <= other) ? v : other;
      u64 mx = (v <= other) ? other : v;
      v = takeMin ? mn : mx;
    }
  }
  val = __shfl((unsigned long long)v, gl & 15, 64);
  tau = __shfl((unsigned long long)val, 15, 16);
}

__device__ __forceinline__ void scan_range_g64(const float4* __restrict__ sb,
    int s, int e, float qx, float qy, float qz, float qq,
    int lane, int slot16, u64& val, u64& tau) {
  for (int t0 = s; t0 < e; t0 += 64) {
    int j = t0 + lane;
    u64 ck = ~0ull;
    if (j < e) {
      float4 P = sb[j];
      float rr = P.x * P.x + P.y * P.y + P.z * P.z;
      float d2 = qq + rr - 2.0f * (qx * P.x + qy * P.y + qz * P.z);
      ck = ((u64)fbias(d2) << 32) | (u32)__float_as_uint(P.w);
    }
    u64 m64 = __ballot(ck < tau);
    group_insert_g64(m64, ck, slot16, val, tau);
  }
}

// Exactness: after scanning box B, if the Kth smallest d2 is strictly less
// than the squared distance to the nearest NON-clipped face of B, no outside
// point can enter the top-K. Ring expansion scans box(R+1)\box(R) exactly
// once per point (flattened over <=34 segments); insertion ORDER does not
// affect the selected set (unique u64 keys) so tie-breaking matches the
// reference top_k. Full fallback remains the final guard.
template<int GR, int R, int NREF>
__device__ __forceinline__ void knn_tail16_g64(
    const float4* __restrict__ sb, const int* __restrict__ cs,
    float qx, float qy, float qz, float qq,
    int ix, int iy, int iz, int x0, int x1, int y0, int y1, int z0, int z1,
    int lane, int slot16, u64& val, u64& tau) {
  const float h = 1.0f / GR;
  float m = 1e30f;
  if (x0 > 0)      m = fminf(m, qx - x0 * h);
  if (x1 < GR - 1) m = fminf(m, (x1 + 1) * h - qx);
  if (y0 > 0)      m = fminf(m, qy - y0 * h);
  if (y1 < GR - 1) m = fminf(m, (y1 + 1) * h - qy);
  if (z0 > 0)      m = fminf(m, qz - z0 * h);
  if (z1 < GR - 1) m = fminf(m, (z1 + 1) * h - qz);
  float bound = m * m;
  float kth_d2 = funbias((u32)(tau >> 32));
  if (!(kth_d2 < bound)) {  // wave-uniform (1 query/wave)
    // ---- flattened ring scan: box(R+1)\box(R) over <=34 segments ----
    int X0 = max(ix - (R + 1), 0), X1 = min(ix + (R + 1), GR - 1);
    int Y0 = max(iy - (R + 1), 0), Y1 = min(iy + (R + 1), GR - 1);
    int Z0 = max(iz - (R + 1), 0), Z1 = min(iz + (R + 1), GR - 1);
    int NY2 = Y1 - Y0 + 1;
    int nrow2 = (Z1 - Z0 + 1) * NY2;
    int nyO = y1 - y0 + 1;
    int nmid = (z1 - z0 + 1) * nyO;
    int nseg = nrow2 + nmid;  // <= 25 + 9 = 34
    int s_i = 0, len_i = 0;
    if (lane < nrow2) {
      int zz = Z0 + lane / NY2, yy = Y0 + lane % NY2;
      int c0 = (zz * GR + yy) * GR;
      bool mid = (zz >= z0 && zz <= z1 && yy >= y0 && yy <= y1);
      s_i = cs[c0 + X0];
      len_i = (mid ? cs[c0 + x0] : cs[c0 + X1 + 1]) - s_i;
    } else if (lane < nseg) {
      int i = lane - nrow2;
      int zz = z0 + i / nyO, yy = y0 + i % nyO;
      int c0 = (zz * GR + yy) * GR;
      s_i = cs[c0 + x1 + 1];
      len_i = cs[c0 + X1 + 1] - s_i;
    }
    int p_i = len_i;
#pragma unroll
    for (int st = 1; st < 64; st <<= 1) {
      int o = __shfl_up(p_i, st, 64);
      if (lane >= st) p_i += o;
    }
    int T2 = __shfl(p_i, 63, 64);
    p_i -= len_i;
    int d_i = s_i - p_i;
    if (lane >= nseg) p_i = 0x7fffffff;

    for (int v0 = 0; v0 < T2; v0 += 64) {
      int v = v0 + lane;
      int r = 0;
#pragma unroll
      for (int st = 32; st >= 1; st >>= 1) {
        int pc = __shfl(p_i, r + st, 64);
        if (v >= pc) r += st;
      }
      int addr = v + __shfl(d_i, r, 64);
      u64 ck = ~0ull;
      if (v < T2) {
        float4 P = sb[addr];
        float rr = P.x * P.x + P.y * P.y + P.z * P.z;
        float d2 = qq + rr - 2.0f * (qx * P.x + qy * P.y + qz * P.z);
        ck = ((u64)fbias(d2) << 32) | (u32)__float_as_uint(P.w);
      }
      u64 m64 = __ballot(ck < tau);
      group_insert_g64(m64, ck, slot16, val, tau);
    }

    x0 = X0; x1 = X1; y0 = Y0; y1 = Y1; z0 = Z0; z1 = Z1;
    m = 1e30f;
    if (x0 > 0)      m = fminf(m, qx - x0 * h);
    if (x1 < GR - 1) m = fminf(m, (x1 + 1) * h - qx);
    if (y0 > 0)      m = fminf(m, qy - y0 * h);
    if (y1 < GR - 1) m = fminf(m, (y1 + 1) * h - qy);
    if (z0 > 0)      m = fminf(m, qz - z0 * h);
    if (z1 < GR - 1) m = fminf(m, (z1 + 1) * h - qz);
    bound = m * m;
    kth_d2 = funbias((u32)(tau >> 32));
    if (!(kth_d2 < bound)) {  // essentially unreachable
      for (int t0 = 0; t0 < NREF; t0 += 64) {
        int j = t0 + lane;
        u64 ck = ~0ull;
        if (j < NREF) {
          float4 P = sb[j];
          int cx = min(max((int)(P.x * GR), 0), GR - 1);
          int cy = min(max((int)(P.y * GR), 0), GR - 1);
          int cz = min(max((int)(P.z * GR), 0), GR - 1);
          bool inbox = (cx >= x0 && cx <= x1 && cy >= y0 && cy <= y1 &&
                        cz >= z0 && cz <= z1);
          if (!inbox) {
            float rr = P.x * P.x + P.y * P.y + P.z * P.z;
            float d2 = qq + rr - 2.0f * (qx * P.x + qy * P.y + qz * P.z);
            ck = ((u64)fbias(d2) << 32) | (u32)__float_as_uint(P.w);
          }
        }
        u64 m64 = __ballot(ck < tau);
        group_insert_g64(m64, ck, slot16, val, tau);
      }
    }
  }
}

// ---------------- K=16 grid, one query per 64-lane wave --------------------
// R=1: the near box is scanned FIRST (round-1 bitonic covers ~all of it ->
// near-final tau), the R=2 ring then runs as cheap ballot-skip rounds.
template<int GR, int R, int NREF>
__device__ void knn_grid16_g64_dev(int vbx, int b,
    const float* __restrict__ pos, const float4* __restrict__ sorted,
    const int* __restrict__ cellStart, int csStride, int Mq,
    int* __restrict__ oidx) {
  int wv = threadIdx.x >> 6, lane = threadIdx.x & 63;
  int q = vbx * 4 + wv;
  const float* pb = pos + (size_t)b * NFULL * 3;
  const float4* sb = sorted + (size_t)b * NREF;
  const int* cs = cellStart + b * csStride;
  float qx = pb[q * 3 + 0], qy = pb[q * 3 + 1], qz = pb[q * 3 + 2];
  float qq = qx * qx + qy * qy + qz * qz;
  int ix = min(max((int)(qx * GR), 0), GR - 1);
  int iy = min(max((int)(qy * GR), 0), GR - 1);
  int iz = min(max((int)(qz * GR), 0), GR - 1);
  int x0 = max(ix - R, 0), x1 = min(ix + R, GR - 1);
  int y0 = max(iy - R, 0), y1 = min(iy + R, GR - 1);
  int z0 = max(iz - R, 0), z1 = min(iz + R, GR - 1);

  int ny = y1 - y0 + 1;
  int nrow = (z1 - z0 + 1) * ny;  // <= 9 for R=1
  int s_i = 0, len_i = 0;
  if (lane < nrow) {
    int zz = z0 + lane / ny, yy = y0 + lane % ny;
    int c0 = (zz * GR + yy) * GR + x0;
    s_i = cs[c0];
    len_i = cs[c0 + (x1 - x0) + 1] - s_i;
  }
  int p_i = len_i;
#pragma unroll
  for (int st = 1; st < 64; st <<= 1) {
    int o = __shfl_up(p_i, st, 64);
    if (lane >= st) p_i += o;
  }
  int T = __shfl(p_i, 63, 64);
  p_i -= len_i;              // exclusive prefix
  int d_i = s_i - p_i;       // sorted index = v + d_row
  if (lane >= nrow) p_i = 0x7fffffff;

  int slot16 = lane & 15;
  u64 val, tau;

  // ---- round 1: 64-candidate bitonic bulk build
  {
    int v = lane;
    int r = 0;
#pragma unroll
    for (int st = 32; st >= 1; st >>= 1) {
      int pc = __shfl(p_i, r + st, 64);
      if (v >= pc) r += st;
    }
    int addr = v + __shfl(d_i, r, 64);
    u64 ck = ~0ull;
    if (v < T) {
      float4 P = sb[addr];
      float rr = P.x * P.x + P.y * P.y + P.z * P.z;
      float d2 = qq + rr - 2.0f * (qx * P.x + qy * P.y + qz * P.z);
      ck = ((u64)fbias(d2) << 32) | (u32)__float_as_uint(P.w);
    }
    first_round_sort64(ck, lane, val, tau);
  }

  for (int v0 = 64; v0 < T; v0 += 64) {  // T wave-uniform
    int v = v0 + lane;
    int r = 0;
#pragma unroll
    for (int st = 32; st >= 1; st >>= 1) {
      int pc = __shfl(p_i, r + st, 64);
      if (v >= pc) r += st;
    }
    int addr = v + __shfl(d_i, r, 64);
    u64 ck = ~0ull;
    if (v < T) {
      float4 P = sb[addr];
      float rr = P.x * P.x + P.y * P.y + P.z * P.z;
      float d2 = qq + rr - 2.0f * (qx * P.x + qy * P.y + qz * P.z);
      ck = ((u64)fbias(d2) << 32) | (u32)__float_as_uint(P.w);
    }
    u64 m64 = __ballot(ck < tau);
    group_insert_g64(m64, ck, slot16, val, tau);
  }

  knn_tail16_g64<GR, R, NREF>(sb, cs, qx, qy, qz, qq,
      ix, iy, iz, x0, x1, y0, y1, z0, z1, lane, slot16, val, tau);

  if (lane < 16) {
    size_t base = ((size_t)b * Mq + q) * 16;
    oidx[base + lane] = (int)(u32)val;
  }
}

// ----------------------------------------------- K=16 brute (64-lane) ------
// One query per wave: round-1 bitonic over first 64 candidates, then g64
// ballot-filtered insert rounds (Nref/64 - 1 of them).
__device__ void knn_brute16_g64_dev(int vbx, int b,
    const float* __restrict__ pos, int Nref, int Mq, int* __restrict__ oidx) {
  int wv = threadIdx.x >> 6, lane = threadIdx.x & 63;
  int q = vbx * 4 + wv;
  const float* pb = pos + (size_t)b * NFULL * 3;
  float qx = pb[q * 3 + 0], qy = pb[q * 3 + 1], qz = pb[q * 3 + 2];
  float qq = qx * qx + qy * qy + qz * qz;

  int slot16 = lane & 15;
  u64 val, tau;

  {
    int j = lane;
    float rx = pb[j * 3 + 0];
    float ry = pb[j * 3 + 1];
    float rz = pb[j * 3 + 2];
    float rr = rx * rx + ry * ry + rz * rz;
    float d2 = qq + rr - 2.0f * (qx * rx + qy * ry + qz * rz);
    u64 ck = ((u64)fbias(d2) << 32) | (u32)j;
    first_round_sort64(ck, lane, val, tau);
  }

  for (int t0 = 64; t0 < Nref; t0 += 64) {
    int j = t0 + lane;
    float rx = pb[j * 3 + 0];
    float ry = pb[j * 3 + 1];
    float rz = pb[j * 3 + 2];
    float rr = rx * rx + ry * ry + rz * rz;
    float d2 = qq + rr - 2.0f * (qx * rx + qy * ry + qz * rz);
    u64 ck = ((u64)fbias(d2) << 32) | (u32)j;
    u64 m64 = __ballot(ck < tau);
    group_insert_g64(m64, ck, slot16, val, tau);
  }

  if (lane < 16) {
    size_t base = ((size_t)b * Mq + q) * 16;
    oidx[base + lane] = (int)(u32)val;
  }
}

// ================= K=3 machinery (16 lanes/query, per-lane top-3) ==========
__device__ __forceinline__ void lane_insert3(u64 ck, u64& v0, u64& v1, u64& v2) {
  u64 a = (v0 <= ck) ? v0 : ck;
  u64 bb = (v0 <= ck) ? ck : v0;
  v0 = a;
  u64 c = (v1 <= bb) ? v1 : bb;
  u64 d = (v1 <= bb) ? bb : v1;
  v1 = c;
  v2 = (v2 <= d) ? v2 : d;
}

__device__ __forceinline__ void merge3(u64 v0, u64 v1, u64 v2,
                                       u64& o0, u64& o1, u64& o2) {
  u64 h = v0;
  int hc = 0;
  u64 outs[3];
#pragma unroll
  for (int k = 0; k < 3; ++k) {
    u64 m = h;
#pragma unroll
    for (int st = 1; st < 16; st <<= 1) {
      u64 o = __shfl_xor((unsigned long long)m, st, 16);
      m = (m <= o) ? m : o;
    }
    outs[k] = m;
    if (h == m) { ++hc; h = (hc == 1) ? v1 : ((hc == 2) ? v2 : ~0ull); }
  }
  o0 = outs[0]; o1 = outs[1]; o2 = outs[2];
}

__device__ __forceinline__ void scan_range3(const float4* __restrict__ sb,
    int s, int e, float qx, float qy, float qz, float qq,
    int gl, u64& v0, u64& v1, u64& v2) {
  for (int t0 = s; t0 < e; t0 += 16) {
    int j = t0 + gl;
    if (j < e) {
      float4 P = sb[j];
      float rr = P.x * P.x + P.y * P.y + P.z * P.z;
      float d2 = qq + rr - 2.0f * (qx * P.x + qy * P.y + qz * P.z);
      u64 ck = ((u64)fbias(d2) << 32) | (u32)__float_as_uint(P.w);
      lane_insert3(ck, v0, v1, v2);
    }
  }
}

template<int GR, int R, int NREF>
__device__ __forceinline__ void knn_tail3(
    const float4* __restrict__ sb, const int* __restrict__ cs,
    float qx, float qy, float qz, float qq,
    int ix, int iy, int iz, int x0, int x1, int y0, int y1, int z0, int z1,
    int gl, u64& v0, u64& v1, u64& v2, u64& o0, u64& o1, u64& o2) {
  const float h = 1.0f / GR;
  float m = 1e30f;
  if (x0 > 0)      m = fminf(m, qx - x0 * h);
  if (x1 < GR - 1) m = fminf(m, (x1 + 1) * h - qx);
  if (y0 > 0)      m = fminf(m, qy - y0 * h);
  if (y1 < GR - 1) m = fminf(m, (y1 + 1) * h - qy);
  if (z0 > 0)      m = fminf(m, qz - z0 * h);
  if (z1 < GR - 1) m = fminf(m, (z1 + 1) * h - qz);
  float bound = m * m;
  merge3(v0, v1, v2, o0, o1, o2);
  float kth_d2 = funbias((u32)(o2 >> 32));
  if (!(kth_d2 < bound)) {  // group-uniform; rare
    int X0 = max(ix - (R + 1), 0), X1 = min(ix + (R + 1), GR - 1);
    int Y0 = max(iy - (R + 1), 0), Y1 = min(iy + (R + 1), GR - 1);
    int Z0 = max(iz - (R + 1), 0), Z1 = min(iz + (R + 1), GR - 1);
    int NY2 = Y1 - Y0 + 1;
    int nrow2 = (Z1 - Z0 + 1) * NY2;
    for (int rr2 = 0; rr2 < nrow2; ++rr2) {
      int zz = Z0 + rr2 / NY2, yy = Y0 + rr2 % NY2;
      int c0 = (zz * GR + yy) * GR;
      bool mid = (zz >= z0 && zz <= z1 && yy >= y0 && yy <= y1);
      int s1 = cs[c0 + X0];
      int e1 = mid ? cs[c0 + x0] : cs[c0 + X1 + 1];
      scan_range3(sb, s1, e1, qx, qy, qz, qq, gl, v0, v1, v2);
      if (mid) {
        int s2 = cs[c0 + x1 + 1];
        int e2 = cs[c0 + X1 + 1];
        scan_range3(sb, s2, e2, qx, qy, qz, qq, gl, v0, v1, v2);
      }
    }
    x0 = X0; x1 = X1; y0 = Y0; y1 = Y1; z0 = Z0; z1 = Z1;
    m = 1e30f;
    if (x0 > 0)      m = fminf(m, qx - x0 * h);
    if (x1 < GR - 1) m = fminf(m, (x1 + 1) * h - qx);
    if (y0 > 0)      m = fminf(m, qy - y0 * h);
    if (y1 < GR - 1) m = fminf(m, (y1 + 1) * h - qy);
    if (z0 > 0)      m = fminf(m, qz - z0 * h);
    if (z1 < GR - 1) m = fminf(m, (z1 + 1) * h - qz);
    bound = m * m;
    merge3(v0, v1, v2, o0, o1, o2);
    kth_d2 = funbias((u32)(o2 >> 32));
    if (!(kth_d2 < bound)) {  // essentially unreachable
      for (int t0 = 0; t0 < NREF; t0 += 16) {
        int j = t0 + gl;
        if (j < NREF) {
          float4 P = sb[j];
          int cx = min(max((int)(P.x * GR), 0), GR - 1);
          int cy = min(max((int)(P.y * GR), 0), GR - 1);
          int cz = min(max((int)(P.z * GR), 0), GR - 1);
          bool inbox = (cx >= x0 && cx <= x1 && cy >= y0 && cy <= y1 &&
                        cz >= z0 && cz <= z1);
          if (!inbox) {
            float rr = P.x * P.x + P.y * P.y + P.z * P.z;
            float d2 = qq + rr - 2.0f * (qx * P.x + qy * P.y + qz * P.z);
            u64 ck = ((u64)fbias(d2) << 32) | (u32)__float_as_uint(P.w);
            lane_insert3(ck, v0, v1, v2);
          }
        }
      }
      merge3(v0, v1, v2, o0, o1, o2);
    }
  }
}

template<int GR, int R, int NREF>
__device__ void knn_grid_flat3_dev(int vbx, int b,
    const float* __restrict__ pos, const float4* __restrict__ sorted,
    const int* __restrict__ cellStart, int csStride, int Mq,
    int* __restrict__ oidx, float* __restrict__ od2) {
  int wv = threadIdx.x >> 6, lane = threadIdx.x & 63;
  int g = lane >> 4, gl = lane & 15;
  int q = vbx * 16 + wv * 4 + g;
  const float* pb = pos + (size_t)b * NFULL * 3;
  const float4* sb = sorted + (size_t)b * NREF;
  const int* cs = cellStart + b * csStride;
  float qx = pb[q * 3 + 0], qy = pb[q * 3 + 1], qz = pb[q * 3 + 2];
  float qq = qx * qx + qy * qy + qz * qz;
  int ix = min(max((int)(qx * GR), 0), GR - 1);
  int iy = min(max((int)(qy * GR), 0), GR - 1);
  int iz = min(max((int)(qz * GR), 0), GR - 1);
  int x0 = max(ix - R, 0), x1 = min(ix + R, GR - 1);
  int y0 = max(iy - R, 0), y1 = min(iy + R, GR - 1);
  int z0 = max(iz - R, 0), z1 = min(iz + R, GR - 1);

  int ny = y1 - y0 + 1;
  int nrow = (z1 - z0 + 1) * ny;  // <= 9 for R=1
  int s_i = 0, len_i = 0;
  if (gl < nrow) {
    int zz = z0 + gl / ny, yy = y0 + gl % ny;
    int c0 = (zz * GR + yy) * GR + x0;
    s_i = cs[c0];
    len_i = cs[c0 + (x1 - x0) + 1] - s_i;
  }
  int p_i = len_i;
#pragma unroll
  for (int st = 1; st < 16; st <<= 1) {
    int o = __shfl_up(p_i, st, 16);
    if (gl >= st) p_i += o;
  }
  int T = __shfl(p_i, 15, 16);
  p_i -= len_i;              // exclusive prefix
  int d_i = s_i - p_i;       // sorted index = v + d_row
  if (gl >= nrow) p_i = 0x7fffffff;

  u64 v0 = ~0ull, v1 = ~0ull, v2 = ~0ull;

  for (int vb = 0; vb < T; vb += 16) {  // T group-uniform
    int v = vb + gl;
    int r = 0;
#pragma unroll
    for (int st = 8; st >= 1; st >>= 1) {
      int pc = __shfl(p_i, r + st, 16);
      if (v >= pc) r += st;
    }
    int addr = v + __shfl(d_i, r, 16);
    if (v < T) {
      float4 P = sb[addr];
      float rr = P.x * P.x + P.y * P.y + P.z * P.z;
      float d2 = qq + rr - 2.0f * (qx * P.x + qy * P.y + qz * P.z);
      u64 ck = ((u64)fbias(d2) << 32) | (u32)__float_as_uint(P.w);
      lane_insert3(ck, v0, v1, v2);
    }
  }

  u64 o0, o1, o2;
  knn_tail3<GR, R, NREF>(sb, cs, qx, qy, qz, qq,
      ix, iy, iz, x0, x1, y0, y1, z0, z1, gl, v0, v1, v2, o0, o1, o2);

  if (gl < 3) {
    u64 val = (gl == 0) ? o0 : ((gl == 1) ? o1 : o2);
    size_t base = ((size_t)b * Mq + q) * 3;
    oidx[base + gl] = (int)(u32)val;
    od2[base + gl] = fmaxf(funbias((u32)(val >> 32)), 0.0f);
  }
}

template<int GR, int R, int NREF>
__device__ void knn_grid_flat32_3_dev(int vbx, int b,
    const float* __restrict__ pos, const float4* __restrict__ sorted,
    const int* __restrict__ cellStart, int csStride, int Mq,
    int* __restrict__ oidx, float* __restrict__ od2) {
  int wv = threadIdx.x >> 6, lane = threadIdx.x & 63;
  int g = lane >> 4, gl = lane & 15;
  int q = vbx * 16 + wv * 4 + g;
  const float* pb = pos + (size_t)b * NFULL * 3;
  const float4* sb = sorted + (size_t)b * NREF;
  const int* cs = cellStart + b * csStride;
  float qx = pb[q * 3 + 0], qy = pb[q * 3 + 1], qz = pb[q * 3 + 2];
  float qq = qx * qx + qy * qy + qz * qz;
  int ix = min(max((int)(qx * GR), 0), GR - 1);
  int iy = min(max((int)(qy * GR), 0), GR - 1);
  int iz = min(max((int)(qz * GR), 0), GR - 1);
  int x0 = max(ix - R, 0), x1 = min(ix + R, GR - 1);
  int y0 = max(iy - R, 0), y1 = min(iy + R, GR - 1);
  int z0 = max(iz - R, 0), z1 = min(iz + R, GR - 1);

  int ny = y1 - y0 + 1;
  int nrow = (z1 - z0 + 1) * ny;  // <= 25 for R=2
  int sLo = 0, lenLo = 0, sHi = 0, lenHi = 0;
  if (gl < nrow) {
    int zz = z0 + gl / ny, yy = y0 + gl % ny;
    int c0 = (zz * GR + yy) * GR + x0;
    sLo = cs[c0]; lenLo = cs[c0 + (x1 - x0) + 1] - sLo;
  }
  {
    int i2 = gl + 16;
    if (i2 < nrow) {
      int zz = z0 + i2 / ny, yy = y0 + i2 % ny;
      int c0 = (zz * GR + yy) * GR + x0;
      sHi = cs[c0]; lenHi = cs[c0 + (x1 - x0) + 1] - sHi;
    }
  }
  int pLo = lenLo, pHi = lenHi;
#pragma unroll
  for (int st = 1; st < 16; st <<= 1) {
    int o = __shfl_up(pLo, st, 16);
    if (gl >= st) pLo += o;
    int o2_ = __shfl_up(pHi, st, 16);
    if (gl >= st) pHi += o2_;
  }
  int tot16 = __shfl(pLo, 15, 16);
  pHi += tot16;
  int T = __shfl(pHi, 15, 16);
  pLo -= lenLo; pHi -= lenHi;      // exclusive prefixes
  int dLo = sLo - pLo, dHi = sHi - pHi;
  if (gl >= nrow) pLo = 0x7fffffff;
  if (gl + 16 >= nrow) pHi = 0x7fffffff;

  u64 v0 = ~0ull, v1 = ~0ull, v2 = ~0ull;

  for (int vb = 0; vb < T; vb += 16) {  // T group-uniform
    int v = vb + gl;
    int r = 0;
#pragma unroll
    for (int st = 16; st >= 1; st >>= 1) {
      int j = r + st;                      // j <= 31
      int pcL = __shfl(pLo, j & 15, 16);
      int pcH = __shfl(pHi, j & 15, 16);
      int pc = (j < 16) ? pcL : pcH;
      if (v >= pc) r = j;
    }
    int dL = __shfl(dLo, r & 15, 16);
    int dH = __shfl(dHi, r & 15, 16);
    int addr = v + ((r < 16) ? dL : dH);
    if (v < T) {
      float4 P = sb[addr];
      float rr = P.x * P.x + P.y * P.y + P.z * P.z;
      float d2 = qq + rr - 2.0f * (qx * P.x + qy * P.y + qz * P.z);
      u64 ck = ((u64)fbias(d2) << 32) | (u32)__float_as_uint(P.w);
      lane_insert3(ck, v0, v1, v2);
    }
  }

  u64 o0, o1, o2;
  knn_tail3<GR, R, NREF>(sb, cs, qx, qy, qz, qq,
      ix, iy, iz, x0, x1, y0, y1, z0, z1, gl, v0, v1, v2, o0, o1, o2);

  if (gl < 3) {
    u64 val = (gl == 0) ? o0 : ((gl == 1) ? o1 : o2);
    size_t base = ((size_t)b * Mq + q) * 3;
    oidx[base + gl] = (int)(u32)val;
    od2[base + gl] = fmaxf(funbias((u32)(val >> 32)), 0.0f);
  }
}

__device__ void knn_brute3_dev(int vbx, int b,
    const float* __restrict__ pos, int Nref, int Mq,
    int* __restrict__ oidx, float* __restrict__ od2) {
  int wv = threadIdx.x >> 6, lane = threadIdx.x & 63;
  int g = lane >> 4, gl = lane & 15;
  int q = vbx * 16 + wv * 4 + g;
  const float* pb = pos + (size_t)b * NFULL * 3;
  float qx = pb[q * 3 + 0], qy = pb[q * 3 + 1], qz = pb[q * 3 + 2];
  float qq = qx * qx + qy * qy + qz * qz;

  u64 v0 = ~0ull, v1 = ~0ull, v2 = ~0ull;
  for (int j = gl; j < Nref; j += 16) {
    float rx = pb[j * 3 + 0];
    float ry = pb[j * 3 + 1];
    float rz = pb[j * 3 + 2];
    float rr = rx * rx + ry * ry + rz * rz;
    float d2 = qq + rr - 2.0f * (qx * rx + qy * ry + qz * rz);
    u64 ck = ((u64)fbias(d2) << 32) | (u32)j;
    lane_insert3(ck, v0, v1, v2);
  }
  u64 o0, o1, o2;
  merge3(v0, v1, v2, o0, o1, o2);

  if (gl < 3) {
    u64 val = (gl == 0) ? o0 : ((gl == 1) ? o1 : o2);
    size_t base = ((size_t)b * Mq + q) * 3;
    oidx[base + gl] = (int)(u32)val;
    od2[base + gl] = fmaxf(funbias((u32)(val >> 32)), 0.0f);
  }
}

// ----------------------------------- fused weight packing helpers ---------
__device__ __forceinline__ void pack_tile_rt(const float* __restrict__ W,
                                             short* __restrict__ outp,
                                             int KDIM, int N, int tile, int lane) {
  int NT = N >> 4;
  int kt = tile / NT, nt = tile - kt * NT;
  int n = nt * 16 + (lane & 15);
  int k0 = kt * 32 + (lane >> 4) * 8;
  bf8_t v;
#pragma unroll
  for (int j = 0; j < 8; ++j) {
    int k = k0 + j;
    v[j] = (k < KDIM) ? f2bf(W[(size_t)k * N + n]) : (short)0;
  }
  *(bf8_t*)(outp + ((size_t)tile * 64 + lane) * 8) = v;
}

__device__ void pack_dispatch(int blk, int lane,
    const float* d0W1, short* d0W1p, const float* d0W2, short* d0W2p,
    const float* d1W1, short* d1W1p, const float* d1W2, short* d1W2p,
    const float* d2W1, short* d2W1p, const float* d2W2, short* d2W2p,
    const float* u2W, short* u2Wp, const float* fW1, short* fW1p,
    const float* fW2, short* fW2p,
    const float* u0W, short* u0Wp, const float* u1W, short* u1Wp,
    const float* pos, float* posOut) {
  if      (blk < 8)    pack_tile_rt(d0W1, d0W1p, 6, 128, blk, lane);
  else if (blk < 40)   pack_tile_rt(d0W2, d0W2p, 128, 128, blk - 8, lane);
  else if (blk < 120)  pack_tile_rt(d1W1, d1W1p, 131, 256, blk - 40, lane);
  else if (blk < 248)  pack_tile_rt(d1W2, d1W2p, 256, 256, blk - 120, lane);
  else if (blk < 536)  pack_tile_rt(d2W1, d2W1p, 259, 512, blk - 248, lane);
  else if (blk < 1048) pack_tile_rt(d2W2, d2W2p, 512, 512, blk - 536, lane);
  else if (blk < 1088) pack_tile_rt(u2W, u2Wp, 134, 128, blk - 1048, lane);
  else if (blk < 1120) pack_tile_rt(fW1, fW1p, 128, 128, blk - 1088, lane);
  else if (blk < 1152) pack_tile_rt(fW2, fW2p, 128, 128, blk - 1120, lane);
  else if (blk < 1536) pack_tile_rt(u0W, u0Wp, 768, 256, blk - 1152, lane);
  else if (blk < 1632) pack_tile_rt(u1W, u1Wp, 384, 128, blk - 1536, lane);
  else {
    int base = (blk - 1632) * 256;  // 384 x 256 = 98304 = BATCH*NFULL*3
#pragma unroll
    for (int j = 0; j < 4; ++j) {
      int i = base + lane + j * 64;
      posOut[i] = pos[i];
    }
  }
}

// ---- fused pre-kernel: grid builds + packing + brute kNN (idx2, idxu0) ----
// bx<12: grid build; 12..515: packing; 516..643: idx2 (g64); 644..771: idxu0.
__global__ __launch_bounds__(256) void pre_kernel(
    const float* __restrict__ pos, float4* __restrict__ sortedA,
    int* __restrict__ csA, float4* __restrict__ sortedB, int* __restrict__ csB,
    float4* __restrict__ sortedC, int* __restrict__ csC,
    const float* d0W1, short* d0W1p, const float* d0W2, short* d0W2p,
    const float* d1W1, short* d1W1p, const float* d1W2, short* d1W2p,
    const float* d2W1, short* d2W1p, const float* d2W2, short* d2W2p,
    const float* u2W, short* u2Wp, const float* fW1, short* fW1p,
    const float* fW2, short* fW2p,
    const float* u0W, short* u0Wp, const float* u1W, short* u1Wp,
    float* posOut,
    int* __restrict__ idx2, int* __restrict__ idxu0, float* __restrict__ d2u0) {
  __shared__ int cnt[4096];
  __shared__ int partial[256];
  int bx = blockIdx.x, t = threadIdx.x;
  if (bx >= 644) {          // idxu0: 512 q over 128 pts (brute K=3)
    int i = bx - 644;
    knn_brute3_dev(i & 31, i >> 5, pos, 128, 512, idxu0, d2u0);
    return;
  }
  if (bx >= 516) {          // idx2: 128 q over 512 pts (brute K=16, g64)
    int i = bx - 516;
    knn_brute16_g64_dev(i & 31, i >> 5, pos, 512, 128, idx2);
    return;
  }
  if (bx >= 12) {
    int tt = (bx - 12) * 4 + (t >> 6);
    pack_dispatch(tt, t & 63,
        d0W1, d0W1p, d0W2, d0W2p, d1W1, d1W1p, d1W2, d1W2p,
        d2W1, d2W1p, d2W2, d2W2p, u2W, u2Wp, fW1, fW1p, fW2, fW2p,
        u0W, u0Wp, u1W, u1Wp, pos, posOut);
    return;
  }
  int which = bx >> 2, b = bx & 3;
  int NREF = (which == 0) ? 8192 : (which == 1) ? 2048 : 512;
  int GR = (which == 0) ? 16 : 8;
  int NC = GR * GR * GR;
  float4* sorted = ((which == 0) ? sortedA : (which == 1) ? sortedB : sortedC)
                   + (size_t)b * NREF;
  int* cs = ((which == 0) ? csA + b * 4097 : (which == 1) ? csB + b * 513
                                           : csC + b * 513);
  const float* pb = pos + (size_t)b * NFULL * 3;
  for (int c = t; c < NC; c += 256) cnt[c] = 0;
  __syncthreads();
  for (int p = t; p < NREF; p += 256) {
    float x = pb[p * 3 + 0], y = pb[p * 3 + 1], z = pb[p * 3 + 2];
    int cx = min(max((int)(x * GR), 0), GR - 1);
    int cy = min(max((int)(y * GR), 0), GR - 1);
    int cz = min(max((int)(z * GR), 0), GR - 1);
    atomicAdd(&cnt[(cz * GR + cy) * GR + cx], 1);
  }
  __syncthreads();
  int chunk = (NC + 255) / 256;
  int s = 0;
  for (int i = 0; i < chunk; ++i) {
    int c = t * chunk + i;
    if (c < NC) s += cnt[c];
  }
  partial[t] = s;
  __syncthreads();
  if (t == 0) {
    int run = 0;
    for (int i = 0; i < 256; ++i) { int v = partial[i]; partial[i] = run; run += v; }
  }
  __syncthreads();
  int run = partial[t];
  for (int i = 0; i < chunk; ++i) {
    int c = t * chunk + i;
    if (c < NC) { int v = cnt[c]; cnt[c] = run; run += v; }
  }
  __syncthreads();
  for (int c = t; c < NC; c += 256) cs[c] = cnt[c];
  if (t == 0) cs[NC] = NREF;
  __syncthreads();
  for (int p = t; p < NREF; p += 256) {
    float x = pb[p * 3 + 0], y = pb[p * 3 + 1], z = pb[p * 3 + 2];
    int cx = min(max((int)(x * GR), 0), GR - 1);
    int cy = min(max((int)(y * GR), 0), GR - 1);
    int cz = min(max((int)(z * GR), 0), GR - 1);
    int slot = atomicAdd(&cnt[(cz * GR + cy) * GR + cx], 1);
    sorted[slot] = make_float4(x, y, z, __uint_as_float((u32)p));
  }
}

// -------- fused kNN: idx1/idx0 (g64 K=16, R=1 near-first) + K=3 overlap ----
__global__ __launch_bounds__(256) void knn_kernel(
    const float* __restrict__ pos,
    const float4* __restrict__ sortedA, const int* __restrict__ csA,
    const float4* __restrict__ sortedB, const int* __restrict__ csB,
    const float4* __restrict__ sortedC, const int* __restrict__ csC,
    int* __restrict__ idx0, int* __restrict__ idx1,
    int* __restrict__ idxu1, float* __restrict__ d2u1,
    int* __restrict__ idxu2, float* __restrict__ d2u2) {
  int bx = blockIdx.x, b = blockIdx.y;
  if (bx < 128)        // idx1: 512 q over 2048 pts (heaviest per-query)
    knn_grid16_g64_dev<8, 1, 2048>(bx, b, pos, sortedB, csB, 513, 512, idx1);
  else if (bx < 640)   // idx0: 2048 q over 8192 pts
    knn_grid16_g64_dev<16, 1, 8192>(bx - 128, b, pos, sortedA, csA, 4097, 2048, idx0);
  else if (bx < 768)   // idxu1: 2048 q over 512 pts, K=3
    knn_grid_flat32_3_dev<8, 2, 512>(bx - 640, b, pos, sortedC, csC, 513, 2048, idxu1, d2u1);
  else                 // idxu2: 8192 q over 2048 pts, K=3
    knn_grid_flat3_dev<8, 1, 2048>(bx - 768, b, pos, sortedB, csB, 513, 8192, idxu2, d2u2);
}

// ----------------------------------------------------- down MLP (MFMA) -----
template<int FEAT, int CIN, int CHID, int FPAD, int QB, int WAVES>
__global__ __launch_bounds__(64 * WAVES) void down_mfma_kernel(
    const float* __restrict__ pos, const float* __restrict__ xin,
    const int* __restrict__ idx,
    const short* __restrict__ W1p, const float* __restrict__ b1,
    const short* __restrict__ W2p, const float* __restrict__ b2,
    float* __restrict__ out, int n, int nprev) {
  const int KT1 = FPAD / 32, NT1 = CHID / 16;
  const int KT2 = CHID / 32, NT2 = CHID / 16;
  __shared__ short sFeat[QB][16][FPAD + 8];
  __shared__ short sH1[QB][16][CHID + 8];
  __shared__ int sIdx[QB][16];
  __shared__ float sCtr[QB][3];
  int b = blockIdx.y, q0 = blockIdx.x * QB;
  int t = threadIdx.x;
  int lane = t & 63, wv = t >> 6;
  const float* pb = pos + (size_t)b * NFULL * 3;
  const float* xb = xin + (size_t)b * nprev * CIN;
  if (t < QB * 16)
    sIdx[t >> 4][t & 15] = idx[((size_t)b * n + q0 + (t >> 4)) * 16 + (t & 15)];
  if (t < QB * 3) sCtr[t / 3][t % 3] = pb[(q0 + t / 3) * 3 + (t % 3)];
  __syncthreads();
  for (int e = t; e < QB * 16 * FPAD; e += 64 * WAVES) {
    int k = e / FPAD, c = e - k * FPAD;
    int qq = k >> 4, kk = k & 15;
    float v = 0.f;
    if (c < 3) v = pb[sIdx[qq][kk] * 3 + c] - sCtr[qq][c];
    else if (c < FEAT) v = xb[(size_t)sIdx[qq][kk] * CIN + (c - 3)];
    sFeat[qq][kk][c] = f2bf(v);
  }
  __syncthreads();

  int col = lane & 15, quad = lane >> 4;
  const bf8_t* W1t = (const bf8_t*)W1p;
  for (int nt = 2 * wv; nt < NT1; nt += 2 * WAVES) {
    f4_t acc[QB][2];
    float bb0 = b1[nt * 16 + col], bb1 = b1[nt * 16 + 16 + col];
#pragma unroll
    for (int q = 0; q < QB; ++q) {
      acc[q][0] = {bb0, bb0, bb0, bb0};
      acc[q][1] = {bb1, bb1, bb1, bb1};
    }
#pragma unroll
    for (int kt = 0; kt < KT1; ++kt) {
      bf8_t bf0 = W1t[(kt * NT1 + nt) * 64 + lane];
      bf8_t bf1 = W1t[(kt * NT1 + nt + 1) * 64 + lane];
#pragma unroll
      for (int q = 0; q < QB; ++q) {
        bf8_t a = *(const bf8_t*)&sFeat[q][col][kt * 32 + quad * 8];
        acc[q][0] = __builtin_amdgcn_mfma_f32_16x16x32_bf16(a, bf0, acc[q][0], 0, 0, 0);
        acc[q][1] = __builtin_amdgcn_mfma_f32_16x16x32_bf16(a, bf1, acc[q][1], 0, 0, 0);
      }
    }
#pragma unroll
    for (int q = 0; q < QB; ++q)
#pragma unroll
      for (int r = 0; r < 4; ++r) {
        sH1[q][quad * 4 + r][nt * 16 + col] = f2bf(fmaxf(acc[q][0][r], 0.f));
        sH1[q][quad * 4 + r][nt * 16 + 16 + col] = f2bf(fmaxf(acc[q][1][r], 0.f));
      }
  }
  __syncthreads();

  const bf8_t* W2t = (const bf8_t*)W2p;
  for (int nt = 2 * wv; nt < NT2; nt += 2 * WAVES) {
    f4_t acc[QB][2];
    float bb0 = b2[nt * 16 + col], bb1 = b2[nt * 16 + 16 + col];
#pragma unroll
    for (int q = 0; q < QB; ++q) {
      acc[q][0] = {bb0, bb0, bb0, bb0};
      acc[q][1] = {bb1, bb1, bb1, bb1};
    }
#pragma unroll
    for (int kt = 0; kt < KT2; ++kt) {
      bf8_t bf0 = W2t[(kt * NT2 + nt) * 64 + lane];
      bf8_t bf1 = W2t[(kt * NT2 + nt + 1) * 64 + lane];
#pragma unroll
      for (int q = 0; q < QB; ++q) {
        bf8_t a = *(const bf8_t*)&sH1[q][col][kt * 32 + quad * 8];
        acc[q][0] = __builtin_amdgcn_mfma_f32_16x16x32_bf16(a, bf0, acc[q][0], 0, 0, 0);
        acc[q][1] = __builtin_amdgcn_mfma_f32_16x16x32_bf16(a, bf1, acc[q][1], 0, 0, 0);
      }
    }
#pragma unroll
    for (int q = 0; q < QB; ++q) {
      float m0 = fmaxf(fmaxf(acc[q][0][0], acc[q][0][1]), fmaxf(acc[q][0][2], acc[q][0][3]));
      float m1 = fmaxf(fmaxf(acc[q][1][0], acc[q][1][1]), fmaxf(acc[q][1][2], acc[q][1][3]));
      m0 = fmaxf(m0, __shfl_xor(m0, 16, 64));
      m0 = fmaxf(m0, __shfl_xor(m0, 32, 64));
      m1 = fmaxf(m1, __shfl_xor(m1, 16, 64));
      m1 = fmaxf(m1, __shfl_xor(m1, 32, 64));
      if (lane < 16) {
        float* ob = out + ((size_t)b * n + q0 + q) * CHID;
        ob[nt * 16 + lane] = m0;
        ob[nt * 16 + 16 + lane] = m1;
      }
    }
  }
}

// -------------------------------------------- up MLP (bf16 MFMA version) ---
template<int CIN, int CPRV, int COUT, int WPB>
__global__ __launch_bounds__(64 * WPB) void up_mfma_kernel(
    const float* __restrict__ xc, int ncoarse,
    const int* __restrict__ idx3, const float* __restrict__ d23,
    const float* __restrict__ prv, const short* __restrict__ Wp,
    const float* __restrict__ bvec, float* __restrict__ out, int m) {
  const int CTOT = CIN + CPRV;
  const int KT = CTOT / 32, NT = COUT / 16;
  __shared__ short sA[16][CTOT + 8];
  __shared__ float sWt[16][3];
  __shared__ int   sIt[16][3];
  int b = blockIdx.y, q0 = blockIdx.x * 16, t = threadIdx.x;
  int lane = t & 63, wv = t >> 6;
  if (t < 16) {
    size_t base = ((size_t)b * m + q0 + t) * 3;
    float d0 = d23[base + 0], d1 = d23[base + 1], d2v = d23[base + 2];
    float w0 = 1.f / (d0 + 1e-8f), w1 = 1.f / (d1 + 1e-8f), w2 = 1.f / (d2v + 1e-8f);
    float s = w0 + w1 + w2;
    sWt[t][0] = w0 / s; sWt[t][1] = w1 / s; sWt[t][2] = w2 / s;
    sIt[t][0] = idx3[base + 0]; sIt[t][1] = idx3[base + 1]; sIt[t][2] = idx3[base + 2];
  }
  __syncthreads();
  const float* xb = xc + (size_t)b * ncoarse * CIN;
  const float* pvb = prv + ((size_t)b * m + q0) * CPRV;
  for (int e = t; e < 16 * CIN; e += 64 * WPB) {
    int p = e / CIN, c = e % CIN;
    float v = sWt[p][0] * xb[(size_t)sIt[p][0] * CIN + c]
            + sWt[p][1] * xb[(size_t)sIt[p][1] * CIN + c]
            + sWt[p][2] * xb[(size_t)sIt[p][2] * CIN + c];
    sA[p][c] = f2bf(v);
  }
  for (int e = t; e < 16 * CPRV; e += 64 * WPB) {
    int p = e / CPRV, c = e % CPRV;
    sA[p][CIN + c] = f2bf(pvb[(size_t)p * CPRV + c]);
  }
  __syncthreads();
  int col = lane & 15, quad = lane >> 4;
  const bf8_t* Wt = (const bf8_t*)Wp;
  float* ob = out + ((size_t)b * m + q0) * COUT;
  for (int nt = 2 * wv; nt < NT; nt += 2 * WPB) {
    float bb0 = bvec[nt * 16 + col], bb1 = bvec[nt * 16 + 16 + col];
    f4_t acc0 = {bb0, bb0, bb0, bb0}, acc1 = {bb1, bb1, bb1, bb1};
#pragma unroll
    for (int kt = 0; kt < KT; ++kt) {
      bf8_t a = *(const bf8_t*)&sA[col][kt * 32 + quad * 8];
      bf8_t bf0 = Wt[(kt * NT + nt) * 64 + lane];
      bf8_t bf1 = Wt[(kt * NT + nt + 1) * 64 + lane];
      acc0 = __builtin_amdgcn_mfma_f32_16x16x32_bf16(a, bf0, acc0, 0, 0, 0);
      acc1 = __builtin_amdgcn_mfma_f32_16x16x32_bf16(a, bf1, acc1, 0, 0, 0);
    }
#pragma unroll
    for (int r = 0; r < 4; ++r) {
      ob[(size_t)(quad * 4 + r) * COUT + nt * 16 + col] = fmaxf(acc0[r], 0.f);
      ob[(size_t)(quad * 4 + r) * COUT + nt * 16 + 16 + col] = fmaxf(acc1[r], 0.f);
    }
  }
}

// ------------------------------------- fused up2 + final MLP (bf16 MFMA) ---
__global__ __launch_bounds__(128) void up2f_mfma_kernel(
    const float* __restrict__ xc,
    const int* __restrict__ idx3, const float* __restrict__ d23,
    const float* __restrict__ x0, const float* __restrict__ pos0,
    const short* __restrict__ u2Wp, const float* __restrict__ u2b,
    const short* __restrict__ fW1p, const float* __restrict__ fb1,
    const short* __restrict__ fW2p, const float* __restrict__ fb2,
    float* __restrict__ out) {
  __shared__ short sA[16][168];
  __shared__ short sB[16][136];
  __shared__ float sWt[16][3];
  __shared__ int   sIt[16][3];
  int b = blockIdx.y, q0 = blockIdx.x * 16, t = threadIdx.x;
  int lane = t & 63, wv = t >> 6;
  if (t < 16) {
    size_t base = ((size_t)b * NFULL + q0 + t) * 3;
    float d0 = d23[base + 0], d1 = d23[base + 1], d2v = d23[base + 2];
    float w0 = 1.f / (d0 + 1e-8f), w1 = 1.f / (d1 + 1e-8f), w2 = 1.f / (d2v + 1e-8f);
    float s = w0 + w1 + w2;
    sWt[t][0] = w0 / s; sWt[t][1] = w1 / s; sWt[t][2] = w2 / s;
    sIt[t][0] = idx3[base + 0]; sIt[t][1] = idx3[base + 1]; sIt[t][2] = idx3[base + 2];
  }
  __syncthreads();
  const float* xb = xc + (size_t)b * 2048 * 128;
#pragma unroll
  for (int p = 0; p < 16; ++p) {
    float v = sWt[p][0] * xb[(size_t)sIt[p][0] * 128 + t]
            + sWt[p][1] * xb[(size_t)sIt[p][1] * 128 + t]
            + sWt[p][2] * xb[(size_t)sIt[p][2] * 128 + t];
    sA[p][t] = f2bf(v);
  }
  for (int e = t; e < 16 * 32; e += 128) {
    int p = e / 32, c = 128 + (e % 32);
    float v = 0.f;
    if (c < 131) v = x0[((size_t)b * NFULL + q0 + p) * 3 + (c - 128)];
    else if (c < 134) v = pos0[((size_t)b * NFULL + q0 + p) * 3 + (c - 131)];
    sA[p][c] = f2bf(v);
  }
  __syncthreads();
  int col = lane & 15, quad = lane >> 4;

  bf8_t a1[5];
#pragma unroll
  for (int kt = 0; kt < 5; ++kt)
    a1[kt] = *(const bf8_t*)&sA[col][kt * 32 + quad * 8];
  const bf8_t* W1t = (const bf8_t*)u2Wp;
  for (int nt = 2 * wv; nt < 8; nt += 4) {
    float bb0 = u2b[nt * 16 + col], bb1 = u2b[nt * 16 + 16 + col];
    f4_t acc0 = {bb0, bb0, bb0, bb0}, acc1 = {bb1, bb1, bb1, bb1};
#pragma unroll
    for (int kt = 0; kt < 5; ++kt) {
      bf8_t bf0 = W1t[(kt * 8 + nt) * 64 + lane];
      bf8_t bf1 = W1t[(kt * 8 + nt + 1) * 64 + lane];
      acc0 = __builtin_amdgcn_mfma_f32_16x16x32_bf16(a1[kt], bf0, acc0, 0, 0, 0);
      acc1 = __builtin_amdgcn_mfma_f32_16x16x32_bf16(a1[kt], bf1, acc1, 0, 0, 0);
    }
#pragma unroll
    for (int r = 0; r < 4; ++r) {
      sB[quad * 4 + r][nt * 16 + col] = f2bf(fmaxf(acc0[r], 0.f));
      sB[quad * 4 + r][nt * 16 + 16 + col] = f2bf(fmaxf(acc1[r], 0.f));
    }
  }
  __syncthreads();

  bf8_t a2[4];
#pragma unroll
  for (int kt = 0; kt < 4; ++kt)
    a2[kt] = *(const bf8_t*)&sB[col][kt * 32 + quad * 8];
  const bf8_t* W2t = (const bf8_t*)fW1p;
  for (int nt = 2 * wv; nt < 8; nt += 4) {
    float bb0 = fb1[nt * 16 + col], bb1 = fb1[nt * 16 + 16 + col];
    f4_t acc0 = {bb0, bb0, bb0, bb0}, acc1 = {bb1, bb1, bb1, bb1};
#pragma unroll
    for (int kt = 0; kt < 4; ++kt) {
      bf8_t bf0 = W2t[(kt * 8 + nt) * 64 + lane];
      bf8_t bf1 = W2t[(kt * 8 + nt + 1) * 64 + lane];
      acc0 = __builtin_amdgcn_mfma_f32_16x16x32_bf16(a2[kt], bf0, acc0, 0, 0, 0);
      acc1 = __builtin_amdgcn_mfma_f32_16x16x32_bf16(a2[kt], bf1, acc1, 0, 0, 0);
    }
#pragma unroll
    for (int r = 0; r < 4; ++r) {
      sA[quad * 4 + r][nt * 16 + col] = f2bf(fmaxf(acc0[r], 0.f));
      sA[quad * 4 + r][nt * 16 + 16 + col] = f2bf(fmaxf(acc1[r], 0.f));
    }
  }
  __syncthreads();

  bf8_t a3[4];
#pragma unroll
  for (int kt = 0; kt < 4; ++kt)
    a3[kt] = *(const bf8_t*)&sA[col][kt * 32 + quad * 8];
  const bf8_t* W3t = (const bf8_t*)fW2p;
  float* ob = out + ((size_t)b * NFULL + q0) * 128;
  for (int nt = 2 * wv; nt < 8; nt += 4) {
    float bb0 = fb2[nt * 16 + col], bb1 = fb2[nt * 16 + 16 + col];
    f4_t acc0 = {bb0, bb0, bb0, bb0}, acc1 = {bb1, bb1, bb1, bb1};
#pragma unroll
    for (int kt = 0; kt < 4; ++kt) {
      bf8_t bf0 = W3t[(kt * 8 + nt) * 64 + lane];
      bf8_t bf1 = W3t[(kt * 8 + nt + 1) * 64 + lane];
      acc0 = __builtin_amdgcn_mfma_f32_16x16x32_bf16(a3[kt], bf0, acc0, 0, 0, 0);
      acc1 = __builtin_amdgcn_mfma_f32_16x16x32_bf16(a3[kt], bf1, acc1, 0, 0, 0);
    }
#pragma unroll
    for (int r = 0; r < 4; ++r) {
      ob[(size_t)(quad * 4 + r) * 128 + nt * 16 + col] = acc0[r];
      ob[(size_t)(quad * 4 + r) * 128 + nt * 16 + 16 + col] = acc1[r];
    }
  }
}

// ------------------------------------------------------------------ launch -
extern "C" void kernel_launch(void* const* d_in, const int* in_sizes, int n_in,
                              void* d_out, int out_size, void* d_ws, size_t ws_size,
                              hipStream_t stream) {
  const float* x    = (const float*)d_in[0];
  const float* pos  = (const float*)d_in[1];
  const float* d0W1 = (const float*)d_in[2];
  const float* d0b1 = (const float*)d_in[3];
  const float* d0W2 = (const float*)d_in[4];
  const float* d0b2 = (const float*)d_in[5];
  const float* d1W1 = (const float*)d_in[6];
  const float* d1b1 = (const float*)d_in[7];
  const float* d1W2 = (const float*)d_in[8];
  const float* d1b2 = (const float*)d_in[9];
  const float* d2W1 = (const float*)d_in[10];
  const float* d2b1 = (const float*)d_in[11];
  const float* d2W2 = (const float*)d_in[12];
  const float* d2b2 = (const float*)d_in[13];
  const float* u0W  = (const float*)d_in[14];
  const float* u0b  = (const float*)d_in[15];
  const float* u1W  = (const float*)d_in[16];
  const float* u1b  = (const float*)d_in[17];
  const float* u2W  = (const float*)d_in[18];
  const float* u2b  = (const float*)d_in[19];
  const float* fW1  = (const float*)d_in[20];
  const float* fb1  = (const float*)d_in[21];
  const float* fW2  = (const float*)d_in[22];
  const float* fb2  = (const float*)d_in[23];

  char* ws = (char*)d_ws;
  float* x1    = (float*)(ws + 0);
  float* x2    = (float*)(ws + 4194304);
  float* x3    = (float*)(ws + 6291456);
  float* up0o  = (float*)(ws + 7340032);
  float* up1o  = (float*)(ws + 9437184);
  int*   idx0  = (int*)  (ws + 13631488);
  int*   idx1  = (int*)  (ws + 14155776);
  int*   idx2  = (int*)  (ws + 14286848);
  float4* sortedC = (float4*)(ws + 14319616); // 4*512*16 = 32768
  int*    csC     = (int*)   (ws + 14352384); // 4*513*4  = 8208
  int*   idxu0 = (int*)  (ws + 14843904);
  float* d2u0  = (float*)(ws + 14868480);
  int*   idxu1 = (int*)  (ws + 14893056);
  float* d2u1  = (float*)(ws + 14991360);
  int*   idxu2 = (int*)  (ws + 15089664);
  float* d2u2  = (float*)(ws + 15482880);
  short* d1W1p = (short*)(ws + 15876096);
  short* d1W2p = (short*)(ws + 15958016);
  short* d2W1p = (short*)(ws + 16089088);
  short* d2W2p = (short*)(ws + 16384000);
  short* d0W1p = (short*)(ws + 16908288);
  short* d0W2p = (short*)(ws + 16916480);
  float4* sortedA = (float4*)(ws + 16949248);  // 4*8192*16 = 524288
  int*    csA     = (int*)   (ws + 17473536);  // 4*4097*4  = 65552
  float4* sortedB = (float4*)(ws + 17539136);  // 4*2048*16 = 131072
  int*    csB     = (int*)   (ws + 17670208);  // 4*513*4   = 8208
  short* u2Wp  = (short*)(ws + 17697920);
  short* fW1p  = (short*)(ws + 17738880);
  short* fW2p  = (short*)(ws + 17771648);

  float* out = (float*)d_out;
  // Packed u0W/u1W live in the d_out main region: it is dead until the final
  // up2f_mfma_kernel writes it, and both are fully consumed before that.
  short* u0Wp = (short*)out;                       // 768*256*2 = 393216 B
  short* u1Wp = (short*)(out + 98304);             // 384*128*2 =  98304 B

  // ---- pre: grids + packing + pos copy + brute kNN (idx2, idxu0) ----
  pre_kernel<<<dim3(772), 256, 0, stream>>>(
      pos, sortedA, csA, sortedB, csB, sortedC, csC,
      d0W1, d0W1p, d0W2, d0W2p, d1W1, d1W1p, d1W2, d1W2p,
      d2W1, d2W1p, d2W2, d2W2p, u2W, u2Wp, fW1, fW1p, fW2, fW2p,
      u0W, u0Wp, u1W, u1Wp,
      out + (size_t)BATCH * NFULL * 128,
      idx2, idxu0, d2u0);

  // ---- fused kNN: g64 K=16 near-first (idx1, idx0) + K=3 overlap ----
  knn_kernel<<<dim3(1280, BATCH), 256, 0, stream>>>(
      pos, sortedA, csA, sortedB, csB, sortedC, csC,
      idx0, idx1, idxu1, d2u1, idxu2, d2u2);

  // ---- down path ----
  down_mfma_kernel<6, 3, 128, 32, 4, 4><<<dim3(512, BATCH), 256, 0, stream>>>(
      pos, x, idx0, d0W1p, d0b1, d0W2p, d0b2, x1, 2048, 8192);
  down_mfma_kernel<131, 128, 256, 160, 4, 8><<<dim3(128, BATCH), 512, 0, stream>>>(
      pos, x1, idx1, d1W1p, d1b1, d1W2p, d1b2, x2, 512, 2048);
  down_mfma_kernel<259, 256, 512, 288, 2, 8><<<dim3(64, BATCH), 512, 0, stream>>>(
      pos, x2, idx2, d2W1p, d2b1, d2W2p, d2b2, x3, 128, 512);

  // ---- up path ----
  up_mfma_kernel<512, 256, 256, 4><<<dim3(32, BATCH), 256, 0, stream>>>(
      x3, 128, idxu0, d2u0, x2, u0Wp, u0b, up0o, 512);
  up_mfma_kernel<256, 128, 128, 2><<<dim3(128, BATCH), 128, 0, stream>>>(
      up0o, 512, idxu1, d2u1, x1, u1Wp, u1b, up1o, 2048);
  up2f_mfma_kernel<<<dim3(512, BATCH), 128, 0, stream>>>(
      up1o, idxu2, d2u2, x, pos, u2Wp, u2b, fW1p, fb1, fW2p, fb2, out);
}